// Round 2
// baseline (744.947 us; speedup 1.0000x reference)
//
#include <hip/hip_runtime.h>

typedef short bf16x8 __attribute__((ext_vector_type(8)));
typedef unsigned short u16x8 __attribute__((ext_vector_type(8)));
typedef float f32x4 __attribute__((ext_vector_type(4)));
typedef unsigned short u16;

#define MFMA16(a, b, c) __builtin_amdgcn_mfma_f32_16x16x32_bf16((a), (b), (c), 0, 0, 0)

__device__ __forceinline__ u16 bf16_rtn(float f) {
  unsigned u = __float_as_uint(f);
  u += 0x7fffu + ((u >> 16) & 1u);
  return (u16)(u >> 16);
}
__device__ __forceinline__ float bf16_to_f(u16 h) {
  return __uint_as_float(((unsigned)h) << 16);
}
__device__ __forceinline__ void splitf(float f, u16& hi, u16& lo) {
  hi = bf16_rtn(f);
  lo = bf16_rtn(f - bf16_to_f(hi));
}
__device__ __forceinline__ void gload16(const void* g, void* l) {
  __builtin_amdgcn_global_load_lds(
      (const __attribute__((address_space(1))) unsigned int*)g,
      (__attribute__((address_space(3))) unsigned int*)l, 16, 0, 0);
}

// ---------------- elementwise convert ----------------
__global__ void k_split(const float* __restrict__ in, u16* __restrict__ hi,
                        u16* __restrict__ lo, int n4) {
  int i = blockIdx.x * blockDim.x + threadIdx.x;
  if (i >= n4) return;
  float4 v = ((const float4*)in)[i];
  ushort4 h, l;
  splitf(v.x, h.x, l.x);
  splitf(v.y, h.y, l.y);
  splitf(v.z, h.z, l.z);
  splitf(v.w, h.w, l.w);
  ((ushort4*)hi)[i] = h;
  ((ushort4*)lo)[i] = l;
}

__global__ void k_conv(const float* __restrict__ in, u16* __restrict__ hi, int n4) {
  int i = blockIdx.x * blockDim.x + threadIdx.x;
  if (i >= n4) return;
  float4 v = ((const float4*)in)[i];
  ushort4 h;
  h.x = bf16_rtn(v.x);
  h.y = bf16_rtn(v.y);
  h.z = bf16_rtn(v.z);
  h.w = bf16_rtn(v.w);
  ((ushort4*)hi)[i] = h;
}

// ------------- transpose fp32 [R][C] -> bf16 [C][R] (hi / hi+lo) -------------
template <int SPLIT>
__global__ void k_tconv(const float* __restrict__ in, u16* __restrict__ hi,
                        u16* __restrict__ lo, int R, int C) {
  __shared__ float tile[32][33];
  int c0 = blockIdx.x * 32, r0 = blockIdx.y * 32;
  int tx = threadIdx.x & 31, ty = threadIdx.x >> 5;
#pragma unroll
  for (int i = 0; i < 4; ++i)
    tile[ty + i * 8][tx] = in[(size_t)(r0 + ty + i * 8) * C + c0 + tx];
  __syncthreads();
#pragma unroll
  for (int i = 0; i < 4; ++i) {
    float v = tile[tx][ty + i * 8];
    size_t o = (size_t)(c0 + ty + i * 8) * R + r0 + tx;
    if (SPLIT) {
      u16 h, l;
      splitf(v, h, l);
      hi[o] = h;
      lo[o] = l;
    } else {
      hi[o] = bf16_rtn(v);
    }
  }
}

// ------------- transpose u16 [R][C] -> [C][R], batched over z -------------
__global__ void k_t16(const u16* __restrict__ in, u16* __restrict__ out, int R, int C) {
  size_t base = (size_t)blockIdx.z * R * C;
  __shared__ u16 tile[32][33];
  int c0 = blockIdx.x * 32, r0 = blockIdx.y * 32;
  int tx = threadIdx.x & 31, ty = threadIdx.x >> 5;
#pragma unroll
  for (int i = 0; i < 4; ++i)
    tile[ty + i * 8][tx] = in[base + (size_t)(r0 + ty + i * 8) * C + c0 + tx];
  __syncthreads();
#pragma unroll
  for (int i = 0; i < 4; ++i)
    out[base + (size_t)(c0 + ty + i * 8) * R + r0 + tx] = tile[tx][ty + i * 8];
}

// ------------- GEMM: C[M,Nc] = A[M,K] * B[Nc,K]^T + bias -------------
// m97 structure: global_load_lds width-16 staging into linear LDS, 128x128 tile.
// OUT: 0 = fp32 row-major, 1 = bf16 row-major, 2 = split hi/lo head-major [n,h,T,64]
template <int SPLIT, int GELU, int OUT>
__global__ __launch_bounds__(256) void k_gemm(
    const u16* __restrict__ Ahi, const u16* __restrict__ Alo,
    const u16* __restrict__ Bhi, const u16* __restrict__ Blo,
    const float* __restrict__ bias, void* __restrict__ C0, void* __restrict__ C1,
    int M, int Nc, int K) {
  extern __shared__ u16 sm[];
  u16* lA = sm;
  u16* lB = sm + 4096;
  u16* lAl = SPLIT ? sm + 8192 : (u16*)nullptr;
  u16* lBl = SPLIT ? sm + 12288 : (u16*)nullptr;

  int t = threadIdx.x;
  int m0 = blockIdx.y * 128, n0 = blockIdx.x * 128;
  int lane = t & 63, w = t >> 6;
  int wr = (w >> 1) * 64, wc = (w & 1) * 64;
  int li = lane & 15, g = lane >> 4;
  int srow = lane >> 2, scol = (lane & 3) * 8;  // staging: 16 rows x 32 cols per 1KB call

  f32x4 acc[4][4] = {};

  const int nk = K >> 5;
  for (int kb = 0; kb < nk; ++kb) {
    int k0 = kb * 32;
#pragma unroll
    for (int c = 0; c < 2; ++c) {
      int row = w * 32 + c * 16 + srow;
      int ldso = w * 1024 + c * 512;  // elements
      gload16(Ahi + (size_t)(m0 + row) * K + k0 + scol, lA + ldso);
      gload16(Bhi + (size_t)(n0 + row) * K + k0 + scol, lB + ldso);
      if (SPLIT) {
        gload16(Alo + (size_t)(m0 + row) * K + k0 + scol, lAl + ldso);
        gload16(Blo + (size_t)(n0 + row) * K + k0 + scol, lBl + ldso);
      }
    }
    __syncthreads();
    bf16x8 af[4], bfr[4], afl[4], bfl[4];
#pragma unroll
    for (int i = 0; i < 4; ++i) {
      af[i] = *(const bf16x8*)&lA[(wr + i * 16 + li) * 32 + g * 8];
      bfr[i] = *(const bf16x8*)&lB[(wc + i * 16 + li) * 32 + g * 8];
      if (SPLIT) {
        afl[i] = *(const bf16x8*)&lAl[(wr + i * 16 + li) * 32 + g * 8];
        bfl[i] = *(const bf16x8*)&lBl[(wc + i * 16 + li) * 32 + g * 8];
      }
    }
#pragma unroll
    for (int a = 0; a < 4; ++a)
#pragma unroll
      for (int b = 0; b < 4; ++b) {
        acc[a][b] = MFMA16(af[a], bfr[b], acc[a][b]);
        if (SPLIT) {
          acc[a][b] = MFMA16(af[a], bfl[b], acc[a][b]);
          acc[a][b] = MFMA16(afl[a], bfr[b], acc[a][b]);
        }
      }
    __syncthreads();
  }

#pragma unroll
  for (int a = 0; a < 4; ++a)
#pragma unroll
    for (int b = 0; b < 4; ++b)
#pragma unroll
      for (int r = 0; r < 4; ++r) {
        int row = m0 + wr + a * 16 + g * 4 + r;
        int col = n0 + wc + b * 16 + li;
        float v = acc[a][b][r] + bias[col];
        if (GELU) v = 0.5f * v * (1.0f + erff(v * 0.70710678118654752f));
        if (OUT == 0) {
          ((float*)C0)[(size_t)row * Nc + col] = v;
        } else if (OUT == 1) {
          ((u16*)C0)[(size_t)row * Nc + col] = bf16_rtn(v);
        } else {
          // head-major split: [n, h, t, d]
          u16 hh, ll;
          splitf(v, hh, ll);
          size_t off = (((size_t)(row >> 11) * 16 + (col >> 6)) * 2048 + (row & 2047)) * 64 + (col & 63);
          ((u16*)C0)[off] = hh;
          ((u16*)C1)[off] = ll;
        }
      }
}

// ------------- flash attention, strictly-causal + [0,0], no 1/sqrt(d) -------------
// Q/K pre-split bf16 head-major [n,h,T,64]; V^T [n,h,64,T].
// grid: (qb=T/64 remapped largest-first, H, N); block 256 (4 waves, 16 q-rows each)
__global__ __launch_bounds__(256) void k_attn(
    const u16* __restrict__ Qh, const u16* __restrict__ Ql,
    const u16* __restrict__ Kh, const u16* __restrict__ Kl,
    const u16* __restrict__ VT, u16* __restrict__ out) {
  const int T = 2048, HD = 64, H = 16, E = 1024;
  int qb = 31 - (int)blockIdx.x;  // largest workload first
  int h = blockIdx.y, n = blockIdx.z;
  __shared__ u16 P[2][64][72];
  int t = threadIdx.x, lane = t & 63, w = t >> 6;
  int li = lane & 15, g = lane >> 4;

  const size_t hdoff = (size_t)(n * H + h) * T * HD;
  const u16* qhb = Qh + hdoff + (size_t)qb * 64 * HD;
  const u16* qlb = Ql + hdoff + (size_t)qb * 64 * HD;
  const u16* khb = Kh + hdoff;
  const u16* klb = Kl + hdoff;
  const u16* vtb = VT + hdoff;

  bf16x8 qh[2], ql[2];
#pragma unroll
  for (int ks = 0; ks < 2; ++ks) {
    qh[ks] = *(const bf16x8*)&qhb[(w * 16 + li) * HD + ks * 32 + g * 8];
    ql[ks] = *(const bf16x8*)&qlb[(w * 16 + li) * HD + ks * 32 + g * 8];
  }

  float mr[4] = {-INFINITY, -INFINITY, -INFINITY, -INFINITY};
  float lr[4] = {0.f, 0.f, 0.f, 0.f};
  f32x4 O[4] = {};

  for (int kb = 0; kb <= qb; ++kb) {
    f32x4 s[4] = {};
#pragma unroll
    for (int ks = 0; ks < 2; ++ks)
#pragma unroll
      for (int c = 0; c < 4; ++c) {
        bf16x8 kh = *(const bf16x8*)&khb[(size_t)(kb * 64 + c * 16 + li) * HD + ks * 32 + g * 8];
        bf16x8 kl = *(const bf16x8*)&klb[(size_t)(kb * 64 + c * 16 + li) * HD + ks * 32 + g * 8];
        s[c] = MFMA16(qh[ks], kh, s[c]);
        s[c] = MFMA16(qh[ks], kl, s[c]);
        s[c] = MFMA16(ql[ks], kh, s[c]);
      }

    if (kb == qb) {
#pragma unroll
      for (int c = 0; c < 4; ++c)
#pragma unroll
        for (int r = 0; r < 4; ++r) {
          int i = qb * 64 + w * 16 + g * 4 + r;
          int j = kb * 64 + c * 16 + li;
          if (!(j < i || (i == 0 && j == 0))) s[c][r] = -INFINITY;
        }
    }

    float ml[4];
#pragma unroll
    for (int r = 0; r < 4; ++r)
      ml[r] = fmaxf(fmaxf(s[0][r], s[1][r]), fmaxf(s[2][r], s[3][r]));
#pragma unroll
    for (int off = 1; off < 16; off <<= 1)
#pragma unroll
      for (int r = 0; r < 4; ++r) ml[r] = fmaxf(ml[r], __shfl_xor(ml[r], off, 16));

    float scl[4];
#pragma unroll
    for (int r = 0; r < 4; ++r) {
      float mn = fmaxf(mr[r], ml[r]);
      scl[r] = __expf(mr[r] - mn);
      mr[r] = mn;
    }
    float rs[4] = {0.f, 0.f, 0.f, 0.f};
#pragma unroll
    for (int c = 0; c < 4; ++c)
#pragma unroll
      for (int r = 0; r < 4; ++r) {
        float p = __expf(s[c][r] - mr[r]);
        s[c][r] = p;
        rs[r] += p;
      }
#pragma unroll
    for (int off = 1; off < 16; off <<= 1)
#pragma unroll
      for (int r = 0; r < 4; ++r) rs[r] += __shfl_xor(rs[r], off, 16);
#pragma unroll
    for (int r = 0; r < 4; ++r) lr[r] = lr[r] * scl[r] + rs[r];

    int pb = kb & 1;
#pragma unroll
    for (int c = 0; c < 4; ++c)
#pragma unroll
      for (int r = 0; r < 4; ++r) {
        O[c][r] *= scl[r];
        P[pb][w * 16 + g * 4 + r][c * 16 + li] = bf16_rtn(s[c][r]);
      }
    __syncthreads();  // single barrier per iteration (P double-buffered)

#pragma unroll
    for (int ks = 0; ks < 2; ++ks) {
      bf16x8 pa = *(const bf16x8*)&P[pb][w * 16 + li][ks * 32 + g * 8];
#pragma unroll
      for (int c = 0; c < 4; ++c) {
        bf16x8 vb = *(const bf16x8*)&vtb[(size_t)(c * 16 + li) * T + kb * 64 + ks * 32 + g * 8];
        O[c] = MFMA16(pa, vb, O[c]);
      }
    }
  }

#pragma unroll
  for (int c = 0; c < 4; ++c)
#pragma unroll
    for (int r = 0; r < 4; ++r) {
      float v = O[c][r] / lr[r];
      size_t row = (size_t)(n * T + qb * 64 + w * 16 + g * 4 + r);
      out[row * E + h * HD + c * 16 + li] = bf16_rtn(v);
    }
}

// ---------------------------------------------------------------------------
extern "C" void kernel_launch(void* const* d_in, const int* in_sizes, int n_in,
                              void* d_out, int out_size, void* d_ws, size_t ws_size,
                              hipStream_t stream) {
  const float* kq = (const float*)d_in[0];
  const float* v = (const float*)d_in[1];
  const float* Wk = (const float*)d_in[2];
  const float* bk = (const float*)d_in[3];
  const float* Wq = (const float*)d_in[4];
  const float* bq = (const float*)d_in[5];
  const float* Wv = (const float*)d_in[6];
  const float* bv = (const float*)d_in[7];
  const float* W1 = (const float*)d_in[8];
  const float* b1 = (const float*)d_in[9];
  const float* W2 = (const float*)d_in[10];
  const float* b2 = (const float*)d_in[11];
  float* outp = (float*)d_out;

  char* ws = (char*)d_ws;
  // Region A (32MB): kq_hi, kq_lo, v_bf, vv — dead after attention prep;
  // aliased by FFN hidden hbuf (32MB).
  u16* kq_hi = (u16*)(ws + 0);
  u16* kq_lo = (u16*)(ws + 8388608);
  u16* v_bf = (u16*)(ws + 16777216);
  u16* vv = (u16*)(ws + 25165824);
  u16* hbuf = (u16*)(ws + 0);
  u16* WkT_hi = (u16*)(ws + 33554432);
  u16* WkT_lo = (u16*)(ws + 35651584);
  u16* WqT_hi = (u16*)(ws + 37748736);
  u16* WqT_lo = (u16*)(ws + 39845888);
  u16* WvT = (u16*)(ws + 41943040);
  u16* W1T = (u16*)(ws + 44040192);
  u16* W2T = (u16*)(ws + 52428800);
  u16* Qh = (u16*)(ws + 60817408);
  u16* Ql = (u16*)(ws + 69206016);
  u16* Kh = (u16*)(ws + 77594624);
  u16* Kl = (u16*)(ws + 85983232);
  u16* VT = (u16*)(ws + 94371840);
  u16* attn_o = (u16*)(ws + 102760448);
  // total: 111,149,056 bytes (same footprint as R1)

  // --- conversions ---
  k_split<<<4096, 256, 0, stream>>>(kq, kq_hi, kq_lo, (4096 * 1024) / 4);
  k_conv<<<4096, 256, 0, stream>>>(v, v_bf, (4096 * 1024) / 4);
  k_tconv<1><<<dim3(32, 32), 256, 0, stream>>>(Wk, WkT_hi, WkT_lo, 1024, 1024);
  k_tconv<1><<<dim3(32, 32), 256, 0, stream>>>(Wq, WqT_hi, WqT_lo, 1024, 1024);
  k_tconv<0><<<dim3(32, 32), 256, 0, stream>>>(Wv, WvT, nullptr, 1024, 1024);
  k_tconv<0><<<dim3(128, 32), 256, 0, stream>>>(W1, W1T, nullptr, 1024, 4096);
  k_tconv<0><<<dim3(32, 128), 256, 0, stream>>>(W2, W2T, nullptr, 4096, 1024);

  // --- projections (K, Q split-precision, epilogue writes hi/lo head-major) ---
  k_gemm<1, 0, 2><<<dim3(8, 32), 256, 32768, stream>>>(kq_hi, kq_lo, WkT_hi, WkT_lo, bk, Kh, Kl, 4096, 1024, 1024);
  k_gemm<1, 0, 2><<<dim3(8, 32), 256, 32768, stream>>>(kq_hi, kq_lo, WqT_hi, WqT_lo, bq, Qh, Ql, 4096, 1024, 1024);
  k_gemm<0, 0, 1><<<dim3(8, 32), 256, 16384, stream>>>(v_bf, nullptr, WvT, nullptr, bv, vv, nullptr, 4096, 1024, 1024);

  // --- V transpose to [n,h,d,T] ---
  k_t16<<<dim3(32, 64, 2), 256, 0, stream>>>(vv, VT, 2048, 1024);

  // --- attention ---
  k_attn<<<dim3(32, 16, 2), 256, 0, stream>>>(Qh, Ql, Kh, Kl, VT, attn_o);

  // --- FFN ---
  k_gemm<0, 1, 1><<<dim3(32, 32), 256, 16384, stream>>>(attn_o, nullptr, W1T, nullptr, b1, hbuf, nullptr, 4096, 4096, 1024);
  k_gemm<0, 0, 0><<<dim3(8, 32), 256, 16384, stream>>>(hbuf, nullptr, W2T, nullptr, b2, outp, nullptr, 4096, 1024, 4096);
}

// Round 3
// 488.572 us; speedup vs baseline: 1.5247x; 1.5247x over previous
//
#include <hip/hip_runtime.h>

typedef short bf16x8 __attribute__((ext_vector_type(8)));
typedef unsigned short u16x8 __attribute__((ext_vector_type(8)));
typedef float f32x4 __attribute__((ext_vector_type(4)));
typedef unsigned short u16;

#define MFMA16(a, b, c) __builtin_amdgcn_mfma_f32_16x16x32_bf16((a), (b), (c), 0, 0, 0)

__device__ __forceinline__ u16 bf16_rtn(float f) {
  unsigned u = __float_as_uint(f);
  u += 0x7fffu + ((u >> 16) & 1u);
  return (u16)(u >> 16);
}
__device__ __forceinline__ float bf16_to_f(u16 h) {
  return __uint_as_float(((unsigned)h) << 16);
}
__device__ __forceinline__ void splitf(float f, u16& hi, u16& lo) {
  hi = bf16_rtn(f);
  lo = bf16_rtn(f - bf16_to_f(hi));
}
__device__ __forceinline__ void gload16(const void* g, void* l) {
  __builtin_amdgcn_global_load_lds(
      (const __attribute__((address_space(1))) unsigned int*)g,
      (__attribute__((address_space(3))) unsigned int*)l, 16, 0, 0);
}

// ---------------- elementwise convert ----------------
__global__ void k_split(const float* __restrict__ in, u16* __restrict__ hi,
                        u16* __restrict__ lo, int n4) {
  int i = blockIdx.x * blockDim.x + threadIdx.x;
  if (i >= n4) return;
  float4 v = ((const float4*)in)[i];
  ushort4 h, l;
  splitf(v.x, h.x, l.x);
  splitf(v.y, h.y, l.y);
  splitf(v.z, h.z, l.z);
  splitf(v.w, h.w, l.w);
  ((ushort4*)hi)[i] = h;
  ((ushort4*)lo)[i] = l;
}

__global__ void k_conv(const float* __restrict__ in, u16* __restrict__ hi, int n4) {
  int i = blockIdx.x * blockDim.x + threadIdx.x;
  if (i >= n4) return;
  float4 v = ((const float4*)in)[i];
  ushort4 h;
  h.x = bf16_rtn(v.x);
  h.y = bf16_rtn(v.y);
  h.z = bf16_rtn(v.z);
  h.w = bf16_rtn(v.w);
  ((ushort4*)hi)[i] = h;
}

// ------------- transpose fp32 [R][C] -> bf16 [C][R] (hi / hi+lo) -------------
template <int SPLIT>
__global__ void k_tconv(const float* __restrict__ in, u16* __restrict__ hi,
                        u16* __restrict__ lo, int R, int C) {
  __shared__ float tile[32][33];
  int c0 = blockIdx.x * 32, r0 = blockIdx.y * 32;
  int tx = threadIdx.x & 31, ty = threadIdx.x >> 5;
#pragma unroll
  for (int i = 0; i < 4; ++i)
    tile[ty + i * 8][tx] = in[(size_t)(r0 + ty + i * 8) * C + c0 + tx];
  __syncthreads();
#pragma unroll
  for (int i = 0; i < 4; ++i) {
    float v = tile[tx][ty + i * 8];
    size_t o = (size_t)(c0 + ty + i * 8) * R + r0 + tx;
    if (SPLIT) {
      u16 h, l;
      splitf(v, h, l);
      hi[o] = h;
      lo[o] = l;
    } else {
      hi[o] = bf16_rtn(v);
    }
  }
}

// ------------- transpose u16 [R][C] -> [C][R], batched over z -------------
__global__ void k_t16(const u16* __restrict__ in, u16* __restrict__ out, int R, int C) {
  size_t base = (size_t)blockIdx.z * R * C;
  __shared__ u16 tile[32][33];
  int c0 = blockIdx.x * 32, r0 = blockIdx.y * 32;
  int tx = threadIdx.x & 31, ty = threadIdx.x >> 5;
#pragma unroll
  for (int i = 0; i < 4; ++i)
    tile[ty + i * 8][tx] = in[base + (size_t)(r0 + ty + i * 8) * C + c0 + tx];
  __syncthreads();
#pragma unroll
  for (int i = 0; i < 4; ++i)
    out[base + (size_t)(c0 + ty + i * 8) * R + r0 + tx] = tile[tx][ty + i * 8];
}

// ------------- GEMM: C[M,Nc] = A[M,K] * B[Nc,K]^T + bias -------------
// global_load_lds width-16 staging into linear LDS. Tile BM x 128, BK=32.
// OUT: 0 = fp32 row-major, 1 = bf16 row-major,
//      2 = split hi/lo head-major [n,h,t,d] (Q),
//      3 = split packed K layout: per (n,h,kb=t/64): 8192 u16 =
//          [hi: [ks=d/32][t%64][d%32]][lo: same]
template <int SPLIT, int GELU, int OUT, int BM>
__global__ __launch_bounds__(256) void k_gemm(
    const u16* __restrict__ Ahi, const u16* __restrict__ Alo,
    const u16* __restrict__ Bhi, const u16* __restrict__ Blo,
    const float* __restrict__ bias, void* __restrict__ C0, void* __restrict__ C1,
    int M, int Nc, int K) {
  extern __shared__ u16 sm[];
  const int ASZ = BM * 32;  // u16 per A tile
  u16* lA = sm;
  u16* lB = sm + ASZ;
  u16* lAl = SPLIT ? sm + ASZ + 4096 : (u16*)nullptr;
  u16* lBl = SPLIT ? sm + 2 * ASZ + 4096 : (u16*)nullptr;

  int t = threadIdx.x;
  int m0 = blockIdx.y * BM, n0 = blockIdx.x * 128;
  int lane = t & 63, w = t >> 6;
  const int wr = (BM == 128) ? (w >> 1) * 64 : 0;
  const int wc = (BM == 128) ? (w & 1) * 64 : w * 32;
  const int NB = (BM == 128) ? 4 : 2;
  int li = lane & 15, g = lane >> 4;
  int srow = lane >> 2, scol = (lane & 3) * 8;

  f32x4 acc[4][4] = {};

  const int nk = K >> 5;
  for (int kb = 0; kb < nk; ++kb) {
    int k0 = kb * 32;
    // B: 128 rows, 2 rounds of 64 rows
#pragma unroll
    for (int c = 0; c < 2; ++c) {
      int row = w * 32 + c * 16 + srow;
      int ldso = w * 1024 + c * 512;
      gload16(Bhi + (size_t)(n0 + row) * K + k0 + scol, lB + ldso);
      if (SPLIT) gload16(Blo + (size_t)(n0 + row) * K + k0 + scol, lBl + ldso);
    }
    // A: BM rows
    if (BM == 128) {
#pragma unroll
      for (int c = 0; c < 2; ++c) {
        int row = w * 32 + c * 16 + srow;
        int ldso = w * 1024 + c * 512;
        gload16(Ahi + (size_t)(m0 + row) * K + k0 + scol, lA + ldso);
        if (SPLIT) gload16(Alo + (size_t)(m0 + row) * K + k0 + scol, lAl + ldso);
      }
    } else {
      int row = w * 16 + srow;
      int ldso = w * 512;
      gload16(Ahi + (size_t)(m0 + row) * K + k0 + scol, lA + ldso);
      if (SPLIT) gload16(Alo + (size_t)(m0 + row) * K + k0 + scol, lAl + ldso);
    }
    __syncthreads();
    bf16x8 af[4], bfr[4], afl[4], bfl[4];
#pragma unroll
    for (int i = 0; i < 4; ++i) {
      af[i] = *(const bf16x8*)&lA[(wr + i * 16 + li) * 32 + g * 8];
      if (SPLIT) afl[i] = *(const bf16x8*)&lAl[(wr + i * 16 + li) * 32 + g * 8];
    }
#pragma unroll
    for (int j = 0; j < NB; ++j) {
      bfr[j] = *(const bf16x8*)&lB[(wc + j * 16 + li) * 32 + g * 8];
      if (SPLIT) bfl[j] = *(const bf16x8*)&lBl[(wc + j * 16 + li) * 32 + g * 8];
    }
#pragma unroll
    for (int a = 0; a < 4; ++a)
#pragma unroll
      for (int b = 0; b < NB; ++b) {
        acc[a][b] = MFMA16(af[a], bfr[b], acc[a][b]);
        if (SPLIT) {
          acc[a][b] = MFMA16(af[a], bfl[b], acc[a][b]);
          acc[a][b] = MFMA16(afl[a], bfr[b], acc[a][b]);
        }
      }
    __syncthreads();
  }

#pragma unroll
  for (int a = 0; a < 4; ++a)
#pragma unroll
    for (int b = 0; b < NB; ++b)
#pragma unroll
      for (int r = 0; r < 4; ++r) {
        int row = m0 + wr + a * 16 + g * 4 + r;
        int col = n0 + wc + b * 16 + li;
        float v = acc[a][b][r] + bias[col];
        if (GELU) v = 0.5f * v * (1.0f + erff(v * 0.70710678118654752f));
        if (OUT == 0) {
          ((float*)C0)[(size_t)row * Nc + col] = v;
        } else if (OUT == 1) {
          ((u16*)C0)[(size_t)row * Nc + col] = bf16_rtn(v);
        } else if (OUT == 2) {
          u16 hh, ll;
          splitf(v, hh, ll);
          size_t off = (((size_t)(row >> 11) * 16 + (col >> 6)) * 2048 + (row & 2047)) * 64 + (col & 63);
          ((u16*)C0)[off] = hh;
          ((u16*)C1)[off] = ll;
        } else {  // OUT == 3: packed K
          u16 hh, ll;
          splitf(v, hh, ll);
          int n = row >> 11, tt = row & 2047, kbb = tt >> 6, tr = tt & 63;
          int h = col >> 6, d = col & 63, ks = d >> 5, dc = d & 31;
          size_t base = ((size_t)(n * 16 + h) * 32 + kbb) * 8192;
          size_t oh = base + (size_t)ks * 2048 + tr * 32 + dc;
          ((u16*)C0)[oh] = hh;
          ((u16*)C0)[oh + 4096] = ll;
        }
      }
}

// ------------- flash attention, strictly-causal + [0,0], no 1/sqrt(d) -------------
// Q pre-split bf16 [n,h,T,64]; K pre-split packed per-64-block; V^T [n,h,64,T].
// grid: (qb remapped largest-first, H, N); block 256 (4 waves, 16 q-rows each).
// K double-buffered in LDS via global_load_lds; ONE barrier per K-block.
__global__ __launch_bounds__(256) void k_attn(
    const u16* __restrict__ Qh, const u16* __restrict__ Ql,
    const u16* __restrict__ Kpk, const u16* __restrict__ VT,
    u16* __restrict__ out) {
  const int T = 2048, HD = 64, H = 16, E = 1024;
  int qb = 31 - (int)blockIdx.x;  // largest workload first
  int h = blockIdx.y, n = blockIdx.z;
  __shared__ u16 KB[2][8192];     // [buf][hi slab 4096 | lo slab 4096]
  __shared__ u16 P[2][64][36];    // [ks][row][32+4 pad]
  int t = threadIdx.x, lane = t & 63, w = t >> 6;
  int li = lane & 15, g = lane >> 4;

  const size_t nh = (size_t)n * H + h;
  const u16* qhb = Qh + (nh * 2048 + (size_t)qb * 64) * 64;
  const u16* qlb = Ql + (nh * 2048 + (size_t)qb * 64) * 64;
  const u16* kblk = Kpk + nh * 32 * 8192;
  const u16* vtb = VT + nh * HD * T;

  bf16x8 qh[2], ql[2];
#pragma unroll
  for (int ks = 0; ks < 2; ++ks) {
    qh[ks] = *(const bf16x8*)&qhb[(w * 16 + li) * 64 + ks * 32 + g * 8];
    ql[ks] = *(const bf16x8*)&qlb[(w * 16 + li) * 64 + ks * 32 + g * 8];
  }

  // prologue: stage kb=0 into buf 0 (each wave stages its 4KB quarter)
#pragma unroll
  for (int j = 0; j < 4; ++j)
    gload16(kblk + (size_t)w * 2048 + j * 512 + lane * 8, &KB[0][w * 2048 + j * 512]);
  __syncthreads();

  float mr[4] = {-INFINITY, -INFINITY, -INFINITY, -INFINITY};
  float lr[4] = {0.f, 0.f, 0.f, 0.f};
  f32x4 O[4] = {};
  int cur = 0;

  for (int kb = 0; kb <= qb; ++kb) {
    // stage next K block early (hides under compute; drained at the barrier)
    if (kb < qb) {
      const u16* src = kblk + (size_t)(kb + 1) * 8192 + w * 2048 + lane * 8;
#pragma unroll
      for (int j = 0; j < 4; ++j)
        gload16(src + j * 512, &KB[cur ^ 1][w * 2048 + j * 512]);
    }

    f32x4 s[4] = {};
#pragma unroll
    for (int ks = 0; ks < 2; ++ks)
#pragma unroll
      for (int c = 0; c < 4; ++c) {
        bf16x8 kh = *(const bf16x8*)&KB[cur][ks * 2048 + (c * 16 + li) * 32 + g * 8];
        bf16x8 kl = *(const bf16x8*)&KB[cur][4096 + ks * 2048 + (c * 16 + li) * 32 + g * 8];
        s[c] = MFMA16(qh[ks], kh, s[c]);
        s[c] = MFMA16(qh[ks], kl, s[c]);
        s[c] = MFMA16(ql[ks], kh, s[c]);
      }

    if (kb == qb) {
#pragma unroll
      for (int c = 0; c < 4; ++c)
#pragma unroll
        for (int r = 0; r < 4; ++r) {
          int i = qb * 64 + w * 16 + g * 4 + r;
          int j = kb * 64 + c * 16 + li;
          if (!(j < i || (i == 0 && j == 0))) s[c][r] = -INFINITY;
        }
    }

    float ml[4];
#pragma unroll
    for (int r = 0; r < 4; ++r)
      ml[r] = fmaxf(fmaxf(s[0][r], s[1][r]), fmaxf(s[2][r], s[3][r]));
#pragma unroll
    for (int off = 1; off < 16; off <<= 1)
#pragma unroll
      for (int r = 0; r < 4; ++r) ml[r] = fmaxf(ml[r], __shfl_xor(ml[r], off, 16));

    float scl[4];
#pragma unroll
    for (int r = 0; r < 4; ++r) {
      float mn = fmaxf(mr[r], ml[r]);
      scl[r] = __expf(mr[r] - mn);
      mr[r] = mn;
    }
    float rs[4] = {0.f, 0.f, 0.f, 0.f};
#pragma unroll
    for (int c = 0; c < 4; ++c)
#pragma unroll
      for (int r = 0; r < 4; ++r) {
        float p = __expf(s[c][r] - mr[r]);
        s[c][r] = p;
        rs[r] += p;
      }
#pragma unroll
    for (int off = 1; off < 16; off <<= 1)
#pragma unroll
      for (int r = 0; r < 4; ++r) rs[r] += __shfl_xor(rs[r], off, 16);
#pragma unroll
    for (int r = 0; r < 4; ++r) lr[r] = lr[r] * scl[r] + rs[r];

    // P write/read is wave-local (each wave owns rows [w*16, w*16+16)) -> no barrier
#pragma unroll
    for (int c = 0; c < 4; ++c)
#pragma unroll
      for (int r = 0; r < 4; ++r) {
        O[c][r] *= scl[r];
        P[c >> 1][w * 16 + g * 4 + r][(c & 1) * 16 + li] = bf16_rtn(s[c][r]);
      }

#pragma unroll
    for (int ks = 0; ks < 2; ++ks) {
      bf16x8 pa = *(const bf16x8*)&P[ks][w * 16 + li][g * 8];
#pragma unroll
      for (int c = 0; c < 4; ++c) {
        bf16x8 vb = *(const bf16x8*)&vtb[(size_t)(c * 16 + li) * T + kb * 64 + ks * 32 + g * 8];
        O[c] = MFMA16(pa, vb, O[c]);
      }
    }
    __syncthreads();  // next buf staged + all waves done with KB[cur]
    cur ^= 1;
  }

#pragma unroll
  for (int c = 0; c < 4; ++c)
#pragma unroll
    for (int r = 0; r < 4; ++r) {
      float v = O[c][r] / lr[r];
      size_t row = (size_t)n * T + qb * 64 + w * 16 + g * 4 + r;
      out[row * E + h * HD + c * 16 + li] = bf16_rtn(v);
    }
}

// ---------------------------------------------------------------------------
extern "C" void kernel_launch(void* const* d_in, const int* in_sizes, int n_in,
                              void* d_out, int out_size, void* d_ws, size_t ws_size,
                              hipStream_t stream) {
  const float* kq = (const float*)d_in[0];
  const float* v = (const float*)d_in[1];
  const float* Wk = (const float*)d_in[2];
  const float* bk = (const float*)d_in[3];
  const float* Wq = (const float*)d_in[4];
  const float* bq = (const float*)d_in[5];
  const float* Wv = (const float*)d_in[6];
  const float* bv = (const float*)d_in[7];
  const float* W1 = (const float*)d_in[8];
  const float* b1 = (const float*)d_in[9];
  const float* W2 = (const float*)d_in[10];
  const float* b2 = (const float*)d_in[11];
  float* outp = (float*)d_out;

  char* ws = (char*)d_ws;
  u16* kq_hi = (u16*)(ws + 0);
  u16* kq_lo = (u16*)(ws + 8388608);
  u16* v_bf = (u16*)(ws + 16777216);
  u16* vv = (u16*)(ws + 25165824);
  u16* hbuf = (u16*)(ws + 0);  // aliases region A after attention
  u16* WkT_hi = (u16*)(ws + 33554432);
  u16* WkT_lo = (u16*)(ws + 35651584);
  u16* WqT_hi = (u16*)(ws + 37748736);
  u16* WqT_lo = (u16*)(ws + 39845888);
  u16* WvT = (u16*)(ws + 41943040);
  u16* W1T = (u16*)(ws + 44040192);
  u16* W2T = (u16*)(ws + 52428800);
  u16* Qh = (u16*)(ws + 60817408);
  u16* Ql = (u16*)(ws + 69206016);
  u16* Kpk = (u16*)(ws + 77594624);  // 16MB packed hi/lo
  u16* VT = (u16*)(ws + 94371840);
  u16* attn_o = (u16*)(ws + 102760448);
  // total: 111,149,056 bytes

  // --- conversions ---
  k_split<<<4096, 256, 0, stream>>>(kq, kq_hi, kq_lo, (4096 * 1024) / 4);
  k_conv<<<4096, 256, 0, stream>>>(v, v_bf, (4096 * 1024) / 4);
  k_tconv<1><<<dim3(32, 32), 256, 0, stream>>>(Wk, WkT_hi, WkT_lo, 1024, 1024);
  k_tconv<1><<<dim3(32, 32), 256, 0, stream>>>(Wq, WqT_hi, WqT_lo, 1024, 1024);
  k_tconv<0><<<dim3(32, 32), 256, 0, stream>>>(Wv, WvT, nullptr, 1024, 1024);
  k_tconv<0><<<dim3(128, 32), 256, 0, stream>>>(W1, W1T, nullptr, 1024, 4096);
  k_tconv<0><<<dim3(32, 128), 256, 0, stream>>>(W2, W2T, nullptr, 4096, 1024);

  // --- projections: BM=64 -> 512 blocks (2/CU) ---
  k_gemm<1, 0, 3, 64><<<dim3(8, 64), 256, 24576, stream>>>(kq_hi, kq_lo, WkT_hi, WkT_lo, bk, Kpk, nullptr, 4096, 1024, 1024);
  k_gemm<1, 0, 2, 64><<<dim3(8, 64), 256, 24576, stream>>>(kq_hi, kq_lo, WqT_hi, WqT_lo, bq, Qh, Ql, 4096, 1024, 1024);
  k_gemm<0, 0, 1, 64><<<dim3(8, 64), 256, 12288, stream>>>(v_bf, nullptr, WvT, nullptr, bv, vv, nullptr, 4096, 1024, 1024);

  // --- V transpose to [n,h,d,T] ---
  k_t16<<<dim3(32, 64, 2), 256, 0, stream>>>(vv, VT, 2048, 1024);

  // --- attention ---
  k_attn<<<dim3(32, 16, 2), 256, 0, stream>>>(Qh, Ql, Kpk, VT, attn_o);

  // --- FFN ---
  k_gemm<0, 1, 1, 128><<<dim3(32, 32), 256, 16384, stream>>>(attn_o, nullptr, W1T, nullptr, b1, hbuf, nullptr, 4096, 4096, 1024);
  k_gemm<0, 0, 0, 64><<<dim3(8, 64), 256, 12288, stream>>>(hbuf, nullptr, W2T, nullptr, b2, outp, nullptr, 4096, 1024, 4096);
}

// Round 5
// 357.593 us; speedup vs baseline: 2.0832x; 1.3663x over previous
//
#include <hip/hip_runtime.h>

typedef short bf16x8 __attribute__((ext_vector_type(8)));
typedef unsigned short u16x8 __attribute__((ext_vector_type(8)));
typedef float f32x4 __attribute__((ext_vector_type(4)));
typedef unsigned short u16;

#define MFMA16(a, b, c) __builtin_amdgcn_mfma_f32_16x16x32_bf16((a), (b), (c), 0, 0, 0)
// Explicit drain of outstanding global_load_lds before a barrier.
// Do NOT rely on __syncthreads() emitting vmcnt(0): cross-wave visibility of
// async LDS-destined loads needs this guaranteed (R4 post-timing race).
#define VMCNT0() asm volatile("s_waitcnt vmcnt(0)" ::: "memory")

__device__ __forceinline__ u16 bf16_rtn(float f) {
  unsigned u = __float_as_uint(f);
  u += 0x7fffu + ((u >> 16) & 1u);
  return (u16)(u >> 16);
}
__device__ __forceinline__ float bf16_to_f(u16 h) {
  return __uint_as_float(((unsigned)h) << 16);
}
__device__ __forceinline__ void splitf(float f, u16& hi, u16& lo) {
  hi = bf16_rtn(f);
  lo = bf16_rtn(f - bf16_to_f(hi));
}
__device__ __forceinline__ void gload16(const void* g, void* l) {
  __builtin_amdgcn_global_load_lds(
      (const __attribute__((address_space(1))) unsigned int*)g,
      (__attribute__((address_space(3))) unsigned int*)l, 16, 0, 0);
}

// ---------------- elementwise convert ----------------
__global__ void k_split(const float* __restrict__ in, u16* __restrict__ hi,
                        u16* __restrict__ lo, int n4) {
  int i = blockIdx.x * blockDim.x + threadIdx.x;
  if (i >= n4) return;
  float4 v = ((const float4*)in)[i];
  ushort4 h, l;
  splitf(v.x, h.x, l.x);
  splitf(v.y, h.y, l.y);
  splitf(v.z, h.z, l.z);
  splitf(v.w, h.w, l.w);
  ((ushort4*)hi)[i] = h;
  ((ushort4*)lo)[i] = l;
}

__global__ void k_conv(const float* __restrict__ in, u16* __restrict__ hi, int n4) {
  int i = blockIdx.x * blockDim.x + threadIdx.x;
  if (i >= n4) return;
  float4 v = ((const float4*)in)[i];
  ushort4 h;
  h.x = bf16_rtn(v.x);
  h.y = bf16_rtn(v.y);
  h.z = bf16_rtn(v.z);
  h.w = bf16_rtn(v.w);
  ((ushort4*)hi)[i] = h;
}

// ------------- transpose fp32 [R][C] -> bf16 [C][R] (hi / hi+lo) -------------
template <int SPLIT>
__global__ void k_tconv(const float* __restrict__ in, u16* __restrict__ hi,
                        u16* __restrict__ lo, int R, int C) {
  __shared__ float tile[32][33];
  int c0 = blockIdx.x * 32, r0 = blockIdx.y * 32;
  int tx = threadIdx.x & 31, ty = threadIdx.x >> 5;
#pragma unroll
  for (int i = 0; i < 4; ++i)
    tile[ty + i * 8][tx] = in[(size_t)(r0 + ty + i * 8) * C + c0 + tx];
  __syncthreads();
#pragma unroll
  for (int i = 0; i < 4; ++i) {
    float v = tile[tx][ty + i * 8];
    size_t o = (size_t)(c0 + ty + i * 8) * R + r0 + tx;
    if (SPLIT) {
      u16 h, l;
      splitf(v, h, l);
      hi[o] = h;
      lo[o] = l;
    } else {
      hi[o] = bf16_rtn(v);
    }
  }
}

// ------------- pack V into KV slabs -------------
// vv: bf16 [n][2048][1024]; per (n,h,kb) slab of 12288 u16:
//   [K hi 4096][K lo 4096][V 4096: phys = d*64 + (t&7) + 8*((t>>3) ^ (d&7))]
__global__ void k_vpack(const u16* __restrict__ vv, u16* __restrict__ KV) {
  int kb = blockIdx.x, h = blockIdx.y, n = blockIdx.z;
  __shared__ u16 tile[64][72];
  int tid = threadIdx.x;
  {
    int t = tid >> 2, dc = (tid & 3) * 16;
    const u16* src = vv + ((size_t)n * 2048 + kb * 64 + t) * 1024 + h * 64 + dc;
    *(u16x8*)&tile[t][dc] = *(const u16x8*)src;
    *(u16x8*)&tile[t][dc + 8] = *(const u16x8*)(src + 8);
  }
  __syncthreads();
  int d = tid >> 2, c2 = (tid & 3) * 2;
  size_t slab = (((size_t)n * 16 + h) * 32 + kb) * 12288 + 8192;
#pragma unroll
  for (int k = 0; k < 2; ++k) {
    int cc = c2 + k;
    u16x8 val;
#pragma unroll
    for (int i = 0; i < 8; ++i) val[i] = tile[cc * 8 + i][d];
    *(u16x8*)&KV[slab + d * 64 + ((cc ^ (d & 7)) << 3)] = val;
  }
}

// ------------- GEMM: C[M,Nc] = A[M,K] * B[Nc,K]^T + bias -------------
// OUT: 0 = fp32 row-major, 1 = bf16 row-major,
//      2 = split hi/lo head-major [n,h,t,d] (Q),
//      3 = split K into KV slabs (swizzled): per (n,h,kb) slab 12288 u16,
//          hi at ks*2048 + tr*32 + (dc&7) + 8*((dc>>3)^((tr>>1)&3)), lo at +4096
template <int SPLIT, int GELU, int OUT, int BM>
__global__ __launch_bounds__(256) void k_gemm(
    const u16* __restrict__ Ahi, const u16* __restrict__ Alo,
    const u16* __restrict__ Bhi, const u16* __restrict__ Blo,
    const float* __restrict__ bias, void* __restrict__ C0, void* __restrict__ C1,
    int M, int Nc, int K) {
  extern __shared__ u16 sm[];
  const int ASZ = BM * 32;
  u16* lA = sm;
  u16* lB = sm + ASZ;
  u16* lAl = SPLIT ? sm + ASZ + 4096 : (u16*)nullptr;
  u16* lBl = SPLIT ? sm + 2 * ASZ + 4096 : (u16*)nullptr;

  int t = threadIdx.x;
  int m0 = blockIdx.y * BM, n0 = blockIdx.x * 128;
  int lane = t & 63, w = t >> 6;
  const int wr = (BM == 128) ? (w >> 1) * 64 : 0;
  const int wc = (BM == 128) ? (w & 1) * 64 : w * 32;
  const int NB = (BM == 128) ? 4 : 2;
  int li = lane & 15, g = lane >> 4;
  int srow = lane >> 2, scol = (lane & 3) * 8;

  f32x4 acc[4][4] = {};

  const int nk = K >> 5;
  for (int kb = 0; kb < nk; ++kb) {
    int k0 = kb * 32;
#pragma unroll
    for (int c = 0; c < 2; ++c) {
      int row = w * 32 + c * 16 + srow;
      int ldso = w * 1024 + c * 512;
      gload16(Bhi + (size_t)(n0 + row) * K + k0 + scol, lB + ldso);
      if (SPLIT) gload16(Blo + (size_t)(n0 + row) * K + k0 + scol, lBl + ldso);
    }
    if (BM == 128) {
#pragma unroll
      for (int c = 0; c < 2; ++c) {
        int row = w * 32 + c * 16 + srow;
        int ldso = w * 1024 + c * 512;
        gload16(Ahi + (size_t)(m0 + row) * K + k0 + scol, lA + ldso);
        if (SPLIT) gload16(Alo + (size_t)(m0 + row) * K + k0 + scol, lAl + ldso);
      }
    } else {
      int row = w * 16 + srow;
      int ldso = w * 512;
      gload16(Ahi + (size_t)(m0 + row) * K + k0 + scol, lA + ldso);
      if (SPLIT) gload16(Alo + (size_t)(m0 + row) * K + k0 + scol, lAl + ldso);
    }
    VMCNT0();
    __syncthreads();
    bf16x8 af[4], bfr[4], afl[4], bfl[4];
#pragma unroll
    for (int i = 0; i < 4; ++i) {
      af[i] = *(const bf16x8*)&lA[(wr + i * 16 + li) * 32 + g * 8];
      if (SPLIT) afl[i] = *(const bf16x8*)&lAl[(wr + i * 16 + li) * 32 + g * 8];
    }
#pragma unroll
    for (int j = 0; j < NB; ++j) {
      bfr[j] = *(const bf16x8*)&lB[(wc + j * 16 + li) * 32 + g * 8];
      if (SPLIT) bfl[j] = *(const bf16x8*)&lBl[(wc + j * 16 + li) * 32 + g * 8];
    }
#pragma unroll
    for (int a = 0; a < 4; ++a)
#pragma unroll
      for (int b = 0; b < NB; ++b) {
        acc[a][b] = MFMA16(af[a], bfr[b], acc[a][b]);
        if (SPLIT) {
          acc[a][b] = MFMA16(af[a], bfl[b], acc[a][b]);
          acc[a][b] = MFMA16(afl[a], bfr[b], acc[a][b]);
        }
      }
    __syncthreads();
  }

#pragma unroll
  for (int a = 0; a < 4; ++a)
#pragma unroll
    for (int b = 0; b < NB; ++b)
#pragma unroll
      for (int r = 0; r < 4; ++r) {
        int row = m0 + wr + a * 16 + g * 4 + r;
        int col = n0 + wc + b * 16 + li;
        float v = acc[a][b][r] + bias[col];
        if (GELU) v = 0.5f * v * (1.0f + erff(v * 0.70710678118654752f));
        if (OUT == 0) {
          ((float*)C0)[(size_t)row * Nc + col] = v;
        } else if (OUT == 1) {
          ((u16*)C0)[(size_t)row * Nc + col] = bf16_rtn(v);
        } else if (OUT == 2) {
          u16 hh, ll;
          splitf(v, hh, ll);
          size_t off = (((size_t)(row >> 11) * 16 + (col >> 6)) * 2048 + (row & 2047)) * 64 + (col & 63);
          ((u16*)C0)[off] = hh;
          ((u16*)C1)[off] = ll;
        } else {  // OUT == 3: K into KV slabs, swizzled
          u16 hh, ll;
          splitf(v, hh, ll);
          int nn = row >> 11, tt = row & 2047, kbb = tt >> 6, tr = tt & 63;
          int hq = col >> 6, d = col & 63, ks = d >> 5, dc = d & 31;
          size_t base = (((size_t)nn * 16 + hq) * 32 + kbb) * 12288;
          size_t oh = base + ks * 2048 + tr * 32 + (dc & 7) + (((dc >> 3) ^ ((tr >> 1) & 3)) << 3);
          ((u16*)C0)[oh] = hh;
          ((u16*)C0)[oh + 4096] = ll;
        }
      }
}

// ------------- flash attention, strictly-causal + [0,0], no 1/sqrt(d) -------------
// Q pre-split [n,h,T,64]; K+V in swizzled KV slabs. QBLK=128, 8 waves, 512 thr.
// One barrier per K-block + explicit vmcnt(0) drain (cross-wave gload16 safety).
__global__ __launch_bounds__(512) void k_attn(
    const u16* __restrict__ Qh, const u16* __restrict__ Ql,
    const u16* __restrict__ KV, u16* __restrict__ out) {
  const int T = 2048, HD = 64, H = 16, E = 1024;
  int hc = blockIdx.x;
  int h = hc & 15, n = hc >> 4;
  int qq = 15 - (int)blockIdx.y;  // largest workload first; q rows [qq*128, qq*128+128)
  __shared__ u16 KB[2][12288];
  __shared__ u16 P[2][128][36];
  int t = threadIdx.x, lane = t & 63, w = t >> 6;
  int li = lane & 15, g = lane >> 4;

  const size_t nh = (size_t)n * H + h;
  const u16* qhb = Qh + (nh * 2048 + (size_t)qq * 128) * 64;
  const u16* qlb = Ql + (nh * 2048 + (size_t)qq * 128) * 64;
  const u16* kvb = KV + nh * 32 * 12288;

  bf16x8 qh[2], ql[2];
#pragma unroll
  for (int ks = 0; ks < 2; ++ks) {
    qh[ks] = *(const bf16x8*)&qhb[(w * 16 + li) * 64 + ks * 32 + g * 8];
    ql[ks] = *(const bf16x8*)&qlb[(w * 16 + li) * 64 + ks * 32 + g * 8];
  }

  // prologue: stage slab kb=0 (each wave copies 3 x 1KB)
#pragma unroll
  for (int j = 0; j < 3; ++j)
    gload16(kvb + (w * 3 + j) * 512 + lane * 8, &KB[0][(w * 3 + j) * 512]);
  VMCNT0();
  __syncthreads();

  float mr[4] = {-INFINITY, -INFINITY, -INFINITY, -INFINITY};
  float lr[4] = {0.f, 0.f, 0.f, 0.f};
  f32x4 O[4] = {};
  int cur = 0;
  const int nkb = 2 * qq + 2;

  for (int kb = 0; kb < nkb; ++kb) {
    if (kb + 1 < nkb) {
      const u16* src = kvb + (size_t)(kb + 1) * 12288 + (w * 3) * 512 + lane * 8;
#pragma unroll
      for (int j = 0; j < 3; ++j)
        gload16(src + j * 512, &KB[cur ^ 1][(w * 3 + j) * 512]);
    }

    f32x4 s[4] = {};
#pragma unroll
    for (int ks = 0; ks < 2; ++ks)
#pragma unroll
      for (int c = 0; c < 4; ++c) {
        int jr = c * 16 + li;
        int sw = (jr >> 1) & 3;
        bf16x8 kh = *(const bf16x8*)&KB[cur][ks * 2048 + jr * 32 + ((g ^ sw) << 3)];
        bf16x8 kl = *(const bf16x8*)&KB[cur][4096 + ks * 2048 + jr * 32 + ((g ^ sw) << 3)];
        s[c] = MFMA16(qh[ks], kh, s[c]);
        s[c] = MFMA16(qh[ks], kl, s[c]);
        s[c] = MFMA16(ql[ks], kh, s[c]);
      }

    if (kb >= 2 * qq) {  // diagonal or fully-masked tile
#pragma unroll
      for (int c = 0; c < 4; ++c)
#pragma unroll
        for (int r = 0; r < 4; ++r) {
          int i = qq * 128 + w * 16 + g * 4 + r;
          int j = kb * 64 + c * 16 + li;
          if (!(j < i || (i == 0 && j == 0))) s[c][r] = -INFINITY;
        }
    }

    float ml[4];
#pragma unroll
    for (int r = 0; r < 4; ++r)
      ml[r] = fmaxf(fmaxf(s[0][r], s[1][r]), fmaxf(s[2][r], s[3][r]));
#pragma unroll
    for (int off = 1; off < 16; off <<= 1)
#pragma unroll
      for (int r = 0; r < 4; ++r) ml[r] = fmaxf(ml[r], __shfl_xor(ml[r], off, 16));

    float scl[4];
#pragma unroll
    for (int r = 0; r < 4; ++r) {
      float mn = fmaxf(mr[r], ml[r]);
      scl[r] = __expf(mr[r] - mn);
      mr[r] = mn;
    }
    float rs[4] = {0.f, 0.f, 0.f, 0.f};
#pragma unroll
    for (int c = 0; c < 4; ++c)
#pragma unroll
      for (int r = 0; r < 4; ++r) {
        float p = __expf(s[c][r] - mr[r]);
        s[c][r] = p;
        rs[r] += p;
      }
#pragma unroll
    for (int off = 1; off < 16; off <<= 1)
#pragma unroll
      for (int r = 0; r < 4; ++r) rs[r] += __shfl_xor(rs[r], off, 16);
#pragma unroll
    for (int r = 0; r < 4; ++r) lr[r] = lr[r] * scl[r] + rs[r];

    // P is wave-local (wave owns rows [w*16, w*16+16)) -> no extra barrier
#pragma unroll
    for (int c = 0; c < 4; ++c)
#pragma unroll
      for (int r = 0; r < 4; ++r) {
        O[c][r] *= scl[r];
        P[c >> 1][w * 16 + g * 4 + r][(c & 1) * 16 + li] = bf16_rtn(s[c][r]);
      }

#pragma unroll
    for (int ks = 0; ks < 2; ++ks) {
      bf16x8 pa = *(const bf16x8*)&P[ks][w * 16 + li][g * 8];
#pragma unroll
      for (int c = 0; c < 4; ++c) {
        int d = c * 16 + li;
        int tc = ks * 4 + g;
        bf16x8 vb = *(const bf16x8*)&KB[cur][8192 + d * 64 + ((tc ^ (d & 7)) << 3)];
        O[c] = MFMA16(pa, vb, O[c]);
      }
    }
    VMCNT0();        // prefetch for KB[cur^1] fully landed before any wave proceeds
    __syncthreads();  // + all waves done reading KB[cur]
    cur ^= 1;
  }

#pragma unroll
  for (int c = 0; c < 4; ++c)
#pragma unroll
    for (int r = 0; r < 4; ++r) {
      float v = O[c][r] / lr[r];
      size_t row = (size_t)n * T + qq * 128 + w * 16 + g * 4 + r;
      out[row * E + h * HD + c * 16 + li] = bf16_rtn(v);
    }
}

// ---------------------------------------------------------------------------
extern "C" void kernel_launch(void* const* d_in, const int* in_sizes, int n_in,
                              void* d_out, int out_size, void* d_ws, size_t ws_size,
                              hipStream_t stream) {
  const float* kq = (const float*)d_in[0];
  const float* v = (const float*)d_in[1];
  const float* Wk = (const float*)d_in[2];
  const float* bk = (const float*)d_in[3];
  const float* Wq = (const float*)d_in[4];
  const float* bq = (const float*)d_in[5];
  const float* Wv = (const float*)d_in[6];
  const float* bv = (const float*)d_in[7];
  const float* W1 = (const float*)d_in[8];
  const float* b1 = (const float*)d_in[9];
  const float* W2 = (const float*)d_in[10];
  const float* b2 = (const float*)d_in[11];
  float* outp = (float*)d_out;

  char* ws = (char*)d_ws;
  u16* kq_hi = (u16*)(ws + 0);
  u16* kq_lo = (u16*)(ws + 8388608);
  u16* v_bf = (u16*)(ws + 16777216);
  u16* vv = (u16*)(ws + 25165824);
  u16* hbuf = (u16*)(ws + 0);  // aliases region A after attention
  u16* WkT_hi = (u16*)(ws + 33554432);
  u16* WkT_lo = (u16*)(ws + 35651584);
  u16* WqT_hi = (u16*)(ws + 37748736);
  u16* WqT_lo = (u16*)(ws + 39845888);
  u16* WvT = (u16*)(ws + 41943040);
  u16* W1T = (u16*)(ws + 44040192);
  u16* W2T = (u16*)(ws + 52428800);
  u16* Qh = (u16*)(ws + 60817408);
  u16* Ql = (u16*)(ws + 69206016);
  u16* KV = (u16*)(ws + 77594624);  // 24MB: 1024 slabs x 24KB (K hi/lo + V)
  u16* attn_o = (u16*)(ws + 102760448);
  // total: 111,149,056 bytes

  // --- conversions ---
  k_split<<<4096, 256, 0, stream>>>(kq, kq_hi, kq_lo, (4096 * 1024) / 4);
  k_conv<<<4096, 256, 0, stream>>>(v, v_bf, (4096 * 1024) / 4);
  k_tconv<1><<<dim3(32, 32), 256, 0, stream>>>(Wk, WkT_hi, WkT_lo, 1024, 1024);
  k_tconv<1><<<dim3(32, 32), 256, 0, stream>>>(Wq, WqT_hi, WqT_lo, 1024, 1024);
  k_tconv<0><<<dim3(32, 32), 256, 0, stream>>>(Wv, WvT, nullptr, 1024, 1024);
  k_tconv<0><<<dim3(128, 32), 256, 0, stream>>>(W1, W1T, nullptr, 1024, 4096);
  k_tconv<0><<<dim3(32, 128), 256, 0, stream>>>(W2, W2T, nullptr, 4096, 1024);

  // --- projections ---
  k_gemm<1, 0, 3, 64><<<dim3(8, 64), 256, 24576, stream>>>(kq_hi, kq_lo, WkT_hi, WkT_lo, bk, KV, nullptr, 4096, 1024, 1024);
  k_gemm<1, 0, 2, 64><<<dim3(8, 64), 256, 24576, stream>>>(kq_hi, kq_lo, WqT_hi, WqT_lo, bq, Qh, Ql, 4096, 1024, 1024);
  k_gemm<0, 0, 1, 64><<<dim3(8, 64), 256, 12288, stream>>>(v_bf, nullptr, WvT, nullptr, bv, vv, nullptr, 4096, 1024, 1024);

  // --- V pack into KV slabs ---
  k_vpack<<<dim3(32, 16, 2), 256, 0, stream>>>(vv, KV);

  // --- attention ---
  k_attn<<<dim3(32, 16), 512, 0, stream>>>(Qh, Ql, KV, attn_o);

  // --- FFN ---
  k_gemm<0, 1, 1, 128><<<dim3(32, 32), 256, 16384, stream>>>(attn_o, nullptr, W1T, nullptr, b1, hbuf, nullptr, 4096, 4096, 1024);
  k_gemm<0, 0, 0, 64><<<dim3(8, 64), 256, 12288, stream>>>(hbuf, nullptr, W2T, nullptr, b2, outp, nullptr, 4096, 1024, 4096);
}

// Round 6
// 351.511 us; speedup vs baseline: 2.1193x; 1.0173x over previous
//
#include <hip/hip_runtime.h>

typedef short bf16x8 __attribute__((ext_vector_type(8)));
typedef unsigned short u16x8 __attribute__((ext_vector_type(8)));
typedef float f32x4 __attribute__((ext_vector_type(4)));
typedef unsigned short u16;

#define MFMA16(a, b, c) __builtin_amdgcn_mfma_f32_16x16x32_bf16((a), (b), (c), 0, 0, 0)
// Explicit drain of outstanding global_load_lds before a barrier.
// __syncthreads() alone does NOT guarantee cross-wave visibility of async
// LDS-destined loads (R4 post-timing race; fixed in R5).
#define VMCNT0() asm volatile("s_waitcnt vmcnt(0)" ::: "memory")

__device__ __forceinline__ u16 bf16_rtn(float f) {
  unsigned u = __float_as_uint(f);
  u += 0x7fffu + ((u >> 16) & 1u);
  return (u16)(u >> 16);
}
__device__ __forceinline__ float bf16_to_f(u16 h) {
  return __uint_as_float(((unsigned)h) << 16);
}
__device__ __forceinline__ void splitf(float f, u16& hi, u16& lo) {
  hi = bf16_rtn(f);
  lo = bf16_rtn(f - bf16_to_f(hi));
}
__device__ __forceinline__ void gload16(const void* g, void* l) {
  __builtin_amdgcn_global_load_lds(
      (const __attribute__((address_space(1))) unsigned int*)g,
      (__attribute__((address_space(3))) unsigned int*)l, 16, 0, 0);
}

// ---------------- fused elementwise convert: kq -> hi/lo, v -> bf16 ----------------
__global__ void k_cvt(const float* __restrict__ a, const float* __restrict__ b,
                      u16* __restrict__ hi, u16* __restrict__ lo,
                      u16* __restrict__ vb) {
  int i = blockIdx.x * blockDim.x + threadIdx.x;
  const int N4 = 1 << 20;  // 4M elements / 4
  if (i < N4) {
    float4 v4 = ((const float4*)a)[i];
    ushort4 h, l;
    splitf(v4.x, h.x, l.x);
    splitf(v4.y, h.y, l.y);
    splitf(v4.z, h.z, l.z);
    splitf(v4.w, h.w, l.w);
    ((ushort4*)hi)[i] = h;
    ((ushort4*)lo)[i] = l;
  } else {
    int j = i - N4;
    float4 v4 = ((const float4*)b)[j];
    ushort4 h;
    h.x = bf16_rtn(v4.x);
    h.y = bf16_rtn(v4.y);
    h.z = bf16_rtn(v4.z);
    h.w = bf16_rtn(v4.w);
    ((ushort4*)vb)[j] = h;
  }
}

// ------------- transpose fp32 [R][C] -> bf16 [C][R] (hi / hi+lo) -------------
template <int SPLIT>
__global__ void k_tconv(const float* __restrict__ in, u16* __restrict__ hi,
                        u16* __restrict__ lo, int R, int C) {
  __shared__ float tile[32][33];
  int c0 = blockIdx.x * 32, r0 = blockIdx.y * 32;
  int tx = threadIdx.x & 31, ty = threadIdx.x >> 5;
#pragma unroll
  for (int i = 0; i < 4; ++i)
    tile[ty + i * 8][tx] = in[(size_t)(r0 + ty + i * 8) * C + c0 + tx];
  __syncthreads();
#pragma unroll
  for (int i = 0; i < 4; ++i) {
    float v = tile[tx][ty + i * 8];
    size_t o = (size_t)(c0 + ty + i * 8) * R + r0 + tx;
    if (SPLIT) {
      u16 h, l;
      splitf(v, h, l);
      hi[o] = h;
      lo[o] = l;
    } else {
      hi[o] = bf16_rtn(v);
    }
  }
}

// ------------- pack V into KV slabs -------------
// vv: bf16 [n][2048][1024]; per (n,h,kb) slab of 8192 u16:
//   [K hi 4096][V 4096: phys = d*64 + (t&7) + 8*((t>>3) ^ (d&7))]
__global__ void k_vpack(const u16* __restrict__ vv, u16* __restrict__ KV) {
  int kb = blockIdx.x, h = blockIdx.y, n = blockIdx.z;
  __shared__ u16 tile[64][72];
  int tid = threadIdx.x;
  {
    int t = tid >> 2, dc = (tid & 3) * 16;
    const u16* src = vv + ((size_t)n * 2048 + kb * 64 + t) * 1024 + h * 64 + dc;
    *(u16x8*)&tile[t][dc] = *(const u16x8*)src;
    *(u16x8*)&tile[t][dc + 8] = *(const u16x8*)(src + 8);
  }
  __syncthreads();
  int d = tid >> 2, c2 = (tid & 3) * 2;
  size_t slab = (((size_t)n * 16 + h) * 32 + kb) * 8192 + 4096;
#pragma unroll
  for (int k = 0; k < 2; ++k) {
    int cc = c2 + k;
    u16x8 val;
#pragma unroll
    for (int i = 0; i < 8; ++i) val[i] = tile[cc * 8 + i][d];
    *(u16x8*)&KV[slab + d * 64 + ((cc ^ (d & 7)) << 3)] = val;
  }
}

// ------------- GEMM: C[M,Nc] = A[M,K] * B[Nc,K]^T + bias -------------
// OUT: 0 = fp32 row-major, 1 = bf16 row-major,
//      2 = split hi/lo head-major [n,h,t,d] (Q),
//      3 = K hi only into KV slabs (swizzled): per (n,h,kb) slab 8192 u16,
//          hi at ks*2048 + tr*32 + (dc&7) + 8*((dc>>3)^((tr>>1)&3))
template <int SPLIT, int GELU, int OUT, int BM>
__global__ __launch_bounds__(256) void k_gemm(
    const u16* __restrict__ Ahi, const u16* __restrict__ Alo,
    const u16* __restrict__ Bhi, const u16* __restrict__ Blo,
    const float* __restrict__ bias, void* __restrict__ C0, void* __restrict__ C1,
    int M, int Nc, int K) {
  extern __shared__ u16 sm[];
  const int ASZ = BM * 32;
  u16* lA = sm;
  u16* lB = sm + ASZ;
  u16* lAl = SPLIT ? sm + ASZ + 4096 : (u16*)nullptr;
  u16* lBl = SPLIT ? sm + 2 * ASZ + 4096 : (u16*)nullptr;

  int t = threadIdx.x;
  int m0 = blockIdx.y * BM, n0 = blockIdx.x * 128;
  int lane = t & 63, w = t >> 6;
  const int wr = (BM == 128) ? (w >> 1) * 64 : 0;
  const int wc = (BM == 128) ? (w & 1) * 64 : w * 32;
  const int NB = (BM == 128) ? 4 : 2;
  int li = lane & 15, g = lane >> 4;
  int srow = lane >> 2, scol = (lane & 3) * 8;

  f32x4 acc[4][4] = {};

  const int nk = K >> 5;
  for (int kb = 0; kb < nk; ++kb) {
    int k0 = kb * 32;
#pragma unroll
    for (int c = 0; c < 2; ++c) {
      int row = w * 32 + c * 16 + srow;
      int ldso = w * 1024 + c * 512;
      gload16(Bhi + (size_t)(n0 + row) * K + k0 + scol, lB + ldso);
      if (SPLIT) gload16(Blo + (size_t)(n0 + row) * K + k0 + scol, lBl + ldso);
    }
    if (BM == 128) {
#pragma unroll
      for (int c = 0; c < 2; ++c) {
        int row = w * 32 + c * 16 + srow;
        int ldso = w * 1024 + c * 512;
        gload16(Ahi + (size_t)(m0 + row) * K + k0 + scol, lA + ldso);
        if (SPLIT) gload16(Alo + (size_t)(m0 + row) * K + k0 + scol, lAl + ldso);
      }
    } else {
      int row = w * 16 + srow;
      int ldso = w * 512;
      gload16(Ahi + (size_t)(m0 + row) * K + k0 + scol, lA + ldso);
      if (SPLIT) gload16(Alo + (size_t)(m0 + row) * K + k0 + scol, lAl + ldso);
    }
    VMCNT0();
    __syncthreads();
    bf16x8 af[4], bfr[4], afl[4], bfl[4];
#pragma unroll
    for (int i = 0; i < 4; ++i) {
      af[i] = *(const bf16x8*)&lA[(wr + i * 16 + li) * 32 + g * 8];
      if (SPLIT) afl[i] = *(const bf16x8*)&lAl[(wr + i * 16 + li) * 32 + g * 8];
    }
#pragma unroll
    for (int j = 0; j < NB; ++j) {
      bfr[j] = *(const bf16x8*)&lB[(wc + j * 16 + li) * 32 + g * 8];
      if (SPLIT) bfl[j] = *(const bf16x8*)&lBl[(wc + j * 16 + li) * 32 + g * 8];
    }
#pragma unroll
    for (int a = 0; a < 4; ++a)
#pragma unroll
      for (int b = 0; b < NB; ++b) {
        acc[a][b] = MFMA16(af[a], bfr[b], acc[a][b]);
        if (SPLIT) {
          acc[a][b] = MFMA16(af[a], bfl[b], acc[a][b]);
          acc[a][b] = MFMA16(afl[a], bfr[b], acc[a][b]);
        }
      }
    __syncthreads();
  }

#pragma unroll
  for (int a = 0; a < 4; ++a)
#pragma unroll
    for (int b = 0; b < NB; ++b)
#pragma unroll
      for (int r = 0; r < 4; ++r) {
        int row = m0 + wr + a * 16 + g * 4 + r;
        int col = n0 + wc + b * 16 + li;
        float v = acc[a][b][r] + bias[col];
        if (GELU) v = 0.5f * v * (1.0f + erff(v * 0.70710678118654752f));
        if (OUT == 0) {
          ((float*)C0)[(size_t)row * Nc + col] = v;
        } else if (OUT == 1) {
          ((u16*)C0)[(size_t)row * Nc + col] = bf16_rtn(v);
        } else if (OUT == 2) {
          u16 hh, ll;
          splitf(v, hh, ll);
          size_t off = (((size_t)(row >> 11) * 16 + (col >> 6)) * 2048 + (row & 2047)) * 64 + (col & 63);
          ((u16*)C0)[off] = hh;
          ((u16*)C1)[off] = ll;
        } else {  // OUT == 3: K hi into KV slabs, swizzled
          int nn = row >> 11, tt = row & 2047, kbb = tt >> 6, tr = tt & 63;
          int hq = col >> 6, d = col & 63, ks = d >> 5, dc = d & 31;
          size_t base = (((size_t)nn * 16 + hq) * 32 + kbb) * 8192;
          size_t oh = base + ks * 2048 + tr * 32 + (dc & 7) + (((dc >> 3) ^ ((tr >> 1) & 3)) << 3);
          ((u16*)C0)[oh] = bf16_rtn(v);
        }
      }
}

// ------------- flash attention, strictly-causal + [0,0], no 1/sqrt(d) -------------
// Q pre-split [n,h,T,64]; K(hi)+V in swizzled 16KB KV slabs. QBLK=128, 8 waves.
// 2-pass QK (qh*kh + ql*kh; K-lo dropped — K rounded once after split-precision
// projection, score err sigma ~0.008, softmax-damped). Defer-max (T13, THR=8).
__global__ __launch_bounds__(512) void k_attn(
    const u16* __restrict__ Qh, const u16* __restrict__ Ql,
    const u16* __restrict__ KV, u16* __restrict__ out) {
  const int T = 2048, HD = 64, H = 16, E = 1024;
  int hc = blockIdx.x;
  int h = hc & 15, n = hc >> 4;
  int qq = 15 - (int)blockIdx.y;  // largest workload first
  __shared__ u16 KB[2][8192];     // [buf][K hi 4096 | V 4096]
  __shared__ u16 P[2][128][36];
  int t = threadIdx.x, lane = t & 63, w = t >> 6;
  int li = lane & 15, g = lane >> 4;

  const size_t nh = (size_t)n * H + h;
  const u16* qhb = Qh + (nh * 2048 + (size_t)qq * 128) * 64;
  const u16* qlb = Ql + (nh * 2048 + (size_t)qq * 128) * 64;
  const u16* kvb = KV + nh * 32 * 8192;

  bf16x8 qh[2], ql[2];
#pragma unroll
  for (int ks = 0; ks < 2; ++ks) {
    qh[ks] = *(const bf16x8*)&qhb[(w * 16 + li) * 64 + ks * 32 + g * 8];
    ql[ks] = *(const bf16x8*)&qlb[(w * 16 + li) * 64 + ks * 32 + g * 8];
  }

  // prologue: stage slab kb=0 (each wave copies 2 x 1KB)
#pragma unroll
  for (int j = 0; j < 2; ++j)
    gload16(kvb + (w * 2 + j) * 512 + lane * 8, &KB[0][(w * 2 + j) * 512]);
  VMCNT0();
  __syncthreads();

  float mr[4] = {-INFINITY, -INFINITY, -INFINITY, -INFINITY};
  float lr[4] = {0.f, 0.f, 0.f, 0.f};
  f32x4 O[4] = {};
  int cur = 0;
  const int nkb = 2 * qq + 2;

  for (int kb = 0; kb < nkb; ++kb) {
    if (kb + 1 < nkb) {
      const u16* src = kvb + (size_t)(kb + 1) * 8192 + (w * 2) * 512 + lane * 8;
#pragma unroll
      for (int j = 0; j < 2; ++j)
        gload16(src + j * 512, &KB[cur ^ 1][(w * 2 + j) * 512]);
    }

    f32x4 s[4] = {};
#pragma unroll
    for (int ks = 0; ks < 2; ++ks)
#pragma unroll
      for (int c = 0; c < 4; ++c) {
        int jr = c * 16 + li;
        int sw = (jr >> 1) & 3;
        bf16x8 kh = *(const bf16x8*)&KB[cur][ks * 2048 + jr * 32 + ((g ^ sw) << 3)];
        s[c] = MFMA16(qh[ks], kh, s[c]);
        s[c] = MFMA16(ql[ks], kh, s[c]);
      }

    if (kb >= 2 * qq) {  // diagonal or fully-masked tile
#pragma unroll
      for (int c = 0; c < 4; ++c)
#pragma unroll
        for (int r = 0; r < 4; ++r) {
          int i = qq * 128 + w * 16 + g * 4 + r;
          int j = kb * 64 + c * 16 + li;
          if (!(j < i || (i == 0 && j == 0))) s[c][r] = -INFINITY;
        }
    }

    float ml[4];
#pragma unroll
    for (int r = 0; r < 4; ++r)
      ml[r] = fmaxf(fmaxf(s[0][r], s[1][r]), fmaxf(s[2][r], s[3][r]));
#pragma unroll
    for (int off = 1; off < 16; off <<= 1)
#pragma unroll
      for (int r = 0; r < 4; ++r) ml[r] = fmaxf(ml[r], __shfl_xor(ml[r], off, 16));

    // defer-max (T13): only rescale when the max grew past THR=8;
    // P values then bounded by e^8, fp32 accumulators have headroom.
    bool need = false;
#pragma unroll
    for (int r = 0; r < 4; ++r) need = need || (ml[r] > mr[r] + 8.0f);
    if (__any(need ? 1 : 0)) {
#pragma unroll
      for (int r = 0; r < 4; ++r) {
        float mn = fmaxf(mr[r], ml[r]);
        float scl = __expf(mr[r] - mn);
        mr[r] = mn;
        lr[r] *= scl;
#pragma unroll
        for (int c = 0; c < 4; ++c) O[c][r] *= scl;
      }
    }

    float rs[4] = {0.f, 0.f, 0.f, 0.f};
#pragma unroll
    for (int c = 0; c < 4; ++c)
#pragma unroll
      for (int r = 0; r < 4; ++r) {
        float p = __expf(s[c][r] - mr[r]);
        s[c][r] = p;
        rs[r] += p;
      }
#pragma unroll
    for (int off = 1; off < 16; off <<= 1)
#pragma unroll
      for (int r = 0; r < 4; ++r) rs[r] += __shfl_xor(rs[r], off, 16);
#pragma unroll
    for (int r = 0; r < 4; ++r) lr[r] += rs[r];

    // P is wave-local (wave owns rows [w*16, w*16+16)) -> no extra barrier
#pragma unroll
    for (int c = 0; c < 4; ++c)
#pragma unroll
      for (int r = 0; r < 4; ++r)
        P[c >> 1][w * 16 + g * 4 + r][(c & 1) * 16 + li] = bf16_rtn(s[c][r]);

#pragma unroll
    for (int ks = 0; ks < 2; ++ks) {
      bf16x8 pa = *(const bf16x8*)&P[ks][w * 16 + li][g * 8];
#pragma unroll
      for (int c = 0; c < 4; ++c) {
        int d = c * 16 + li;
        int tc = ks * 4 + g;
        bf16x8 vb = *(const bf16x8*)&KB[cur][4096 + d * 64 + ((tc ^ (d & 7)) << 3)];
        O[c] = MFMA16(pa, vb, O[c]);
      }
    }
    VMCNT0();         // prefetch for KB[cur^1] fully landed before any wave proceeds
    __syncthreads();  // + all waves done reading KB[cur]
    cur ^= 1;
  }

#pragma unroll
  for (int c = 0; c < 4; ++c)
#pragma unroll
    for (int r = 0; r < 4; ++r) {
      float v = O[c][r] / lr[r];
      size_t row = (size_t)n * T + qq * 128 + w * 16 + g * 4 + r;
      out[row * E + h * HD + c * 16 + li] = bf16_rtn(v);
    }
}

// ---------------------------------------------------------------------------
extern "C" void kernel_launch(void* const* d_in, const int* in_sizes, int n_in,
                              void* d_out, int out_size, void* d_ws, size_t ws_size,
                              hipStream_t stream) {
  const float* kq = (const float*)d_in[0];
  const float* v = (const float*)d_in[1];
  const float* Wk = (const float*)d_in[2];
  const float* bk = (const float*)d_in[3];
  const float* Wq = (const float*)d_in[4];
  const float* bq = (const float*)d_in[5];
  const float* Wv = (const float*)d_in[6];
  const float* bv = (const float*)d_in[7];
  const float* W1 = (const float*)d_in[8];
  const float* b1 = (const float*)d_in[9];
  const float* W2 = (const float*)d_in[10];
  const float* b2 = (const float*)d_in[11];
  float* outp = (float*)d_out;

  char* ws = (char*)d_ws;
  u16* kq_hi = (u16*)(ws + 0);
  u16* kq_lo = (u16*)(ws + 8388608);
  u16* v_bf = (u16*)(ws + 16777216);
  u16* vv = (u16*)(ws + 25165824);
  u16* hbuf = (u16*)(ws + 0);  // aliases region A after attention
  u16* WkT_hi = (u16*)(ws + 33554432);
  u16* WkT_lo = (u16*)(ws + 35651584);
  u16* WqT_hi = (u16*)(ws + 37748736);
  u16* WqT_lo = (u16*)(ws + 39845888);
  u16* WvT = (u16*)(ws + 41943040);
  u16* W1T = (u16*)(ws + 44040192);
  u16* W2T = (u16*)(ws + 52428800);
  u16* Qh = (u16*)(ws + 60817408);
  u16* Ql = (u16*)(ws + 69206016);
  u16* KV = (u16*)(ws + 77594624);  // 16MB: 1024 slabs x 16KB (K hi + V)
  u16* attn_o = (u16*)(ws + 102760448);
  // total: 111,149,056 bytes

  // --- conversions ---
  k_cvt<<<8192, 256, 0, stream>>>(kq, v, kq_hi, kq_lo, v_bf);
  k_tconv<1><<<dim3(32, 32), 256, 0, stream>>>(Wk, WkT_hi, WkT_lo, 1024, 1024);
  k_tconv<1><<<dim3(32, 32), 256, 0, stream>>>(Wq, WqT_hi, WqT_lo, 1024, 1024);
  k_tconv<0><<<dim3(32, 32), 256, 0, stream>>>(Wv, WvT, nullptr, 1024, 1024);
  k_tconv<0><<<dim3(128, 32), 256, 0, stream>>>(W1, W1T, nullptr, 1024, 4096);
  k_tconv<0><<<dim3(32, 128), 256, 0, stream>>>(W2, W2T, nullptr, 4096, 1024);

  // --- projections ---
  k_gemm<1, 0, 3, 64><<<dim3(8, 64), 256, 24576, stream>>>(kq_hi, kq_lo, WkT_hi, WkT_lo, bk, KV, nullptr, 4096, 1024, 1024);
  k_gemm<1, 0, 2, 64><<<dim3(8, 64), 256, 24576, stream>>>(kq_hi, kq_lo, WqT_hi, WqT_lo, bq, Qh, Ql, 4096, 1024, 1024);
  k_gemm<0, 0, 1, 64><<<dim3(8, 64), 256, 12288, stream>>>(v_bf, nullptr, WvT, nullptr, bv, vv, nullptr, 4096, 1024, 1024);

  // --- V pack into KV slabs ---
  k_vpack<<<dim3(32, 16, 2), 256, 0, stream>>>(vv, KV);

  // --- attention ---
  k_attn<<<dim3(32, 16), 512, 0, stream>>>(Qh, Ql, KV, attn_o);

  // --- FFN ---
  k_gemm<0, 1, 1, 128><<<dim3(32, 32), 256, 16384, stream>>>(attn_o, nullptr, W1T, nullptr, b1, hbuf, nullptr, 4096, 4096, 1024);
  k_gemm<0, 0, 0, 64><<<dim3(8, 64), 256, 12288, stream>>>(hbuf, nullptr, W2T, nullptr, b2, outp, nullptr, 4096, 1024, 4096);
}

// Round 7
// 320.995 us; speedup vs baseline: 2.3207x; 1.0951x over previous
//
#include <hip/hip_runtime.h>

typedef short bf16x8 __attribute__((ext_vector_type(8)));
typedef unsigned short u16x8 __attribute__((ext_vector_type(8)));
typedef float f32x4 __attribute__((ext_vector_type(4)));
typedef unsigned short u16;

#define MFMA16(a, b, c) __builtin_amdgcn_mfma_f32_16x16x32_bf16((a), (b), (c), 0, 0, 0)
// Explicit drain of outstanding global_load_lds before a barrier.
// __syncthreads() alone does NOT guarantee cross-wave visibility of async
// LDS-destined loads (R4 post-timing race; fixed in R5).
#define VMCNT0() asm volatile("s_waitcnt vmcnt(0)" ::: "memory")

__device__ __forceinline__ u16 bf16_rtn(float f) {
  unsigned u = __float_as_uint(f);
  u += 0x7fffu + ((u >> 16) & 1u);
  return (u16)(u >> 16);
}
__device__ __forceinline__ float bf16_to_f(u16 h) {
  return __uint_as_float(((unsigned)h) << 16);
}
__device__ __forceinline__ void splitf(float f, u16& hi, u16& lo) {
  hi = bf16_rtn(f);
  lo = bf16_rtn(f - bf16_to_f(hi));
}
__device__ __forceinline__ void gload16(const void* g, void* l) {
  __builtin_amdgcn_global_load_lds(
      (const __attribute__((address_space(1))) unsigned int*)g,
      (__attribute__((address_space(3))) unsigned int*)l, 16, 0, 0);
}

// ---------------- fused elementwise convert: kq -> hi/lo, v -> bf16 ----------------
__global__ void k_cvt(const float* __restrict__ a, const float* __restrict__ b,
                      u16* __restrict__ hi, u16* __restrict__ lo,
                      u16* __restrict__ vb) {
  int i = blockIdx.x * blockDim.x + threadIdx.x;
  const int N4 = 1 << 20;  // 4M elements / 4
  if (i < N4) {
    float4 v4 = ((const float4*)a)[i];
    ushort4 h, l;
    splitf(v4.x, h.x, l.x);
    splitf(v4.y, h.y, l.y);
    splitf(v4.z, h.z, l.z);
    splitf(v4.w, h.w, l.w);
    ((ushort4*)hi)[i] = h;
    ((ushort4*)lo)[i] = l;
  } else {
    int j = i - N4;
    float4 v4 = ((const float4*)b)[j];
    ushort4 h;
    h.x = bf16_rtn(v4.x);
    h.y = bf16_rtn(v4.y);
    h.z = bf16_rtn(v4.z);
    h.w = bf16_rtn(v4.w);
    ((ushort4*)vb)[j] = h;
  }
}

// ------------- transpose fp32 [R][C] -> bf16 [C][R] (hi / hi+lo) -------------
template <int SPLIT>
__global__ void k_tconv(const float* __restrict__ in, u16* __restrict__ hi,
                        u16* __restrict__ lo, int R, int C) {
  __shared__ float tile[32][33];
  int c0 = blockIdx.x * 32, r0 = blockIdx.y * 32;
  int tx = threadIdx.x & 31, ty = threadIdx.x >> 5;
#pragma unroll
  for (int i = 0; i < 4; ++i)
    tile[ty + i * 8][tx] = in[(size_t)(r0 + ty + i * 8) * C + c0 + tx];
  __syncthreads();
#pragma unroll
  for (int i = 0; i < 4; ++i) {
    float v = tile[tx][ty + i * 8];
    size_t o = (size_t)(c0 + ty + i * 8) * R + r0 + tx;
    if (SPLIT) {
      u16 h, l;
      splitf(v, h, l);
      hi[o] = h;
      lo[o] = l;
    } else {
      hi[o] = bf16_rtn(v);
    }
  }
}

// ------------- pack V into KV slabs -------------
// vv: bf16 [n][2048][1024]; per (n,h,kb) slab of 8192 u16:
//   [K hi 4096][V 4096: phys = d*64 + (t&7) + 8*((t>>3) ^ (d&7))]
__global__ void k_vpack(const u16* __restrict__ vv, u16* __restrict__ KV) {
  int kb = blockIdx.x, h = blockIdx.y, n = blockIdx.z;
  __shared__ u16 tile[64][72];
  int tid = threadIdx.x;
  {
    int t = tid >> 2, dc = (tid & 3) * 16;
    const u16* src = vv + ((size_t)n * 2048 + kb * 64 + t) * 1024 + h * 64 + dc;
    *(u16x8*)&tile[t][dc] = *(const u16x8*)src;
    *(u16x8*)&tile[t][dc + 8] = *(const u16x8*)(src + 8);
  }
  __syncthreads();
  int d = tid >> 2, c2 = (tid & 3) * 2;
  size_t slab = (((size_t)n * 16 + h) * 32 + kb) * 8192 + 4096;
#pragma unroll
  for (int k = 0; k < 2; ++k) {
    int cc = c2 + k;
    u16x8 val;
#pragma unroll
    for (int i = 0; i < 8; ++i) val[i] = tile[cc * 8 + i][d];
    *(u16x8*)&KV[slab + d * 64 + ((cc ^ (d & 7)) << 3)] = val;
  }
}

// ------------- GEMM: C[M,Nc] = A[M,K] * B[Nc,K]^T + bias -------------
// 128x128 tile, 4 waves, BK=32, double-buffered LDS: stage(kb+1) issued BEFORE
// compute(kb), single vmcnt(0)+barrier per K-step (attn-proven pattern).
// OUT: 0 = fp32 row-major, 1 = bf16 row-major,
//      4 = fused K|Q projection epilogue: col<1024 -> K bf16 into swizzled KV
//          slab; col>=1024 -> Q split hi/lo head-major [n,h,t,d].
template <int SPLIT, int GELU, int OUT>
__global__ __launch_bounds__(256) void k_gemm(
    const u16* __restrict__ Ahi, const u16* __restrict__ Alo,
    const u16* __restrict__ Bhi, const u16* __restrict__ Blo,
    const float* __restrict__ bias, const float* __restrict__ bias2,
    void* __restrict__ C0, void* __restrict__ C1, void* __restrict__ C2,
    int M, int Nc, int K) {
  extern __shared__ u16 sm[];
  const int BUFE = SPLIT ? 16384 : 8192;  // u16 per buffer: [A|B|(Al|Bl)]

  int t = threadIdx.x;
  int m0 = blockIdx.y * 128, n0 = blockIdx.x * 128;
  int lane = t & 63, w = t >> 6;
  int wr = (w >> 1) * 64, wc = (w & 1) * 64;
  int li = lane & 15, g = lane >> 4;
  int srow = lane >> 2, scol = (lane & 3) * 8;

  f32x4 acc[4][4] = {};
  const int nk = K >> 5;

  // prologue: stage kb=0 into buffer 0
#pragma unroll
  for (int c = 0; c < 2; ++c) {
    int row = w * 32 + c * 16 + srow;
    int ldso = w * 1024 + c * 512;
    gload16(Ahi + (size_t)(m0 + row) * K + scol, sm + ldso);
    gload16(Bhi + (size_t)(n0 + row) * K + scol, sm + 4096 + ldso);
    if (SPLIT) {
      gload16(Alo + (size_t)(m0 + row) * K + scol, sm + 8192 + ldso);
      gload16(Blo + (size_t)(n0 + row) * K + scol, sm + 12288 + ldso);
    }
  }
  VMCNT0();
  __syncthreads();

  int cur = 0;
  for (int kb = 0; kb < nk; ++kb) {
    // stage next K-slice early — lands under this step's ds_read+MFMA
    if (kb + 1 < nk) {
      int k0 = (kb + 1) * 32;
      int bo = (cur ^ 1) * BUFE;
#pragma unroll
      for (int c = 0; c < 2; ++c) {
        int row = w * 32 + c * 16 + srow;
        int ldso = bo + w * 1024 + c * 512;
        gload16(Ahi + (size_t)(m0 + row) * K + k0 + scol, sm + ldso);
        gload16(Bhi + (size_t)(n0 + row) * K + k0 + scol, sm + 4096 + ldso);
        if (SPLIT) {
          gload16(Alo + (size_t)(m0 + row) * K + k0 + scol, sm + 8192 + ldso);
          gload16(Blo + (size_t)(n0 + row) * K + k0 + scol, sm + 12288 + ldso);
        }
      }
    }

    const u16* lA = sm + cur * BUFE;
    bf16x8 af[4], bfr[4], afl[4], bfl[4];
#pragma unroll
    for (int i = 0; i < 4; ++i) {
      af[i] = *(const bf16x8*)&lA[(wr + i * 16 + li) * 32 + g * 8];
      bfr[i] = *(const bf16x8*)&lA[4096 + (wc + i * 16 + li) * 32 + g * 8];
      if (SPLIT) {
        afl[i] = *(const bf16x8*)&lA[8192 + (wr + i * 16 + li) * 32 + g * 8];
        bfl[i] = *(const bf16x8*)&lA[12288 + (wc + i * 16 + li) * 32 + g * 8];
      }
    }
#pragma unroll
    for (int a = 0; a < 4; ++a)
#pragma unroll
      for (int b = 0; b < 4; ++b) {
        acc[a][b] = MFMA16(af[a], bfr[b], acc[a][b]);
        if (SPLIT) {
          acc[a][b] = MFMA16(af[a], bfl[b], acc[a][b]);
          acc[a][b] = MFMA16(afl[a], bfr[b], acc[a][b]);
        }
      }
    VMCNT0();         // next buffer fully landed (cross-wave)
    __syncthreads();  // all waves done reading cur
    cur ^= 1;
  }

#pragma unroll
  for (int a = 0; a < 4; ++a)
#pragma unroll
    for (int b = 0; b < 4; ++b)
#pragma unroll
      for (int r = 0; r < 4; ++r) {
        int row = m0 + wr + a * 16 + g * 4 + r;
        int col = n0 + wc + b * 16 + li;
        float bb = (OUT == 4) ? (col < 1024 ? bias[col] : bias2[col - 1024])
                              : bias[col];
        float v = acc[a][b][r] + bb;
        if (GELU) v = 0.5f * v * (1.0f + erff(v * 0.70710678118654752f));
        if (OUT == 0) {
          ((float*)C0)[(size_t)row * Nc + col] = v;
        } else if (OUT == 1) {
          ((u16*)C0)[(size_t)row * Nc + col] = bf16_rtn(v);
        } else if (OUT == 4) {
          if (col < 1024) {  // K -> swizzled KV slab (single bf16 rounding)
            int nn = row >> 11, tt = row & 2047, kbb = tt >> 6, tr = tt & 63;
            int hq = col >> 6, d = col & 63, ks = d >> 5, dc = d & 31;
            size_t base = (((size_t)nn * 16 + hq) * 32 + kbb) * 8192;
            size_t oh = base + ks * 2048 + tr * 32 + (dc & 7) +
                        (((dc >> 3) ^ ((tr >> 1) & 3)) << 3);
            ((u16*)C0)[oh] = bf16_rtn(v);
          } else {  // Q -> split hi/lo head-major [n,h,t,d]
            int cq = col - 1024;
            u16 hh, ll;
            splitf(v, hh, ll);
            size_t off = (((size_t)(row >> 11) * 16 + (cq >> 6)) * 2048 + (row & 2047)) * 64 + (cq & 63);
            ((u16*)C1)[off] = hh;
            ((u16*)C2)[off] = ll;
          }
        }
      }
}

// ------------- flash attention, strictly-causal + [0,0], no 1/sqrt(d) -------------
// Q pre-split [n,h,T,64]; K(hi)+V in swizzled 16KB KV slabs. QBLK=128, 8 waves.
// 2-pass QK (qh*kh + ql*kh). Defer-max (T13, THR=8).
__global__ __launch_bounds__(512) void k_attn(
    const u16* __restrict__ Qh, const u16* __restrict__ Ql,
    const u16* __restrict__ KV, u16* __restrict__ out) {
  const int T = 2048, HD = 64, H = 16, E = 1024;
  int hc = blockIdx.x;
  int h = hc & 15, n = hc >> 4;
  int qq = 15 - (int)blockIdx.y;  // largest workload first
  __shared__ u16 KB[2][8192];     // [buf][K hi 4096 | V 4096]
  __shared__ u16 P[2][128][36];
  int t = threadIdx.x, lane = t & 63, w = t >> 6;
  int li = lane & 15, g = lane >> 4;

  const size_t nh = (size_t)n * H + h;
  const u16* qhb = Qh + (nh * 2048 + (size_t)qq * 128) * 64;
  const u16* qlb = Ql + (nh * 2048 + (size_t)qq * 128) * 64;
  const u16* kvb = KV + nh * 32 * 8192;

  bf16x8 qh[2], ql[2];
#pragma unroll
  for (int ks = 0; ks < 2; ++ks) {
    qh[ks] = *(const bf16x8*)&qhb[(w * 16 + li) * 64 + ks * 32 + g * 8];
    ql[ks] = *(const bf16x8*)&qlb[(w * 16 + li) * 64 + ks * 32 + g * 8];
  }

  // prologue: stage slab kb=0 (each wave copies 2 x 1KB)
#pragma unroll
  for (int j = 0; j < 2; ++j)
    gload16(kvb + (w * 2 + j) * 512 + lane * 8, &KB[0][(w * 2 + j) * 512]);
  VMCNT0();
  __syncthreads();

  float mr[4] = {-INFINITY, -INFINITY, -INFINITY, -INFINITY};
  float lr[4] = {0.f, 0.f, 0.f, 0.f};
  f32x4 O[4] = {};
  int cur = 0;
  const int nkb = 2 * qq + 2;

  for (int kb = 0; kb < nkb; ++kb) {
    if (kb + 1 < nkb) {
      const u16* src = kvb + (size_t)(kb + 1) * 8192 + (w * 2) * 512 + lane * 8;
#pragma unroll
      for (int j = 0; j < 2; ++j)
        gload16(src + j * 512, &KB[cur ^ 1][(w * 2 + j) * 512]);
    }

    f32x4 s[4] = {};
#pragma unroll
    for (int ks = 0; ks < 2; ++ks)
#pragma unroll
      for (int c = 0; c < 4; ++c) {
        int jr = c * 16 + li;
        int sw = (jr >> 1) & 3;
        bf16x8 kh = *(const bf16x8*)&KB[cur][ks * 2048 + jr * 32 + ((g ^ sw) << 3)];
        s[c] = MFMA16(qh[ks], kh, s[c]);
        s[c] = MFMA16(ql[ks], kh, s[c]);
      }

    if (kb >= 2 * qq) {  // diagonal or fully-masked tile
#pragma unroll
      for (int c = 0; c < 4; ++c)
#pragma unroll
        for (int r = 0; r < 4; ++r) {
          int i = qq * 128 + w * 16 + g * 4 + r;
          int j = kb * 64 + c * 16 + li;
          if (!(j < i || (i == 0 && j == 0))) s[c][r] = -INFINITY;
        }
    }

    float ml[4];
#pragma unroll
    for (int r = 0; r < 4; ++r)
      ml[r] = fmaxf(fmaxf(s[0][r], s[1][r]), fmaxf(s[2][r], s[3][r]));
#pragma unroll
    for (int off = 1; off < 16; off <<= 1)
#pragma unroll
      for (int r = 0; r < 4; ++r) ml[r] = fmaxf(ml[r], __shfl_xor(ml[r], off, 16));

    // defer-max (T13): only rescale when the max grew past THR=8;
    // P values then bounded by e^8, fp32 accumulators have headroom.
    bool need = false;
#pragma unroll
    for (int r = 0; r < 4; ++r) need = need || (ml[r] > mr[r] + 8.0f);
    if (__any(need ? 1 : 0)) {
#pragma unroll
      for (int r = 0; r < 4; ++r) {
        float mn = fmaxf(mr[r], ml[r]);
        float scl = __expf(mr[r] - mn);
        mr[r] = mn;
        lr[r] *= scl;
#pragma unroll
        for (int c = 0; c < 4; ++c) O[c][r] *= scl;
      }
    }

    float rs[4] = {0.f, 0.f, 0.f, 0.f};
#pragma unroll
    for (int c = 0; c < 4; ++c)
#pragma unroll
      for (int r = 0; r < 4; ++r) {
        float p = __expf(s[c][r] - mr[r]);
        s[c][r] = p;
        rs[r] += p;
      }
#pragma unroll
    for (int off = 1; off < 16; off <<= 1)
#pragma unroll
      for (int r = 0; r < 4; ++r) rs[r] += __shfl_xor(rs[r], off, 16);
#pragma unroll
    for (int r = 0; r < 4; ++r) lr[r] += rs[r];

    // P is wave-local (wave owns rows [w*16, w*16+16)) -> no extra barrier
#pragma unroll
    for (int c = 0; c < 4; ++c)
#pragma unroll
      for (int r = 0; r < 4; ++r)
        P[c >> 1][w * 16 + g * 4 + r][(c & 1) * 16 + li] = bf16_rtn(s[c][r]);

#pragma unroll
    for (int ks = 0; ks < 2; ++ks) {
      bf16x8 pa = *(const bf16x8*)&P[ks][w * 16 + li][g * 8];
#pragma unroll
      for (int c = 0; c < 4; ++c) {
        int d = c * 16 + li;
        int tc = ks * 4 + g;
        bf16x8 vb = *(const bf16x8*)&KB[cur][4096 + d * 64 + ((tc ^ (d & 7)) << 3)];
        O[c] = MFMA16(pa, vb, O[c]);
      }
    }
    VMCNT0();         // prefetch for KB[cur^1] fully landed before any wave proceeds
    __syncthreads();  // + all waves done reading KB[cur]
    cur ^= 1;
  }

#pragma unroll
  for (int c = 0; c < 4; ++c)
#pragma unroll
    for (int r = 0; r < 4; ++r) {
      float v = O[c][r] / lr[r];
      size_t row = (size_t)n * T + qq * 128 + w * 16 + g * 4 + r;
      out[row * E + h * HD + c * 16 + li] = bf16_rtn(v);
    }
}

// ---------------------------------------------------------------------------
extern "C" void kernel_launch(void* const* d_in, const int* in_sizes, int n_in,
                              void* d_out, int out_size, void* d_ws, size_t ws_size,
                              hipStream_t stream) {
  const float* kq = (const float*)d_in[0];
  const float* v = (const float*)d_in[1];
  const float* Wk = (const float*)d_in[2];
  const float* bk = (const float*)d_in[3];
  const float* Wq = (const float*)d_in[4];
  const float* bq = (const float*)d_in[5];
  const float* Wv = (const float*)d_in[6];
  const float* bv = (const float*)d_in[7];
  const float* W1 = (const float*)d_in[8];
  const float* b1 = (const float*)d_in[9];
  const float* W2 = (const float*)d_in[10];
  const float* b2 = (const float*)d_in[11];
  float* outp = (float*)d_out;

  char* ws = (char*)d_ws;
  u16* kq_hi = (u16*)(ws + 0);
  u16* kq_lo = (u16*)(ws + 8388608);
  u16* v_bf = (u16*)(ws + 16777216);
  u16* vv = (u16*)(ws + 25165824);
  u16* hbuf = (u16*)(ws + 0);  // aliases region A after attention
  u16* WkqT_hi = (u16*)(ws + 33554432);  // 4MB: [WkT rows 0-1023 | WqT rows 1024-2047]
  u16* WkqT_lo = (u16*)(ws + 37748736);  // 4MB
  u16* WvT = (u16*)(ws + 41943040);
  u16* W1T = (u16*)(ws + 44040192);
  u16* W2T = (u16*)(ws + 52428800);
  u16* Qh = (u16*)(ws + 60817408);
  u16* Ql = (u16*)(ws + 69206016);
  u16* KV = (u16*)(ws + 77594624);  // 16MB: 1024 slabs x 16KB (K hi + V)
  u16* attn_o = (u16*)(ws + 102760448);
  // total: 111,149,056 bytes

  // --- conversions ---
  k_cvt<<<8192, 256, 0, stream>>>(kq, v, kq_hi, kq_lo, v_bf);
  k_tconv<1><<<dim3(32, 32), 256, 0, stream>>>(Wk, WkqT_hi, WkqT_lo, 1024, 1024);
  k_tconv<1><<<dim3(32, 32), 256, 0, stream>>>(Wq, WkqT_hi + (1 << 20), WkqT_lo + (1 << 20), 1024, 1024);
  k_tconv<0><<<dim3(32, 32), 256, 0, stream>>>(Wv, WvT, nullptr, 1024, 1024);
  k_tconv<0><<<dim3(128, 32), 256, 0, stream>>>(W1, W1T, nullptr, 1024, 4096);
  k_tconv<0><<<dim3(32, 128), 256, 0, stream>>>(W2, W2T, nullptr, 4096, 1024);

  // --- fused K|Q projection (split-precision, dbuf) ---
  k_gemm<1, 0, 4><<<dim3(16, 32), 256, 65536, stream>>>(
      kq_hi, kq_lo, WkqT_hi, WkqT_lo, bk, bq, KV, Qh, Ql, 4096, 2048, 1024);
  // --- V projection ---
  k_gemm<0, 0, 1><<<dim3(8, 32), 256, 32768, stream>>>(
      v_bf, nullptr, WvT, nullptr, bv, nullptr, vv, nullptr, nullptr, 4096, 1024, 1024);

  // --- V pack into KV slabs ---
  k_vpack<<<dim3(32, 16, 2), 256, 0, stream>>>(vv, KV);

  // --- attention ---
  k_attn<<<dim3(32, 16), 512, 0, stream>>>(Qh, Ql, KV, attn_o);

  // --- FFN ---
  k_gemm<0, 1, 1><<<dim3(32, 32), 256, 32768, stream>>>(
      attn_o, nullptr, W1T, nullptr, b1, nullptr, hbuf, nullptr, nullptr, 4096, 4096, 1024);
  k_gemm<0, 0, 0><<<dim3(8, 32), 256, 32768, stream>>>(
      hbuf, nullptr, W2T, nullptr, b2, nullptr, outp, nullptr, nullptr, 4096, 1024, 4096);
}

// Round 8
// 287.197 us; speedup vs baseline: 2.5939x; 1.1177x over previous
//
#include <hip/hip_runtime.h>

typedef short bf16x8 __attribute__((ext_vector_type(8)));
typedef unsigned short u16x8 __attribute__((ext_vector_type(8)));
typedef float f32x4 __attribute__((ext_vector_type(4)));
typedef unsigned short u16;

#define MFMA16(a, b, c) __builtin_amdgcn_mfma_f32_16x16x32_bf16((a), (b), (c), 0, 0, 0)
// Explicit drain of outstanding global_load_lds before a barrier.
// __syncthreads() alone does NOT guarantee cross-wave visibility of async
// LDS-destined loads (R4 post-timing race; fixed in R5).
#define VMCNT0() asm volatile("s_waitcnt vmcnt(0)" ::: "memory")

__device__ __forceinline__ u16 bf16_rtn(float f) {
  unsigned u = __float_as_uint(f);
  u += 0x7fffu + ((u >> 16) & 1u);
  return (u16)(u >> 16);
}
__device__ __forceinline__ float bf16_to_f(u16 h) {
  return __uint_as_float(((unsigned)h) << 16);
}
__device__ __forceinline__ void splitf(float f, u16& hi, u16& lo) {
  hi = bf16_rtn(f);
  lo = bf16_rtn(f - bf16_to_f(hi));
}
__device__ __forceinline__ void gload16(const void* g, void* l) {
  __builtin_amdgcn_global_load_lds(
      (const __attribute__((address_space(1))) unsigned int*)g,
      (__attribute__((address_space(3))) unsigned int*)l, 16, 0, 0);
}
// D = 2^x (v_exp_f32). exp(S) computed as 2^(S*log2e) with the log2e factor
// folded into the Q projection epilogue. v_exp(-inf) = 0 handles the mask.
__device__ __forceinline__ float exp2_hw(float x) {
  float r;
  asm("v_exp_f32 %0, %1" : "=v"(r) : "v"(x));
  return r;
}

// ---------------- fused elementwise convert: kq -> hi/lo, v -> bf16 ----------------
__global__ void k_cvt(const float* __restrict__ a, const float* __restrict__ b,
                      u16* __restrict__ hi, u16* __restrict__ lo,
                      u16* __restrict__ vb) {
  int i = blockIdx.x * blockDim.x + threadIdx.x;
  const int N4 = 1 << 20;  // 4M elements / 4
  if (i < N4) {
    float4 v4 = ((const float4*)a)[i];
    ushort4 h, l;
    splitf(v4.x, h.x, l.x);
    splitf(v4.y, h.y, l.y);
    splitf(v4.z, h.z, l.z);
    splitf(v4.w, h.w, l.w);
    ((ushort4*)hi)[i] = h;
    ((ushort4*)lo)[i] = l;
  } else {
    int j = i - N4;
    float4 v4 = ((const float4*)b)[j];
    ushort4 h;
    h.x = bf16_rtn(v4.x);
    h.y = bf16_rtn(v4.y);
    h.z = bf16_rtn(v4.z);
    h.w = bf16_rtn(v4.w);
    ((ushort4*)vb)[j] = h;
  }
}

// ------------- transpose fp32 [R][C] -> bf16 [C][R] (hi / hi+lo) -------------
template <int SPLIT>
__global__ void k_tconv(const float* __restrict__ in, u16* __restrict__ hi,
                        u16* __restrict__ lo, int R, int C) {
  __shared__ float tile[32][33];
  int c0 = blockIdx.x * 32, r0 = blockIdx.y * 32;
  int tx = threadIdx.x & 31, ty = threadIdx.x >> 5;
#pragma unroll
  for (int i = 0; i < 4; ++i)
    tile[ty + i * 8][tx] = in[(size_t)(r0 + ty + i * 8) * C + c0 + tx];
  __syncthreads();
#pragma unroll
  for (int i = 0; i < 4; ++i) {
    float v = tile[tx][ty + i * 8];
    size_t o = (size_t)(c0 + ty + i * 8) * R + r0 + tx;
    if (SPLIT) {
      u16 h, l;
      splitf(v, h, l);
      hi[o] = h;
      lo[o] = l;
    } else {
      hi[o] = bf16_rtn(v);
    }
  }
}

// ------------- GEMM: C[M,Nc] = A[M,K] * B[Nc,K]^T + bias -------------
// 128x128 tile, 4 waves, BK=32, double-buffered LDS: stage(kb+1) issued BEFORE
// compute(kb), single vmcnt(0)+barrier per K-step.
// OUT: 0 = fp32 row-major, 1 = bf16 row-major,
//      4 = fused K|Q projection epilogue: col<1024 -> K bf16 into swizzled KV
//          slab; col>=1024 -> Q (pre-scaled by log2e) split hi/lo [n,h,t,d].
//      5 = V into swizzled KV slab V-section (replaces separate pack kernel).
template <int SPLIT, int GELU, int OUT>
__global__ __launch_bounds__(256) void k_gemm(
    const u16* __restrict__ Ahi, const u16* __restrict__ Alo,
    const u16* __restrict__ Bhi, const u16* __restrict__ Blo,
    const float* __restrict__ bias, const float* __restrict__ bias2,
    void* __restrict__ C0, void* __restrict__ C1, void* __restrict__ C2,
    int M, int Nc, int K) {
  extern __shared__ u16 sm[];
  const int BUFE = SPLIT ? 16384 : 8192;  // u16 per buffer: [A|B|(Al|Bl)]

  int t = threadIdx.x;
  int m0 = blockIdx.y * 128, n0 = blockIdx.x * 128;
  int lane = t & 63, w = t >> 6;
  int wr = (w >> 1) * 64, wc = (w & 1) * 64;
  int li = lane & 15, g = lane >> 4;
  int srow = lane >> 2, scol = (lane & 3) * 8;

  f32x4 acc[4][4] = {};
  const int nk = K >> 5;

  // prologue: stage kb=0 into buffer 0
#pragma unroll
  for (int c = 0; c < 2; ++c) {
    int row = w * 32 + c * 16 + srow;
    int ldso = w * 1024 + c * 512;
    gload16(Ahi + (size_t)(m0 + row) * K + scol, sm + ldso);
    gload16(Bhi + (size_t)(n0 + row) * K + scol, sm + 4096 + ldso);
    if (SPLIT) {
      gload16(Alo + (size_t)(m0 + row) * K + scol, sm + 8192 + ldso);
      gload16(Blo + (size_t)(n0 + row) * K + scol, sm + 12288 + ldso);
    }
  }
  VMCNT0();
  __syncthreads();

  int cur = 0;
  for (int kb = 0; kb < nk; ++kb) {
    // stage next K-slice early — lands under this step's ds_read+MFMA
    if (kb + 1 < nk) {
      int k0 = (kb + 1) * 32;
      int bo = (cur ^ 1) * BUFE;
#pragma unroll
      for (int c = 0; c < 2; ++c) {
        int row = w * 32 + c * 16 + srow;
        int ldso = bo + w * 1024 + c * 512;
        gload16(Ahi + (size_t)(m0 + row) * K + k0 + scol, sm + ldso);
        gload16(Bhi + (size_t)(n0 + row) * K + k0 + scol, sm + 4096 + ldso);
        if (SPLIT) {
          gload16(Alo + (size_t)(m0 + row) * K + k0 + scol, sm + 8192 + ldso);
          gload16(Blo + (size_t)(n0 + row) * K + k0 + scol, sm + 12288 + ldso);
        }
      }
    }

    const u16* lA = sm + cur * BUFE;
    bf16x8 af[4], bfr[4], afl[4], bfl[4];
#pragma unroll
    for (int i = 0; i < 4; ++i) {
      af[i] = *(const bf16x8*)&lA[(wr + i * 16 + li) * 32 + g * 8];
      bfr[i] = *(const bf16x8*)&lA[4096 + (wc + i * 16 + li) * 32 + g * 8];
      if (SPLIT) {
        afl[i] = *(const bf16x8*)&lA[8192 + (wr + i * 16 + li) * 32 + g * 8];
        bfl[i] = *(const bf16x8*)&lA[12288 + (wc + i * 16 + li) * 32 + g * 8];
      }
    }
#pragma unroll
    for (int a = 0; a < 4; ++a)
#pragma unroll
      for (int b = 0; b < 4; ++b) {
        acc[a][b] = MFMA16(af[a], bfr[b], acc[a][b]);
        if (SPLIT) {
          acc[a][b] = MFMA16(af[a], bfl[b], acc[a][b]);
          acc[a][b] = MFMA16(afl[a], bfr[b], acc[a][b]);
        }
      }
    VMCNT0();         // next buffer fully landed (cross-wave)
    __syncthreads();  // all waves done reading cur
    cur ^= 1;
  }

#pragma unroll
  for (int a = 0; a < 4; ++a)
#pragma unroll
    for (int b = 0; b < 4; ++b)
#pragma unroll
      for (int r = 0; r < 4; ++r) {
        int row = m0 + wr + a * 16 + g * 4 + r;
        int col = n0 + wc + b * 16 + li;
        float bb = (OUT == 4) ? (col < 1024 ? bias[col] : bias2[col - 1024])
                              : bias[col];
        float v = acc[a][b][r] + bb;
        if (GELU) v = 0.5f * v * (1.0f + erff(v * 0.70710678118654752f));
        if (OUT == 0) {
          ((float*)C0)[(size_t)row * Nc + col] = v;
        } else if (OUT == 1) {
          ((u16*)C0)[(size_t)row * Nc + col] = bf16_rtn(v);
        } else if (OUT == 4) {
          if (col < 1024) {  // K -> swizzled KV slab (single bf16 rounding)
            int nn = row >> 11, tt = row & 2047, kbb = tt >> 6, tr = tt & 63;
            int hq = col >> 6, d = col & 63, ks = d >> 5, dc = d & 31;
            size_t base = (((size_t)nn * 16 + hq) * 32 + kbb) * 8192;
            size_t oh = base + ks * 2048 + tr * 32 + (dc & 7) +
                        (((dc >> 3) ^ ((tr >> 1) & 3)) << 3);
            ((u16*)C0)[oh] = bf16_rtn(v);
          } else {  // Q (pre-scaled by log2e) -> split hi/lo head-major
            int cq = col - 1024;
            float vq = v * 1.4426950408889634f;
            u16 hh, ll;
            splitf(vq, hh, ll);
            size_t off = (((size_t)(row >> 11) * 16 + (cq >> 6)) * 2048 + (row & 2047)) * 64 + (cq & 63);
            ((u16*)C1)[off] = hh;
            ((u16*)C2)[off] = ll;
          }
        } else if (OUT == 5) {  // V -> swizzled KV slab V-section
          int nn = row >> 11, tt = row & 2047, kbb = tt >> 6, tr = tt & 63;
          int hq = col >> 6, d = col & 63;
          size_t base = (((size_t)nn * 16 + hq) * 32 + kbb) * 8192 + 4096;
          size_t ov = base + d * 64 + (tr & 7) + (((tr >> 3) ^ (d & 7)) << 3);
          ((u16*)C0)[ov] = bf16_rtn(v);
        }
      }
}

// ------------- flash attention, strictly-causal + [0,0], no 1/sqrt(d) -------------
// Q pre-split+log2e-scaled [n,h,T,64]; K(hi)+V in swizzled 16KB KV slabs.
// QBLK=128, 8 waves. UNNORMALIZED softmax: scores bounded (|S|<~50 << 88), so
// no running max, no rescale, NO cross-lane ops in the loop — l accumulated
// per-lane, reduced once at the end. P = 2^(S') via v_exp_f32.
__global__ __launch_bounds__(512) void k_attn(
    const u16* __restrict__ Qh, const u16* __restrict__ Ql,
    const u16* __restrict__ KV, u16* __restrict__ out) {
  const int T = 2048, HD = 64, H = 16, E = 1024;
  int hc = blockIdx.x;
  int h = hc & 15, n = hc >> 4;
  int qq = 15 - (int)blockIdx.y;  // largest workload first
  __shared__ u16 KB[2][8192];     // [buf][K hi 4096 | V 4096]
  __shared__ u16 P[2][128][36];
  int t = threadIdx.x, lane = t & 63, w = t >> 6;
  int li = lane & 15, g = lane >> 4;

  const size_t nh = (size_t)n * H + h;
  const u16* qhb = Qh + (nh * 2048 + (size_t)qq * 128) * 64;
  const u16* qlb = Ql + (nh * 2048 + (size_t)qq * 128) * 64;
  const u16* kvb = KV + nh * 32 * 8192;

  bf16x8 qh[2], ql[2];
#pragma unroll
  for (int ks = 0; ks < 2; ++ks) {
    qh[ks] = *(const bf16x8*)&qhb[(w * 16 + li) * 64 + ks * 32 + g * 8];
    ql[ks] = *(const bf16x8*)&qlb[(w * 16 + li) * 64 + ks * 32 + g * 8];
  }

  // prologue: stage slab kb=0 (each wave copies 2 x 1KB)
#pragma unroll
  for (int j = 0; j < 2; ++j)
    gload16(kvb + (w * 2 + j) * 512 + lane * 8, &KB[0][(w * 2 + j) * 512]);
  VMCNT0();
  __syncthreads();

  float lr[4] = {0.f, 0.f, 0.f, 0.f};
  f32x4 O[4] = {};
  int cur = 0;
  const int nkb = 2 * qq + 2;

  for (int kb = 0; kb < nkb; ++kb) {
    if (kb + 1 < nkb) {
      const u16* src = kvb + (size_t)(kb + 1) * 8192 + (w * 2) * 512 + lane * 8;
#pragma unroll
      for (int j = 0; j < 2; ++j)
        gload16(src + j * 512, &KB[cur ^ 1][(w * 2 + j) * 512]);
    }

    f32x4 s[4] = {};
#pragma unroll
    for (int ks = 0; ks < 2; ++ks)
#pragma unroll
      for (int c = 0; c < 4; ++c) {
        int jr = c * 16 + li;
        int sw = (jr >> 1) & 3;
        bf16x8 kh = *(const bf16x8*)&KB[cur][ks * 2048 + jr * 32 + ((g ^ sw) << 3)];
        s[c] = MFMA16(qh[ks], kh, s[c]);
        s[c] = MFMA16(ql[ks], kh, s[c]);
      }

    if (kb >= 2 * qq) {  // diagonal or fully-masked tile
#pragma unroll
      for (int c = 0; c < 4; ++c)
#pragma unroll
        for (int r = 0; r < 4; ++r) {
          int i = qq * 128 + w * 16 + g * 4 + r;
          int j = kb * 64 + c * 16 + li;
          if (!(j < i || (i == 0 && j == 0))) s[c][r] = -INFINITY;
        }
    }

    // unnormalized exp: p = 2^(S*log2e); per-lane l accumulation, no shuffles
#pragma unroll
    for (int c = 0; c < 4; ++c)
#pragma unroll
      for (int r = 0; r < 4; ++r) {
        float p = exp2_hw(s[c][r]);
        s[c][r] = p;
        lr[r] += p;
      }

    // P is wave-local (wave owns rows [w*16, w*16+16)) -> no extra barrier
#pragma unroll
    for (int c = 0; c < 4; ++c)
#pragma unroll
      for (int r = 0; r < 4; ++r)
        P[c >> 1][w * 16 + g * 4 + r][(c & 1) * 16 + li] = bf16_rtn(s[c][r]);

#pragma unroll
    for (int ks = 0; ks < 2; ++ks) {
      bf16x8 pa = *(const bf16x8*)&P[ks][w * 16 + li][g * 8];
#pragma unroll
      for (int c = 0; c < 4; ++c) {
        int d = c * 16 + li;
        int tc = ks * 4 + g;
        bf16x8 vb = *(const bf16x8*)&KB[cur][4096 + d * 64 + ((tc ^ (d & 7)) << 3)];
        O[c] = MFMA16(pa, vb, O[c]);
      }
    }
    VMCNT0();         // prefetch for KB[cur^1] fully landed before any wave proceeds
    __syncthreads();  // + all waves done reading KB[cur]
    cur ^= 1;
  }

  // one-time row-sum reduce across the 16 lanes holding this row's columns
#pragma unroll
  for (int off = 1; off < 16; off <<= 1)
#pragma unroll
    for (int r = 0; r < 4; ++r) lr[r] += __shfl_xor(lr[r], off, 16);

#pragma unroll
  for (int c = 0; c < 4; ++c)
#pragma unroll
    for (int r = 0; r < 4; ++r) {
      float v = O[c][r] / lr[r];
      size_t row = (size_t)n * T + qq * 128 + w * 16 + g * 4 + r;
      out[row * E + h * HD + c * 16 + li] = bf16_rtn(v);
    }
}

// ---------------------------------------------------------------------------
extern "C" void kernel_launch(void* const* d_in, const int* in_sizes, int n_in,
                              void* d_out, int out_size, void* d_ws, size_t ws_size,
                              hipStream_t stream) {
  const float* kq = (const float*)d_in[0];
  const float* v = (const float*)d_in[1];
  const float* Wk = (const float*)d_in[2];
  const float* bk = (const float*)d_in[3];
  const float* Wq = (const float*)d_in[4];
  const float* bq = (const float*)d_in[5];
  const float* Wv = (const float*)d_in[6];
  const float* bv = (const float*)d_in[7];
  const float* W1 = (const float*)d_in[8];
  const float* b1 = (const float*)d_in[9];
  const float* W2 = (const float*)d_in[10];
  const float* b2 = (const float*)d_in[11];
  float* outp = (float*)d_out;

  char* ws = (char*)d_ws;
  u16* kq_hi = (u16*)(ws + 0);
  u16* kq_lo = (u16*)(ws + 8388608);
  u16* v_bf = (u16*)(ws + 16777216);
  u16* hbuf = (u16*)(ws + 0);  // aliases region A after attention
  u16* WkqT_hi = (u16*)(ws + 33554432);  // 4MB: [WkT rows 0-1023 | WqT rows 1024-2047]
  u16* WkqT_lo = (u16*)(ws + 37748736);  // 4MB
  u16* WvT = (u16*)(ws + 41943040);
  u16* W1T = (u16*)(ws + 44040192);
  u16* W2T = (u16*)(ws + 52428800);
  u16* Qh = (u16*)(ws + 60817408);
  u16* Ql = (u16*)(ws + 69206016);
  u16* KV = (u16*)(ws + 77594624);  // 16MB: 1024 slabs x 16KB (K hi + V)
  u16* attn_o = (u16*)(ws + 102760448);
  // total: 111,149,056 bytes

  // --- conversions ---
  k_cvt<<<8192, 256, 0, stream>>>(kq, v, kq_hi, kq_lo, v_bf);
  k_tconv<1><<<dim3(32, 32), 256, 0, stream>>>(Wk, WkqT_hi, WkqT_lo, 1024, 1024);
  k_tconv<1><<<dim3(32, 32), 256, 0, stream>>>(Wq, WkqT_hi + (1 << 20), WkqT_lo + (1 << 20), 1024, 1024);
  k_tconv<0><<<dim3(32, 32), 256, 0, stream>>>(Wv, WvT, nullptr, 1024, 1024);
  k_tconv<0><<<dim3(128, 32), 256, 0, stream>>>(W1, W1T, nullptr, 1024, 4096);
  k_tconv<0><<<dim3(32, 128), 256, 0, stream>>>(W2, W2T, nullptr, 4096, 1024);

  // --- fused K|Q projection (split-precision, dbuf) ---
  k_gemm<1, 0, 4><<<dim3(16, 32), 256, 65536, stream>>>(
      kq_hi, kq_lo, WkqT_hi, WkqT_lo, bk, bq, KV, Qh, Ql, 4096, 2048, 1024);
  // --- V projection, epilogue writes swizzled V slab directly ---
  k_gemm<0, 0, 5><<<dim3(8, 32), 256, 32768, stream>>>(
      v_bf, nullptr, WvT, nullptr, bv, nullptr, KV, nullptr, nullptr, 4096, 1024, 1024);

  // --- attention ---
  k_attn<<<dim3(32, 16), 512, 0, stream>>>(Qh, Ql, KV, attn_o);

  // --- FFN ---
  k_gemm<0, 1, 1><<<dim3(32, 32), 256, 32768, stream>>>(
      attn_o, nullptr, W1T, nullptr, b1, nullptr, hbuf, nullptr, nullptr, 4096, 4096, 1024);
  k_gemm<0, 0, 0><<<dim3(8, 32), 256, 32768, stream>>>(
      hbuf, nullptr, W2T, nullptr, b2, nullptr, outp, nullptr, nullptr, 4096, 1024, 4096);
}

// Round 9
// 250.510 us; speedup vs baseline: 2.9737x; 1.1465x over previous
//
#include <hip/hip_runtime.h>

typedef short bf16x8 __attribute__((ext_vector_type(8)));
typedef unsigned short u16x8 __attribute__((ext_vector_type(8)));
typedef float f32x4 __attribute__((ext_vector_type(4)));
typedef unsigned short u16;

#define MFMA16(a, b, c) __builtin_amdgcn_mfma_f32_16x16x32_bf16((a), (b), (c), 0, 0, 0)
// Explicit drain of outstanding global_load_lds before a barrier.
// __syncthreads() alone does NOT guarantee cross-wave visibility of async
// LDS-destined loads (R4 post-timing race; fixed in R5).
#define VMCNT0() asm volatile("s_waitcnt vmcnt(0)" ::: "memory")

__device__ __forceinline__ u16 bf16_rtn(float f) {
  unsigned u = __float_as_uint(f);
  u += 0x7fffu + ((u >> 16) & 1u);
  return (u16)(u >> 16);
}
__device__ __forceinline__ float bf16_to_f(u16 h) {
  return __uint_as_float(((unsigned)h) << 16);
}
__device__ __forceinline__ void splitf(float f, u16& hi, u16& lo) {
  hi = bf16_rtn(f);
  lo = bf16_rtn(f - bf16_to_f(hi));
}
__device__ __forceinline__ void gload16(const void* g, void* l) {
  __builtin_amdgcn_global_load_lds(
      (const __attribute__((address_space(1))) unsigned int*)g,
      (__attribute__((address_space(3))) unsigned int*)l, 16, 0, 0);
}
__device__ __forceinline__ float exp2_hw(float x) {
  float r;
  asm("v_exp_f32 %0, %1" : "=v"(r) : "v"(x));
  return r;
}
// XCD-aware bijective block swizzle (T1). Requires gx*gy % 8 == 0 (all our grids).
__device__ __forceinline__ void swz_bid(int& bx, int& by) {
  int gx = gridDim.x;
  int lin = (int)blockIdx.y * gx + (int)blockIdx.x;
  int cpx = (gx * (int)gridDim.y) >> 3;
  int nl = (lin & 7) * cpx + (lin >> 3);
  bx = nl % gx;
  by = nl / gx;
}

// ---------------- fused elementwise convert: kq -> hi/lo, v -> bf16 ----------------
__global__ void k_cvt(const float* __restrict__ a, const float* __restrict__ b,
                      u16* __restrict__ hi, u16* __restrict__ lo,
                      u16* __restrict__ vb) {
  int i = blockIdx.x * blockDim.x + threadIdx.x;
  const int N4 = 1 << 20;
  if (i < N4) {
    float4 v4 = ((const float4*)a)[i];
    ushort4 h, l;
    splitf(v4.x, h.x, l.x);
    splitf(v4.y, h.y, l.y);
    splitf(v4.z, h.z, l.z);
    splitf(v4.w, h.w, l.w);
    ((ushort4*)hi)[i] = h;
    ((ushort4*)lo)[i] = l;
  } else {
    int j = i - N4;
    float4 v4 = ((const float4*)b)[j];
    ushort4 h;
    h.x = bf16_rtn(v4.x);
    h.y = bf16_rtn(v4.y);
    h.z = bf16_rtn(v4.z);
    h.w = bf16_rtn(v4.w);
    ((ushort4*)vb)[j] = h;
  }
}

// ------------- transpose fp32 [R][C] -> bf16 [C][R] (hi / hi+lo) -------------
template <int SPLIT>
__global__ void k_tconv(const float* __restrict__ in, u16* __restrict__ hi,
                        u16* __restrict__ lo, int R, int C) {
  __shared__ float tile[32][33];
  int c0 = blockIdx.x * 32, r0 = blockIdx.y * 32;
  int tx = threadIdx.x & 31, ty = threadIdx.x >> 5;
#pragma unroll
  for (int i = 0; i < 4; ++i)
    tile[ty + i * 8][tx] = in[(size_t)(r0 + ty + i * 8) * C + c0 + tx];
  __syncthreads();
#pragma unroll
  for (int i = 0; i < 4; ++i) {
    float v = tile[tx][ty + i * 8];
    size_t o = (size_t)(c0 + ty + i * 8) * R + r0 + tx;
    if (SPLIT) {
      u16 h, l;
      splitf(v, h, l);
      hi[o] = h;
      lo[o] = l;
    } else {
      hi[o] = bf16_rtn(v);
    }
  }
}

// ------------- non-split GEMM: C[M,Nc] = A[M,K]*B[Nc,K]^T + bias -------------
// BM=128, BN in {64,128}, BK=64 staging (full 128B lines), XOR-swizzled LDS
// (inverse swizzle on global source, swizzle on ds_read — conflict-free b128),
// double-buffered, stage(kb+1) before compute(kb), one vmcnt(0)+barrier per
// K-tile. XCD-swizzled block ids.
// OUT: 0 = fp32 row-major, 1 = bf16 row-major, 5 = V into swizzled KV slab.
template <int GELU, int OUT, int BN>
__global__ __launch_bounds__(256) void k_gemm(
    const u16* __restrict__ A, const u16* __restrict__ B,
    const float* __restrict__ bias, void* __restrict__ C0,
    int M, int Nc, int K) {
  extern __shared__ u16 sm[];
  const int NB = BN / 32;
  const int BUFE = 8192 + BN * 64;  // u16 per buffer: A[128][64] | B[BN][64]

  int bx, by;
  swz_bid(bx, by);
  int m0 = by * 128, n0 = bx * BN;
  int t = threadIdx.x, lane = t & 63, w = t >> 6;
  int wr = (w >> 1) * 64, wc = (w & 1) * (BN / 2);
  int li = lane & 15, g = lane >> 4;
  int lrow = lane >> 3, lcg = lane & 7;  // staging lane decomposition

  f32x4 acc[4][4] = {};
  const int nk = K >> 6;

  // ---- staging: one call = 1KB = 8 full 128B rows ----
  auto stage = [&](int kb, int buf) {
    int k0 = kb * 64;
    u16* base = sm + buf * BUFE;
#pragma unroll
    for (int j = 0; j < 4; ++j) {  // A: 16 calls total, 4 per wave
      int jj = w * 4 + j;
      int row = jj * 8 + lrow;
      int cg = lcg ^ (row & 7);
      gload16(A + (size_t)(m0 + row) * K + k0 + cg * 8, base + jj * 512);
    }
#pragma unroll
    for (int j = 0; j < NB; ++j) {  // B: BN/8 calls total, NB per wave
      int jj = w * NB + j;
      int row = jj * 8 + lrow;
      int cg = lcg ^ (row & 7);
      gload16(B + (size_t)(n0 + row) * K + k0 + cg * 8, base + 8192 + jj * 512);
    }
  };

  stage(0, 0);
  VMCNT0();
  __syncthreads();

  int cur = 0;
  for (int kb = 0; kb < nk; ++kb) {
    if (kb + 1 < nk) stage(kb + 1, cur ^ 1);
    const u16* bs = sm + cur * BUFE;
#pragma unroll
    for (int kk = 0; kk < 2; ++kk) {
      bf16x8 af[4], bf[4];
#pragma unroll
      for (int i = 0; i < 4; ++i) {
        int row = wr + i * 16 + li;
        af[i] = *(const bf16x8*)&bs[row * 64 + (((kk * 4 + g) ^ (li & 7)) << 3)];
      }
#pragma unroll
      for (int b = 0; b < NB; ++b) {
        int row = wc + b * 16 + li;
        bf[b] = *(const bf16x8*)&bs[8192 + row * 64 + (((kk * 4 + g) ^ (li & 7)) << 3)];
      }
#pragma unroll
      for (int a = 0; a < 4; ++a)
#pragma unroll
        for (int b = 0; b < NB; ++b) acc[a][b] = MFMA16(af[a], bf[b], acc[a][b]);
    }
    VMCNT0();         // next buffer fully landed (cross-wave)
    __syncthreads();  // all waves done reading cur
    cur ^= 1;
  }

#pragma unroll
  for (int a = 0; a < 4; ++a)
#pragma unroll
    for (int b = 0; b < NB; ++b)
#pragma unroll
      for (int r = 0; r < 4; ++r) {
        int row = m0 + wr + a * 16 + g * 4 + r;
        int col = n0 + wc + b * 16 + li;
        float v = acc[a][b][r] + bias[col];
        if (GELU) v = 0.5f * v * (1.0f + erff(v * 0.70710678118654752f));
        if (OUT == 0) {
          ((float*)C0)[(size_t)row * Nc + col] = v;
        } else if (OUT == 1) {
          ((u16*)C0)[(size_t)row * Nc + col] = bf16_rtn(v);
        } else if (OUT == 5) {  // V -> swizzled KV slab V-section
          int nn = row >> 11, tt = row & 2047, kbb = tt >> 6, tr = tt & 63;
          int hq = col >> 6, d = col & 63;
          size_t base = (((size_t)nn * 16 + hq) * 32 + kbb) * 8192 + 4096;
          size_t ov = base + d * 64 + (tr & 7) + (((tr >> 3) ^ (d & 7)) << 3);
          ((u16*)C0)[ov] = bf16_rtn(v);
        }
      }
}

// ------------- split-precision GEMM (K|Q fused projection) -------------
// 128x128, BK=32, hi+lo 3-pass MFMA, double-buffered (R8 structure) + XCD swz.
// Epilogue: col<1024 -> K bf16 into swizzled KV slab; col>=1024 -> Q
// (pre-scaled by log2e) split hi/lo head-major [n,h,t,d].
__global__ __launch_bounds__(256) void k_gemm_s(
    const u16* __restrict__ Ahi, const u16* __restrict__ Alo,
    const u16* __restrict__ Bhi, const u16* __restrict__ Blo,
    const float* __restrict__ bias, const float* __restrict__ bias2,
    void* __restrict__ C0, void* __restrict__ C1, void* __restrict__ C2,
    int M, int Nc, int K) {
  extern __shared__ u16 sm[];
  const int BUFE = 16384;

  int bx, by;
  swz_bid(bx, by);
  int m0 = by * 128, n0 = bx * 128;
  int t = threadIdx.x, lane = t & 63, w = t >> 6;
  int wr = (w >> 1) * 64, wc = (w & 1) * 64;
  int li = lane & 15, g = lane >> 4;
  int srow = lane >> 2, scol = (lane & 3) * 8;

  f32x4 acc[4][4] = {};
  const int nk = K >> 5;

  auto stage = [&](int kb, int buf) {
    int k0 = kb * 32;
    int bo = buf * BUFE;
#pragma unroll
    for (int c = 0; c < 2; ++c) {
      int row = w * 32 + c * 16 + srow;
      int ldso = bo + w * 1024 + c * 512;
      gload16(Ahi + (size_t)(m0 + row) * K + k0 + scol, sm + ldso);
      gload16(Bhi + (size_t)(n0 + row) * K + k0 + scol, sm + 4096 + ldso);
      gload16(Alo + (size_t)(m0 + row) * K + k0 + scol, sm + 8192 + ldso);
      gload16(Blo + (size_t)(n0 + row) * K + k0 + scol, sm + 12288 + ldso);
    }
  };

  stage(0, 0);
  VMCNT0();
  __syncthreads();

  int cur = 0;
  for (int kb = 0; kb < nk; ++kb) {
    if (kb + 1 < nk) stage(kb + 1, cur ^ 1);
    const u16* lA = sm + cur * BUFE;
    bf16x8 af[4], bfr[4], afl[4], bfl[4];
#pragma unroll
    for (int i = 0; i < 4; ++i) {
      af[i] = *(const bf16x8*)&lA[(wr + i * 16 + li) * 32 + g * 8];
      bfr[i] = *(const bf16x8*)&lA[4096 + (wc + i * 16 + li) * 32 + g * 8];
      afl[i] = *(const bf16x8*)&lA[8192 + (wr + i * 16 + li) * 32 + g * 8];
      bfl[i] = *(const bf16x8*)&lA[12288 + (wc + i * 16 + li) * 32 + g * 8];
    }
#pragma unroll
    for (int a = 0; a < 4; ++a)
#pragma unroll
      for (int b = 0; b < 4; ++b) {
        acc[a][b] = MFMA16(af[a], bfr[b], acc[a][b]);
        acc[a][b] = MFMA16(af[a], bfl[b], acc[a][b]);
        acc[a][b] = MFMA16(afl[a], bfr[b], acc[a][b]);
      }
    VMCNT0();
    __syncthreads();
    cur ^= 1;
  }

#pragma unroll
  for (int a = 0; a < 4; ++a)
#pragma unroll
    for (int b = 0; b < 4; ++b)
#pragma unroll
      for (int r = 0; r < 4; ++r) {
        int row = m0 + wr + a * 16 + g * 4 + r;
        int col = n0 + wc + b * 16 + li;
        float bb = col < 1024 ? bias[col] : bias2[col - 1024];
        float v = acc[a][b][r] + bb;
        if (col < 1024) {  // K -> swizzled KV slab (single bf16 rounding)
          int nn = row >> 11, tt = row & 2047, kbb = tt >> 6, tr = tt & 63;
          int hq = col >> 6, d = col & 63, ks = d >> 5, dc = d & 31;
          size_t base = (((size_t)nn * 16 + hq) * 32 + kbb) * 8192;
          size_t oh = base + ks * 2048 + tr * 32 + (dc & 7) +
                      (((dc >> 3) ^ ((tr >> 1) & 3)) << 3);
          ((u16*)C0)[oh] = bf16_rtn(v);
        } else {  // Q (pre-scaled by log2e) -> split hi/lo head-major
          int cq = col - 1024;
          float vq = v * 1.4426950408889634f;
          u16 hh, ll;
          splitf(vq, hh, ll);
          size_t off = (((size_t)(row >> 11) * 16 + (cq >> 6)) * 2048 + (row & 2047)) * 64 + (cq & 63);
          ((u16*)C1)[off] = hh;
          ((u16*)C2)[off] = ll;
        }
      }
}

// ------------- flash attention, strictly-causal + [0,0], no 1/sqrt(d) -------------
// Q pre-split+log2e-scaled [n,h,T,64]; K(hi)+V in swizzled 16KB KV slabs.
// QBLK=128, 8 waves. Unnormalized softmax (|S|<~50 << 88): no max tracking,
// no cross-lane ops in the loop; l reduced once at the end.
__global__ __launch_bounds__(512) void k_attn(
    const u16* __restrict__ Qh, const u16* __restrict__ Ql,
    const u16* __restrict__ KV, u16* __restrict__ out) {
  const int T = 2048, HD = 64, H = 16, E = 1024;
  int hc = blockIdx.x;
  int h = hc & 15, n = hc >> 4;
  int qq = 15 - (int)blockIdx.y;  // largest workload first
  __shared__ u16 KB[2][8192];     // [buf][K hi 4096 | V 4096]
  __shared__ u16 P[2][128][36];
  int t = threadIdx.x, lane = t & 63, w = t >> 6;
  int li = lane & 15, g = lane >> 4;

  const size_t nh = (size_t)n * H + h;
  const u16* qhb = Qh + (nh * 2048 + (size_t)qq * 128) * 64;
  const u16* qlb = Ql + (nh * 2048 + (size_t)qq * 128) * 64;
  const u16* kvb = KV + nh * 32 * 8192;

  bf16x8 qh[2], ql[2];
#pragma unroll
  for (int ks = 0; ks < 2; ++ks) {
    qh[ks] = *(const bf16x8*)&qhb[(w * 16 + li) * 64 + ks * 32 + g * 8];
    ql[ks] = *(const bf16x8*)&qlb[(w * 16 + li) * 64 + ks * 32 + g * 8];
  }

#pragma unroll
  for (int j = 0; j < 2; ++j)
    gload16(kvb + (w * 2 + j) * 512 + lane * 8, &KB[0][(w * 2 + j) * 512]);
  VMCNT0();
  __syncthreads();

  float lr[4] = {0.f, 0.f, 0.f, 0.f};
  f32x4 O[4] = {};
  int cur = 0;
  const int nkb = 2 * qq + 2;

  for (int kb = 0; kb < nkb; ++kb) {
    if (kb + 1 < nkb) {
      const u16* src = kvb + (size_t)(kb + 1) * 8192 + (w * 2) * 512 + lane * 8;
#pragma unroll
      for (int j = 0; j < 2; ++j)
        gload16(src + j * 512, &KB[cur ^ 1][(w * 2 + j) * 512]);
    }

    f32x4 s[4] = {};
#pragma unroll
    for (int ks = 0; ks < 2; ++ks)
#pragma unroll
      for (int c = 0; c < 4; ++c) {
        int jr = c * 16 + li;
        int sw = (jr >> 1) & 3;
        bf16x8 kh = *(const bf16x8*)&KB[cur][ks * 2048 + jr * 32 + ((g ^ sw) << 3)];
        s[c] = MFMA16(qh[ks], kh, s[c]);
        s[c] = MFMA16(ql[ks], kh, s[c]);
      }

    if (kb >= 2 * qq) {  // diagonal or fully-masked tile
#pragma unroll
      for (int c = 0; c < 4; ++c)
#pragma unroll
        for (int r = 0; r < 4; ++r) {
          int i = qq * 128 + w * 16 + g * 4 + r;
          int j = kb * 64 + c * 16 + li;
          if (!(j < i || (i == 0 && j == 0))) s[c][r] = -INFINITY;
        }
    }

#pragma unroll
    for (int c = 0; c < 4; ++c)
#pragma unroll
      for (int r = 0; r < 4; ++r) {
        float p = exp2_hw(s[c][r]);
        s[c][r] = p;
        lr[r] += p;
      }

#pragma unroll
    for (int c = 0; c < 4; ++c)
#pragma unroll
      for (int r = 0; r < 4; ++r)
        P[c >> 1][w * 16 + g * 4 + r][(c & 1) * 16 + li] = bf16_rtn(s[c][r]);

#pragma unroll
    for (int ks = 0; ks < 2; ++ks) {
      bf16x8 pa = *(const bf16x8*)&P[ks][w * 16 + li][g * 8];
#pragma unroll
      for (int c = 0; c < 4; ++c) {
        int d = c * 16 + li;
        int tc = ks * 4 + g;
        bf16x8 vb = *(const bf16x8*)&KB[cur][4096 + d * 64 + ((tc ^ (d & 7)) << 3)];
        O[c] = MFMA16(pa, vb, O[c]);
      }
    }
    VMCNT0();
    __syncthreads();
    cur ^= 1;
  }

#pragma unroll
  for (int off = 1; off < 16; off <<= 1)
#pragma unroll
    for (int r = 0; r < 4; ++r) lr[r] += __shfl_xor(lr[r], off, 16);

#pragma unroll
  for (int c = 0; c < 4; ++c)
#pragma unroll
    for (int r = 0; r < 4; ++r) {
      float v = O[c][r] / lr[r];
      size_t row = (size_t)n * T + qq * 128 + w * 16 + g * 4 + r;
      out[row * E + h * HD + c * 16 + li] = bf16_rtn(v);
    }
}

// ---------------------------------------------------------------------------
extern "C" void kernel_launch(void* const* d_in, const int* in_sizes, int n_in,
                              void* d_out, int out_size, void* d_ws, size_t ws_size,
                              hipStream_t stream) {
  const float* kq = (const float*)d_in[0];
  const float* v = (const float*)d_in[1];
  const float* Wk = (const float*)d_in[2];
  const float* bk = (const float*)d_in[3];
  const float* Wq = (const float*)d_in[4];
  const float* bq = (const float*)d_in[5];
  const float* Wv = (const float*)d_in[6];
  const float* bv = (const float*)d_in[7];
  const float* W1 = (const float*)d_in[8];
  const float* b1 = (const float*)d_in[9];
  const float* W2 = (const float*)d_in[10];
  const float* b2 = (const float*)d_in[11];
  float* outp = (float*)d_out;

  char* ws = (char*)d_ws;
  u16* kq_hi = (u16*)(ws + 0);
  u16* kq_lo = (u16*)(ws + 8388608);
  u16* v_bf = (u16*)(ws + 16777216);
  u16* hbuf = (u16*)(ws + 0);  // aliases region A after attention
  u16* WkqT_hi = (u16*)(ws + 33554432);  // 4MB: [WkT | WqT]
  u16* WkqT_lo = (u16*)(ws + 37748736);  // 4MB
  u16* WvT = (u16*)(ws + 41943040);
  u16* W1T = (u16*)(ws + 44040192);
  u16* W2T = (u16*)(ws + 52428800);
  u16* Qh = (u16*)(ws + 60817408);
  u16* Ql = (u16*)(ws + 69206016);
  u16* KV = (u16*)(ws + 77594624);  // 16MB: 1024 slabs x 16KB (K hi + V)
  u16* attn_o = (u16*)(ws + 102760448);
  // total: 111,149,056 bytes

  // --- conversions ---
  k_cvt<<<8192, 256, 0, stream>>>(kq, v, kq_hi, kq_lo, v_bf);
  k_tconv<1><<<dim3(32, 32), 256, 0, stream>>>(Wk, WkqT_hi, WkqT_lo, 1024, 1024);
  k_tconv<1><<<dim3(32, 32), 256, 0, stream>>>(Wq, WkqT_hi + (1 << 20), WkqT_lo + (1 << 20), 1024, 1024);
  k_tconv<0><<<dim3(32, 32), 256, 0, stream>>>(Wv, WvT, nullptr, 1024, 1024);
  k_tconv<0><<<dim3(128, 32), 256, 0, stream>>>(W1, W1T, nullptr, 1024, 4096);
  k_tconv<0><<<dim3(32, 128), 256, 0, stream>>>(W2, W2T, nullptr, 4096, 1024);

  // --- fused K|Q projection (split-precision, dbuf, XCD swz) ---
  k_gemm_s<<<dim3(16, 32), 256, 65536, stream>>>(
      kq_hi, kq_lo, WkqT_hi, WkqT_lo, bk, bq, KV, Qh, Ql, 4096, 2048, 1024);
  // --- V projection: BN=64 (512 blocks, 3/CU), BK=64 swizzled staging ---
  k_gemm<0, 5, 64><<<dim3(16, 32), 256, 49152, stream>>>(
      v_bf, WvT, bv, KV, 4096, 1024, 1024);

  // --- attention ---
  k_attn<<<dim3(32, 16), 512, 0, stream>>>(Qh, Ql, KV, attn_o);

  // --- FFN ---
  k_gemm<1, 1, 128><<<dim3(32, 32), 256, 65536, stream>>>(
      attn_o, W1T, b1, hbuf, 4096, 4096, 1024);
  k_gemm<0, 0, 64><<<dim3(16, 32), 256, 49152, stream>>>(
      hbuf, W2T, b2, outp, 4096, 1024, 4096);
}

// Round 10
// 239.941 us; speedup vs baseline: 3.1047x; 1.0440x over previous
//
#include <hip/hip_runtime.h>

typedef short bf16x8 __attribute__((ext_vector_type(8)));
typedef unsigned short u16x8 __attribute__((ext_vector_type(8)));
typedef float f32x4 __attribute__((ext_vector_type(4)));
typedef unsigned short u16;

#define MFMA16(a, b, c) __builtin_amdgcn_mfma_f32_16x16x32_bf16((a), (b), (c), 0, 0, 0)
// Full drain before barrier (R4 race lesson).
#define VMCNT0() asm volatile("s_waitcnt vmcnt(0)" ::: "memory")
// Counted wait (T4): allow n per-wave loads to remain in flight; guarantees all
// OLDER loads (the next tile to be consumed) have landed. Barrier publishes.
#define VMCNTN(n) asm volatile("s_waitcnt vmcnt(" #n ")" ::: "memory")

__device__ __forceinline__ u16 bf16_rtn(float f) {
  unsigned u = __float_as_uint(f);
  u += 0x7fffu + ((u >> 16) & 1u);
  return (u16)(u >> 16);
}
__device__ __forceinline__ float bf16_to_f(u16 h) {
  return __uint_as_float(((unsigned)h) << 16);
}
__device__ __forceinline__ void splitf(float f, u16& hi, u16& lo) {
  hi = bf16_rtn(f);
  lo = bf16_rtn(f - bf16_to_f(hi));
}
__device__ __forceinline__ void gload16(const void* g, void* l) {
  __builtin_amdgcn_global_load_lds(
      (const __attribute__((address_space(1))) unsigned int*)g,
      (__attribute__((address_space(3))) unsigned int*)l, 16, 0, 0);
}
__device__ __forceinline__ float exp2_hw(float x) {
  float r;
  asm("v_exp_f32 %0, %1" : "=v"(r) : "v"(x));
  return r;
}
// XCD-aware bijective block swizzle (T1). Requires gx*gy % 8 == 0 (all our grids).
__device__ __forceinline__ void swz_bid(int& bx, int& by) {
  int gx = gridDim.x;
  int lin = (int)blockIdx.y * gx + (int)blockIdx.x;
  int cpx = (gx * (int)gridDim.y) >> 3;
  int nl = (lin & 7) * cpx + (lin >> 3);
  bx = nl % gx;
  by = nl / gx;
}

// ---------------- elementwise convert: kq -> bf16, v -> bf16 ----------------
__global__ void k_cvt(const float* __restrict__ a, const float* __restrict__ b,
                      u16* __restrict__ ah, u16* __restrict__ vb) {
  int i = blockIdx.x * blockDim.x + threadIdx.x;
  const int N4 = 1 << 20;
  const float4 v4 = (i < N4) ? ((const float4*)a)[i] : ((const float4*)b)[i - N4];
  ushort4 h;
  h.x = bf16_rtn(v4.x);
  h.y = bf16_rtn(v4.y);
  h.z = bf16_rtn(v4.z);
  h.w = bf16_rtn(v4.w);
  if (i < N4)
    ((ushort4*)ah)[i] = h;
  else
    ((ushort4*)vb)[i - N4] = h;
}

// ------------- fused transpose of the three 1024x1024 weights -------------
// z=0: Wk -> WkqT hi/lo rows 0-1023; z=1: Wq -> rows 1024-2047; z=2: Wv plain.
__global__ void k_tconvW(const float* __restrict__ Wk, const float* __restrict__ Wq,
                         const float* __restrict__ Wv, u16* __restrict__ hi,
                         u16* __restrict__ lo, u16* __restrict__ wvt) {
  int z = blockIdx.z;
  const float* in = (z == 0) ? Wk : (z == 1) ? Wq : Wv;
  __shared__ float tile[32][33];
  int c0 = blockIdx.x * 32, r0 = blockIdx.y * 32;
  int tx = threadIdx.x & 31, ty = threadIdx.x >> 5;
#pragma unroll
  for (int i = 0; i < 4; ++i)
    tile[ty + i * 8][tx] = in[(size_t)(r0 + ty + i * 8) * 1024 + c0 + tx];
  __syncthreads();
#pragma unroll
  for (int i = 0; i < 4; ++i) {
    float v = tile[tx][ty + i * 8];
    size_t o = (size_t)(c0 + ty + i * 8) * 1024 + r0 + tx;
    if (z < 2) {
      u16 h, l;
      splitf(v, h, l);
      hi[(size_t)z * 1048576 + o] = h;
      lo[(size_t)z * 1048576 + o] = l;
    } else {
      wvt[o] = bf16_rtn(v);
    }
  }
}

// ------------- transpose fp32 [R][C] -> bf16 [C][R] (plain) -------------
__global__ void k_tconv(const float* __restrict__ in, u16* __restrict__ hi,
                        int R, int C) {
  __shared__ float tile[32][33];
  int c0 = blockIdx.x * 32, r0 = blockIdx.y * 32;
  int tx = threadIdx.x & 31, ty = threadIdx.x >> 5;
#pragma unroll
  for (int i = 0; i < 4; ++i)
    tile[ty + i * 8][tx] = in[(size_t)(r0 + ty + i * 8) * C + c0 + tx];
  __syncthreads();
#pragma unroll
  for (int i = 0; i < 4; ++i)
    hi[(size_t)(c0 + ty + i * 8) * R + r0 + tx] = bf16_rtn(tile[tx][ty + i * 8]);
}

// ------------- non-split GEMM: C[M,Nc] = A[M,K]*B[Nc,K]^T + bias -------------
// BM=128, BN=64, BK=64, XOR-swizzled LDS, 3-buffer depth-2 pipeline with
// counted vmcnt(6) (T4) — drain to 0 only in the last two iterations.
// OUT: 0 = fp32 row-major, 1 = bf16 row-major, 5 = V into swizzled KV slab.
template <int GELU, int OUT, int BN>
__global__ __launch_bounds__(256) void k_gemm(
    const u16* __restrict__ A, const u16* __restrict__ B,
    const float* __restrict__ bias, void* __restrict__ C0,
    int M, int Nc, int K) {
  const int NB = BN / 32;
  const int BUFE = 8192 + BN * 64;  // u16 per buffer: A[128][64] | B[BN][64]
  __shared__ u16 sm[3 * BUFE];

  int bx, by;
  swz_bid(bx, by);
  int m0 = by * 128, n0 = bx * BN;
  int t = threadIdx.x, lane = t & 63, w = t >> 6;
  int wr = (w >> 1) * 64, wc = (w & 1) * (BN / 2);
  int li = lane & 15, g = lane >> 4;
  int lrow = lane >> 3, lcg = lane & 7;

  f32x4 acc[4][NB] = {};
  const int nk = K >> 6;

  auto stage = [&](int kb, int buf) {
    int k0 = kb * 64;
    u16* base = sm + buf * BUFE;
#pragma unroll
    for (int j = 0; j < 4; ++j) {
      int jj = w * 4 + j;
      int row = jj * 8 + lrow;
      int cg = lcg ^ (row & 7);
      gload16(A + (size_t)(m0 + row) * K + k0 + cg * 8, base + jj * 512);
    }
#pragma unroll
    for (int j = 0; j < NB; ++j) {
      int jj = w * NB + j;
      int row = jj * 8 + lrow;
      int cg = lcg ^ (row & 7);
      gload16(B + (size_t)(n0 + row) * K + k0 + cg * 8, base + 8192 + jj * 512);
    }
  };

  stage(0, 0);
  stage(1, 1);
  VMCNTN(6);  // tile 0 landed (6 newest = tile 1 may fly)
  __syncthreads();

  int cur = 0;
  for (int kb = 0; kb < nk; ++kb) {
    int stb = cur + 2;
    if (stb >= 3) stb -= 3;
    if (kb + 2 < nk) stage(kb + 2, stb);

    const u16* bs = sm + cur * BUFE;
#pragma unroll
    for (int kk = 0; kk < 2; ++kk) {
      bf16x8 af[4], bf[NB];
#pragma unroll
      for (int i = 0; i < 4; ++i) {
        int row = wr + i * 16 + li;
        af[i] = *(const bf16x8*)&bs[row * 64 + (((kk * 4 + g) ^ (li & 7)) << 3)];
      }
#pragma unroll
      for (int b = 0; b < NB; ++b) {
        int row = wc + b * 16 + li;
        bf[b] = *(const bf16x8*)&bs[8192 + row * 64 + (((kk * 4 + g) ^ (li & 7)) << 3)];
      }
#pragma unroll
      for (int a = 0; a < 4; ++a)
#pragma unroll
        for (int b = 0; b < NB; ++b) acc[a][b] = MFMA16(af[a], bf[b], acc[a][b]);
    }
    if (kb + 2 < nk) {
      VMCNTN(6);  // tile kb+1 landed; tile kb+2's 6 may stay in flight
    } else {
      VMCNT0();
    }
    __syncthreads();
    cur = (cur == 2) ? 0 : cur + 1;
  }

#pragma unroll
  for (int a = 0; a < 4; ++a)
#pragma unroll
    for (int b = 0; b < NB; ++b)
#pragma unroll
      for (int r = 0; r < 4; ++r) {
        int row = m0 + wr + a * 16 + g * 4 + r;
        int col = n0 + wc + b * 16 + li;
        float v = acc[a][b][r] + bias[col];
        if (GELU) v = 0.5f * v * (1.0f + erff(v * 0.70710678118654752f));
        if (OUT == 0) {
          ((float*)C0)[(size_t)row * Nc + col] = v;
        } else if (OUT == 1) {
          ((u16*)C0)[(size_t)row * Nc + col] = bf16_rtn(v);
        } else if (OUT == 5) {  // V -> swizzled KV slab V-section
          int nn = row >> 11, tt = row & 2047, kbb = tt >> 6, tr = tt & 63;
          int hq = col >> 6, d = col & 63;
          size_t base = (((size_t)nn * 16 + hq) * 32 + kbb) * 8192 + 4096;
          size_t ov = base + d * 64 + (tr & 7) + (((tr >> 3) ^ (d & 7)) << 3);
          ((u16*)C0)[ov] = bf16_rtn(v);
        }
      }
}

// ------------- 2-pass split GEMM (K|Q fused projection) -------------
// acc = Ah*(Bh+Bl): input kq rounded to bf16 (err ~0.004), weights exact in
// hi+lo. Stages 3 arrays [128][32] with (row>>1)&3 XOR swizzle (the 64B-row
// layout is 8-way bank-conflicted per 16-lane phase without it). 3-buffer
// depth-2, counted vmcnt(6).
// Epilogue: col<1024 -> K bf16 into swizzled KV slab; col>=1024 -> Q
// (pre-scaled by log2e) split hi/lo head-major [n,h,t,d].
__global__ __launch_bounds__(256) void k_gemm_s(
    const u16* __restrict__ Ahi, const u16* __restrict__ Bhi,
    const u16* __restrict__ Blo, const float* __restrict__ bias,
    const float* __restrict__ bias2, void* __restrict__ C0,
    void* __restrict__ C1, void* __restrict__ C2, int M, int Nc, int K) {
  const int BUFE = 12288;  // Ah[128][32] | Bh[128][32] | Bl[128][32]
  __shared__ u16 sm[3 * BUFE];

  int bx, by;
  swz_bid(bx, by);
  int m0 = by * 128, n0 = bx * 128;
  int t = threadIdx.x, lane = t & 63, w = t >> 6;
  int wr = (w >> 1) * 64, wc = (w & 1) * 64;
  int li = lane & 15, g = lane >> 4;
  int srow = lane >> 2;
  int sc = ((lane & 3) ^ ((srow >> 1) & 3)) * 8;  // swizzled source chunk

  f32x4 acc[4][4] = {};
  const int nk = K >> 5;

  auto stage = [&](int kb, int buf) {
    int k0 = kb * 32;
    u16* base = sm + buf * BUFE;
#pragma unroll
    for (int c = 0; c < 2; ++c) {
      int row = w * 32 + c * 16 + srow;
      int ldso = w * 1024 + c * 512;
      gload16(Ahi + (size_t)(m0 + row) * K + k0 + sc, base + ldso);
      gload16(Bhi + (size_t)(n0 + row) * K + k0 + sc, base + 4096 + ldso);
      gload16(Blo + (size_t)(n0 + row) * K + k0 + sc, base + 8192 + ldso);
    }
  };

  stage(0, 0);
  stage(1, 1);
  VMCNTN(6);
  __syncthreads();

  int cur = 0;
  for (int kb = 0; kb < nk; ++kb) {
    int stb = cur + 2;
    if (stb >= 3) stb -= 3;
    if (kb + 2 < nk) stage(kb + 2, stb);

    const u16* bs = sm + cur * BUFE;
    bf16x8 af[4], bfr[4], bfl[4];
#pragma unroll
    for (int i = 0; i < 4; ++i) {
      int swz = (g ^ ((li >> 1) & 3)) << 3;
      af[i] = *(const bf16x8*)&bs[(wr + i * 16 + li) * 32 + swz];
      bfr[i] = *(const bf16x8*)&bs[4096 + (wc + i * 16 + li) * 32 + swz];
      bfl[i] = *(const bf16x8*)&bs[8192 + (wc + i * 16 + li) * 32 + swz];
    }
#pragma unroll
    for (int a = 0; a < 4; ++a)
#pragma unroll
      for (int b = 0; b < 4; ++b) {
        acc[a][b] = MFMA16(af[a], bfr[b], acc[a][b]);
        acc[a][b] = MFMA16(af[a], bfl[b], acc[a][b]);
      }
    if (kb + 2 < nk) {
      VMCNTN(6);
    } else {
      VMCNT0();
    }
    __syncthreads();
    cur = (cur == 2) ? 0 : cur + 1;
  }

#pragma unroll
  for (int a = 0; a < 4; ++a)
#pragma unroll
    for (int b = 0; b < 4; ++b)
#pragma unroll
      for (int r = 0; r < 4; ++r) {
        int row = m0 + wr + a * 16 + g * 4 + r;
        int col = n0 + wc + b * 16 + li;
        float bb = col < 1024 ? bias[col] : bias2[col - 1024];
        float v = acc[a][b][r] + bb;
        if (col < 1024) {  // K -> swizzled KV slab (single bf16 rounding)
          int nn = row >> 11, tt = row & 2047, kbb = tt >> 6, tr = tt & 63;
          int hq = col >> 6, d = col & 63, ks = d >> 5, dc = d & 31;
          size_t base = (((size_t)nn * 16 + hq) * 32 + kbb) * 8192;
          size_t oh = base + ks * 2048 + tr * 32 + (dc & 7) +
                      (((dc >> 3) ^ ((tr >> 1) & 3)) << 3);
          ((u16*)C0)[oh] = bf16_rtn(v);
        } else {  // Q (pre-scaled by log2e) -> split hi/lo head-major
          int cq = col - 1024;
          float vq = v * 1.4426950408889634f;
          u16 hh, ll;
          splitf(vq, hh, ll);
          size_t off = (((size_t)(row >> 11) * 16 + (cq >> 6)) * 2048 + (row & 2047)) * 64 + (cq & 63);
          ((u16*)C1)[off] = hh;
          ((u16*)C2)[off] = ll;
        }
      }
}

// ------------- flash attention, strictly-causal + [0,0], no 1/sqrt(d) -------------
// Q pre-split+log2e-scaled [n,h,T,64]; K(hi)+V in swizzled 16KB KV slabs.
// QBLK=128, 8 waves. Unnormalized softmax (|S|<~50 << 88). 3-buffer depth-2
// KV pipeline with counted vmcnt(2).
__global__ __launch_bounds__(512) void k_attn(
    const u16* __restrict__ Qh, const u16* __restrict__ Ql,
    const u16* __restrict__ KV, u16* __restrict__ out) {
  const int T = 2048, HD = 64, H = 16, E = 1024;
  int hc = blockIdx.x;
  int h = hc & 15, n = hc >> 4;
  int qq = 15 - (int)blockIdx.y;  // largest workload first
  __shared__ u16 KB[3][8192];     // [buf][K hi 4096 | V 4096]
  __shared__ u16 P[2][128][36];
  int t = threadIdx.x, lane = t & 63, w = t >> 6;
  int li = lane & 15, g = lane >> 4;

  const size_t nh = (size_t)n * H + h;
  const u16* qhb = Qh + (nh * 2048 + (size_t)qq * 128) * 64;
  const u16* qlb = Ql + (nh * 2048 + (size_t)qq * 128) * 64;
  const u16* kvb = KV + nh * 32 * 8192;

  bf16x8 qh[2], ql[2];
#pragma unroll
  for (int ks = 0; ks < 2; ++ks) {
    qh[ks] = *(const bf16x8*)&qhb[(w * 16 + li) * 64 + ks * 32 + g * 8];
    ql[ks] = *(const bf16x8*)&qlb[(w * 16 + li) * 64 + ks * 32 + g * 8];
  }

  // prologue: stage tiles 0 and 1 (nkb >= 2 always)
#pragma unroll
  for (int j = 0; j < 2; ++j)
    gload16(kvb + (w * 2 + j) * 512 + lane * 8, &KB[0][(w * 2 + j) * 512]);
#pragma unroll
  for (int j = 0; j < 2; ++j)
    gload16(kvb + 8192 + (w * 2 + j) * 512 + lane * 8, &KB[1][(w * 2 + j) * 512]);
  VMCNTN(2);
  __syncthreads();

  float lr[4] = {0.f, 0.f, 0.f, 0.f};
  f32x4 O[4] = {};
  int cur = 0;
  const int nkb = 2 * qq + 2;

  for (int kb = 0; kb < nkb; ++kb) {
    int stb = cur + 2;
    if (stb >= 3) stb -= 3;
    if (kb + 2 < nkb) {
      const u16* src = kvb + (size_t)(kb + 2) * 8192 + (w * 2) * 512 + lane * 8;
#pragma unroll
      for (int j = 0; j < 2; ++j)
        gload16(src + j * 512, &KB[stb][(w * 2 + j) * 512]);
    }

    f32x4 s[4] = {};
#pragma unroll
    for (int ks = 0; ks < 2; ++ks)
#pragma unroll
      for (int c = 0; c < 4; ++c) {
        int jr = c * 16 + li;
        int sw = (jr >> 1) & 3;
        bf16x8 kh = *(const bf16x8*)&KB[cur][ks * 2048 + jr * 32 + ((g ^ sw) << 3)];
        s[c] = MFMA16(qh[ks], kh, s[c]);
        s[c] = MFMA16(ql[ks], kh, s[c]);
      }

    if (kb >= 2 * qq) {  // diagonal or fully-masked tile
#pragma unroll
      for (int c = 0; c < 4; ++c)
#pragma unroll
        for (int r = 0; r < 4; ++r) {
          int i = qq * 128 + w * 16 + g * 4 + r;
          int j = kb * 64 + c * 16 + li;
          if (!(j < i || (i == 0 && j == 0))) s[c][r] = -INFINITY;
        }
    }

#pragma unroll
    for (int c = 0; c < 4; ++c)
#pragma unroll
      for (int r = 0; r < 4; ++r) {
        float p = exp2_hw(s[c][r]);
        s[c][r] = p;
        lr[r] += p;
      }

    // P is wave-local (wave owns rows [w*16, w*16+16)) -> no extra barrier
#pragma unroll
    for (int c = 0; c < 4; ++c)
#pragma unroll
      for (int r = 0; r < 4; ++r)
        P[c >> 1][w * 16 + g * 4 + r][(c & 1) * 16 + li] = bf16_rtn(s[c][r]);

#pragma unroll
    for (int ks = 0; ks < 2; ++ks) {
      bf16x8 pa = *(const bf16x8*)&P[ks][w * 16 + li][g * 8];
#pragma unroll
      for (int c = 0; c < 4; ++c) {
        int d = c * 16 + li;
        int tc = ks * 4 + g;
        bf16x8 vb = *(const bf16x8*)&KB[cur][4096 + d * 64 + ((tc ^ (d & 7)) << 3)];
        O[c] = MFMA16(pa, vb, O[c]);
      }
    }
    if (kb + 2 < nkb) {
      VMCNTN(2);  // tile kb+1 landed; tile kb+2's 2 loads may stay in flight
    } else {
      VMCNT0();
    }
    __syncthreads();
    cur = (cur == 2) ? 0 : cur + 1;
  }

#pragma unroll
  for (int off = 1; off < 16; off <<= 1)
#pragma unroll
    for (int r = 0; r < 4; ++r) lr[r] += __shfl_xor(lr[r], off, 16);

#pragma unroll
  for (int c = 0; c < 4; ++c)
#pragma unroll
    for (int r = 0; r < 4; ++r) {
      float v = O[c][r] / lr[r];
      size_t row = (size_t)n * T + qq * 128 + w * 16 + g * 4 + r;
      out[row * E + h * HD + c * 16 + li] = bf16_rtn(v);
    }
}

// ---------------------------------------------------------------------------
extern "C" void kernel_launch(void* const* d_in, const int* in_sizes, int n_in,
                              void* d_out, int out_size, void* d_ws, size_t ws_size,
                              hipStream_t stream) {
  const float* kq = (const float*)d_in[0];
  const float* v = (const float*)d_in[1];
  const float* Wk = (const float*)d_in[2];
  const float* bk = (const float*)d_in[3];
  const float* Wq = (const float*)d_in[4];
  const float* bq = (const float*)d_in[5];
  const float* Wv = (const float*)d_in[6];
  const float* bv = (const float*)d_in[7];
  const float* W1 = (const float*)d_in[8];
  const float* b1 = (const float*)d_in[9];
  const float* W2 = (const float*)d_in[10];
  const float* b2 = (const float*)d_in[11];
  float* outp = (float*)d_out;

  char* ws = (char*)d_ws;
  u16* kq_hi = (u16*)(ws + 0);
  u16* v_bf = (u16*)(ws + 8388608);
  u16* hbuf = (u16*)(ws + 0);  // 32MB, aliases kq_hi/v_bf after attention
  u16* WkqT_hi = (u16*)(ws + 33554432);  // 4MB: [WkT | WqT]
  u16* WkqT_lo = (u16*)(ws + 37748736);  // 4MB
  u16* WvT = (u16*)(ws + 41943040);
  u16* W1T = (u16*)(ws + 44040192);
  u16* W2T = (u16*)(ws + 52428800);
  u16* Qh = (u16*)(ws + 60817408);
  u16* Ql = (u16*)(ws + 69206016);
  u16* KV = (u16*)(ws + 77594624);  // 16MB: 1024 slabs x 16KB (K hi + V)
  u16* attn_o = (u16*)(ws + 102760448);
  // total: 111,149,056 bytes

  // --- conversions ---
  k_cvt<<<8192, 256, 0, stream>>>(kq, v, kq_hi, v_bf);
  k_tconvW<<<dim3(32, 32, 3), 256, 0, stream>>>(Wk, Wq, Wv, WkqT_hi, WkqT_lo, WvT);
  k_tconv<<<dim3(128, 32), 256, 0, stream>>>(W1, W1T, 1024, 4096);
  k_tconv<<<dim3(32, 128), 256, 0, stream>>>(W2, W2T, 4096, 1024);

  // --- fused K|Q projection (2-pass split, 3-buf counted vmcnt, XCD swz) ---
  k_gemm_s<<<dim3(16, 32), 256, 0, stream>>>(
      kq_hi, WkqT_hi, WkqT_lo, bk, bq, KV, Qh, Ql, 4096, 2048, 1024);
  // --- V projection ---
  k_gemm<0, 5, 64><<<dim3(16, 32), 256, 0, stream>>>(
      v_bf, WvT, bv, KV, 4096, 1024, 1024);

  // --- attention ---
  k_attn<<<dim3(32, 16), 512, 0, stream>>>(Qh, Ql, KV, attn_o);

  // --- FFN ---
  k_gemm<1, 1, 64><<<dim3(64, 32), 256, 0, stream>>>(
      attn_o, W1T, b1, hbuf, 4096, 4096, 1024);
  k_gemm<0, 0, 64><<<dim3(16, 32), 256, 0, stream>>>(
      hbuf, W2T, b2, outp, 4096, 1024, 4096);
}

// Round 11
// 232.330 us; speedup vs baseline: 3.2064x; 1.0328x over previous
//
#include <hip/hip_runtime.h>

typedef short bf16x8 __attribute__((ext_vector_type(8)));
typedef unsigned short u16x8 __attribute__((ext_vector_type(8)));
typedef float f32x4 __attribute__((ext_vector_type(4)));
typedef unsigned short u16;

#define MFMA16(a, b, c) __builtin_amdgcn_mfma_f32_16x16x32_bf16((a), (b), (c), 0, 0, 0)
// Full drain before barrier (R4 race lesson).
#define VMCNT0() asm volatile("s_waitcnt vmcnt(0)" ::: "memory")
// Counted wait (T4): allow n per-wave loads to remain in flight; guarantees all
// OLDER loads (the next tile to be consumed) have landed. Barrier publishes.
#define VMCNTN(n) asm volatile("s_waitcnt vmcnt(" #n ")" ::: "memory")

__device__ __forceinline__ u16 bf16_rtn(float f) {
  unsigned u = __float_as_uint(f);
  u += 0x7fffu + ((u >> 16) & 1u);
  return (u16)(u >> 16);
}
__device__ __forceinline__ float bf16_to_f(u16 h) {
  return __uint_as_float(((unsigned)h) << 16);
}
__device__ __forceinline__ void splitf(float f, u16& hi, u16& lo) {
  hi = bf16_rtn(f);
  lo = bf16_rtn(f - bf16_to_f(hi));
}
__device__ __forceinline__ void gload16(const void* g, void* l) {
  __builtin_amdgcn_global_load_lds(
      (const __attribute__((address_space(1))) unsigned int*)g,
      (__attribute__((address_space(3))) unsigned int*)l, 16, 0, 0);
}
__device__ __forceinline__ float exp2_hw(float x) {
  float r;
  asm("v_exp_f32 %0, %1" : "=v"(r) : "v"(x));
  return r;
}
// XCD-aware bijective block swizzle (T1). Requires gx*gy % 8 == 0 (all our grids).
__device__ __forceinline__ void swz_bid(int& bx, int& by) {
  int gx = gridDim.x;
  int lin = (int)blockIdx.y * gx + (int)blockIdx.x;
  int cpx = (gx * (int)gridDim.y) >> 3;
  int nl = (lin & 7) * cpx + (lin >> 3);
  bx = nl % gx;
  by = nl / gx;
}

// ---------------- elementwise convert: kq -> bf16, v -> bf16 ----------------
__global__ void k_cvt(const float* __restrict__ a, const float* __restrict__ b,
                      u16* __restrict__ ah, u16* __restrict__ vb) {
  int i = blockIdx.x * blockDim.x + threadIdx.x;
  const int N4 = 1 << 20;
  const float4 v4 = (i < N4) ? ((const float4*)a)[i] : ((const float4*)b)[i - N4];
  ushort4 h;
  h.x = bf16_rtn(v4.x);
  h.y = bf16_rtn(v4.y);
  h.z = bf16_rtn(v4.z);
  h.w = bf16_rtn(v4.w);
  if (i < N4)
    ((ushort4*)ah)[i] = h;
  else
    ((ushort4*)vb)[i - N4] = h;
}

// ------------- fused transpose of the three 1024x1024 weights -------------
__global__ void k_tconvW(const float* __restrict__ Wk, const float* __restrict__ Wq,
                         const float* __restrict__ Wv, u16* __restrict__ hi,
                         u16* __restrict__ lo, u16* __restrict__ wvt) {
  int z = blockIdx.z;
  const float* in = (z == 0) ? Wk : (z == 1) ? Wq : Wv;
  __shared__ float tile[32][33];
  int c0 = blockIdx.x * 32, r0 = blockIdx.y * 32;
  int tx = threadIdx.x & 31, ty = threadIdx.x >> 5;
#pragma unroll
  for (int i = 0; i < 4; ++i)
    tile[ty + i * 8][tx] = in[(size_t)(r0 + ty + i * 8) * 1024 + c0 + tx];
  __syncthreads();
#pragma unroll
  for (int i = 0; i < 4; ++i) {
    float v = tile[tx][ty + i * 8];
    size_t o = (size_t)(c0 + ty + i * 8) * 1024 + r0 + tx;
    if (z < 2) {
      u16 h, l;
      splitf(v, h, l);
      hi[(size_t)z * 1048576 + o] = h;
      lo[(size_t)z * 1048576 + o] = l;
    } else {
      wvt[o] = bf16_rtn(v);
    }
  }
}

// ------------- transpose fp32 [R][C] -> bf16 [C][R] (plain) -------------
__global__ void k_tconv(const float* __restrict__ in, u16* __restrict__ hi,
                        int R, int C) {
  __shared__ float tile[32][33];
  int c0 = blockIdx.x * 32, r0 = blockIdx.y * 32;
  int tx = threadIdx.x & 31, ty = threadIdx.x >> 5;
#pragma unroll
  for (int i = 0; i < 4; ++i)
    tile[ty + i * 8][tx] = in[(size_t)(r0 + ty + i * 8) * C + c0 + tx];
  __syncthreads();
#pragma unroll
  for (int i = 0; i < 4; ++i)
    hi[(size_t)(c0 + ty + i * 8) * R + r0 + tx] = bf16_rtn(tile[tx][ty + i * 8]);
}

// ------------- non-split GEMM: BM=128, BN in {64,128} -------------
// BK=64, XOR-swizzled LDS, 3-buffer depth-2, counted vmcnt(6).
// OUT: 0 = fp32 row-major, 1 = bf16 row-major, 5 = V into swizzled KV slab.
template <int GELU, int OUT, int BN>
__global__ __launch_bounds__(256) void k_gemm(
    const u16* __restrict__ A, const u16* __restrict__ B,
    const float* __restrict__ bias, void* __restrict__ C0,
    int M, int Nc, int K) {
  const int NB = BN / 32;
  const int BUFE = 8192 + BN * 64;
  __shared__ u16 sm[3 * BUFE];

  int bx, by;
  swz_bid(bx, by);
  int m0 = by * 128, n0 = bx * BN;
  int t = threadIdx.x, lane = t & 63, w = t >> 6;
  int wr = (w >> 1) * 64, wc = (w & 1) * (BN / 2);
  int li = lane & 15, g = lane >> 4;
  int lrow = lane >> 3, lcg = lane & 7;

  f32x4 acc[4][NB] = {};
  const int nk = K >> 6;

  auto stage = [&](int kb, int buf) {
    int k0 = kb * 64;
    u16* base = sm + buf * BUFE;
#pragma unroll
    for (int j = 0; j < 4; ++j) {
      int jj = w * 4 + j;
      int row = jj * 8 + lrow;
      int cg = lcg ^ (row & 7);
      gload16(A + (size_t)(m0 + row) * K + k0 + cg * 8, base + jj * 512);
    }
#pragma unroll
    for (int j = 0; j < NB; ++j) {
      int jj = w * NB + j;
      int row = jj * 8 + lrow;
      int cg = lcg ^ (row & 7);
      gload16(B + (size_t)(n0 + row) * K + k0 + cg * 8, base + 8192 + jj * 512);
    }
  };

  stage(0, 0);
  stage(1, 1);
  VMCNTN(6);
  __syncthreads();

  int cur = 0;
  for (int kb = 0; kb < nk; ++kb) {
    int stb = cur + 2;
    if (stb >= 3) stb -= 3;
    if (kb + 2 < nk) stage(kb + 2, stb);

    const u16* bs = sm + cur * BUFE;
#pragma unroll
    for (int kk = 0; kk < 2; ++kk) {
      bf16x8 af[4], bf[NB];
#pragma unroll
      for (int i = 0; i < 4; ++i) {
        int row = wr + i * 16 + li;
        af[i] = *(const bf16x8*)&bs[row * 64 + (((kk * 4 + g) ^ (li & 7)) << 3)];
      }
#pragma unroll
      for (int b = 0; b < NB; ++b) {
        int row = wc + b * 16 + li;
        bf[b] = *(const bf16x8*)&bs[8192 + row * 64 + (((kk * 4 + g) ^ (li & 7)) << 3)];
      }
#pragma unroll
      for (int a = 0; a < 4; ++a)
#pragma unroll
        for (int b = 0; b < NB; ++b) acc[a][b] = MFMA16(af[a], bf[b], acc[a][b]);
    }
    if (kb + 2 < nk) {
      VMCNTN(6);
    } else {
      VMCNT0();
    }
    __syncthreads();
    cur = (cur == 2) ? 0 : cur + 1;
  }

#pragma unroll
  for (int a = 0; a < 4; ++a)
#pragma unroll
    for (int b = 0; b < NB; ++b)
#pragma unroll
      for (int r = 0; r < 4; ++r) {
        int row = m0 + wr + a * 16 + g * 4 + r;
        int col = n0 + wc + b * 16 + li;
        float v = acc[a][b][r] + bias[col];
        if (GELU) v = 0.5f * v * (1.0f + erff(v * 0.70710678118654752f));
        if (OUT == 0) {
          ((float*)C0)[(size_t)row * Nc + col] = v;
        } else if (OUT == 1) {
          ((u16*)C0)[(size_t)row * Nc + col] = bf16_rtn(v);
        } else if (OUT == 5) {
          int nn = row >> 11, tt = row & 2047, kbb = tt >> 6, tr = tt & 63;
          int hq = col >> 6, d = col & 63;
          size_t base = (((size_t)nn * 16 + hq) * 32 + kbb) * 8192 + 4096;
          size_t ov = base + d * 64 + (tr & 7) + (((tr >> 3) ^ (d & 7)) << 3);
          ((u16*)C0)[ov] = bf16_rtn(v);
        }
      }
}

// ------------- big-tile GEMM: 256x128, 8 waves, BK=64 -------------
// 3-buffer (144KB LDS) depth-2 counted vmcnt(6); per-block A-panel reuse 2x
// the 128-tile (FFN1's A-refetch was the R10 regression). XOR-swizzled LDS.
template <int GELU, int OUT>
__global__ __launch_bounds__(512, 1) void k_gemm2(
    const u16* __restrict__ A, const u16* __restrict__ B,
    const float* __restrict__ bias, void* __restrict__ C0,
    int M, int Nc, int K) {
  const int BUFE = 16384 + 8192;  // A[256][64] | B[128][64] (u16)
  __shared__ u16 sm[3 * BUFE];    // 144 KB

  int bx, by;
  swz_bid(bx, by);
  int m0 = by * 256, n0 = bx * 128;
  int t = threadIdx.x, lane = t & 63, w = t >> 6;
  int wr = (w >> 1) * 64, wc = (w & 1) * 64;
  int li = lane & 15, g = lane >> 4;
  int lrow = lane >> 3, lcg = lane & 7;

  f32x4 acc[4][4] = {};
  const int nk = K >> 6;

  auto stage = [&](int kb, int buf) {
    int k0 = kb * 64;
    u16* base = sm + buf * BUFE;
#pragma unroll
    for (int j = 0; j < 4; ++j) {  // A: 32 calls, 4 per wave
      int jj = w * 4 + j;
      int row = jj * 8 + lrow;
      int cg = lcg ^ (row & 7);
      gload16(A + (size_t)(m0 + row) * K + k0 + cg * 8, base + jj * 512);
    }
#pragma unroll
    for (int j = 0; j < 2; ++j) {  // B: 16 calls, 2 per wave
      int jj = w * 2 + j;
      int row = jj * 8 + lrow;
      int cg = lcg ^ (row & 7);
      gload16(B + (size_t)(n0 + row) * K + k0 + cg * 8, base + 16384 + jj * 512);
    }
  };

  stage(0, 0);
  stage(1, 1);
  VMCNTN(6);
  __syncthreads();

  int cur = 0;
  for (int kb = 0; kb < nk; ++kb) {
    int stb = cur + 2;
    if (stb >= 3) stb -= 3;
    if (kb + 2 < nk) stage(kb + 2, stb);

    const u16* bs = sm + cur * BUFE;
#pragma unroll
    for (int kk = 0; kk < 2; ++kk) {
      bf16x8 af[4], bf[4];
#pragma unroll
      for (int i = 0; i < 4; ++i) {
        int row = wr + i * 16 + li;
        af[i] = *(const bf16x8*)&bs[row * 64 + (((kk * 4 + g) ^ (li & 7)) << 3)];
      }
#pragma unroll
      for (int b = 0; b < 4; ++b) {
        int row = wc + b * 16 + li;
        bf[b] = *(const bf16x8*)&bs[16384 + row * 64 + (((kk * 4 + g) ^ (li & 7)) << 3)];
      }
#pragma unroll
      for (int a = 0; a < 4; ++a)
#pragma unroll
        for (int b = 0; b < 4; ++b) acc[a][b] = MFMA16(af[a], bf[b], acc[a][b]);
    }
    if (kb + 2 < nk) {
      VMCNTN(6);
    } else {
      VMCNT0();
    }
    __syncthreads();
    cur = (cur == 2) ? 0 : cur + 1;
  }

#pragma unroll
  for (int a = 0; a < 4; ++a)
#pragma unroll
    for (int b = 0; b < 4; ++b)
#pragma unroll
      for (int r = 0; r < 4; ++r) {
        int row = m0 + wr + a * 16 + g * 4 + r;  // wr spans 0..192 over 8 waves
        int col = n0 + wc + b * 16 + li;
        float v = acc[a][b][r] + bias[col];
        if (GELU) v = 0.5f * v * (1.0f + erff(v * 0.70710678118654752f));
        if (OUT == 1)
          ((u16*)C0)[(size_t)row * Nc + col] = bf16_rtn(v);
        else
          ((float*)C0)[(size_t)row * Nc + col] = v;
      }
}

// ------------- 2-pass split GEMM (K|Q fused projection) -------------
__global__ __launch_bounds__(256) void k_gemm_s(
    const u16* __restrict__ Ahi, const u16* __restrict__ Bhi,
    const u16* __restrict__ Blo, const float* __restrict__ bias,
    const float* __restrict__ bias2, void* __restrict__ C0,
    void* __restrict__ C1, void* __restrict__ C2, int M, int Nc, int K) {
  const int BUFE = 12288;
  __shared__ u16 sm[3 * BUFE];

  int bx, by;
  swz_bid(bx, by);
  int m0 = by * 128, n0 = bx * 128;
  int t = threadIdx.x, lane = t & 63, w = t >> 6;
  int wr = (w >> 1) * 64, wc = (w & 1) * 64;
  int li = lane & 15, g = lane >> 4;
  int srow = lane >> 2;
  int sc = ((lane & 3) ^ ((srow >> 1) & 3)) * 8;

  f32x4 acc[4][4] = {};
  const int nk = K >> 5;

  auto stage = [&](int kb, int buf) {
    int k0 = kb * 32;
    u16* base = sm + buf * BUFE;
#pragma unroll
    for (int c = 0; c < 2; ++c) {
      int row = w * 32 + c * 16 + srow;
      int ldso = w * 1024 + c * 512;
      gload16(Ahi + (size_t)(m0 + row) * K + k0 + sc, base + ldso);
      gload16(Bhi + (size_t)(n0 + row) * K + k0 + sc, base + 4096 + ldso);
      gload16(Blo + (size_t)(n0 + row) * K + k0 + sc, base + 8192 + ldso);
    }
  };

  stage(0, 0);
  stage(1, 1);
  VMCNTN(6);
  __syncthreads();

  int cur = 0;
  for (int kb = 0; kb < nk; ++kb) {
    int stb = cur + 2;
    if (stb >= 3) stb -= 3;
    if (kb + 2 < nk) stage(kb + 2, stb);

    const u16* bs = sm + cur * BUFE;
    bf16x8 af[4], bfr[4], bfl[4];
#pragma unroll
    for (int i = 0; i < 4; ++i) {
      int swz = (g ^ ((li >> 1) & 3)) << 3;
      af[i] = *(const bf16x8*)&bs[(wr + i * 16 + li) * 32 + swz];
      bfr[i] = *(const bf16x8*)&bs[4096 + (wc + i * 16 + li) * 32 + swz];
      bfl[i] = *(const bf16x8*)&bs[8192 + (wc + i * 16 + li) * 32 + swz];
    }
#pragma unroll
    for (int a = 0; a < 4; ++a)
#pragma unroll
      for (int b = 0; b < 4; ++b) {
        acc[a][b] = MFMA16(af[a], bfr[b], acc[a][b]);
        acc[a][b] = MFMA16(af[a], bfl[b], acc[a][b]);
      }
    if (kb + 2 < nk) {
      VMCNTN(6);
    } else {
      VMCNT0();
    }
    __syncthreads();
    cur = (cur == 2) ? 0 : cur + 1;
  }

#pragma unroll
  for (int a = 0; a < 4; ++a)
#pragma unroll
    for (int b = 0; b < 4; ++b)
#pragma unroll
      for (int r = 0; r < 4; ++r) {
        int row = m0 + wr + a * 16 + g * 4 + r;
        int col = n0 + wc + b * 16 + li;
        float bb = col < 1024 ? bias[col] : bias2[col - 1024];
        float v = acc[a][b][r] + bb;
        if (col < 1024) {
          int nn = row >> 11, tt = row & 2047, kbb = tt >> 6, tr = tt & 63;
          int hq = col >> 6, d = col & 63, ks = d >> 5, dc = d & 31;
          size_t base = (((size_t)nn * 16 + hq) * 32 + kbb) * 8192;
          size_t oh = base + ks * 2048 + tr * 32 + (dc & 7) +
                      (((dc >> 3) ^ ((tr >> 1) & 3)) << 3);
          ((u16*)C0)[oh] = bf16_rtn(v);
        } else {
          int cq = col - 1024;
          float vq = v * 1.4426950408889634f;
          u16 hh, ll;
          splitf(vq, hh, ll);
          size_t off = (((size_t)(row >> 11) * 16 + (cq >> 6)) * 2048 + (row & 2047)) * 64 + (cq & 63);
          ((u16*)C1)[off] = hh;
          ((u16*)C2)[off] = ll;
        }
      }
}

// ------------- flash attention, strictly-causal + [0,0], no 1/sqrt(d) -------------
__global__ __launch_bounds__(512) void k_attn(
    const u16* __restrict__ Qh, const u16* __restrict__ Ql,
    const u16* __restrict__ KV, u16* __restrict__ out) {
  const int T = 2048, HD = 64, H = 16, E = 1024;
  int hc = blockIdx.x;
  int h = hc & 15, n = hc >> 4;
  int qq = 15 - (int)blockIdx.y;
  __shared__ u16 KB[3][8192];
  __shared__ u16 P[2][128][36];
  int t = threadIdx.x, lane = t & 63, w = t >> 6;
  int li = lane & 15, g = lane >> 4;

  const size_t nh = (size_t)n * H + h;
  const u16* qhb = Qh + (nh * 2048 + (size_t)qq * 128) * 64;
  const u16* qlb = Ql + (nh * 2048 + (size_t)qq * 128) * 64;
  const u16* kvb = KV + nh * 32 * 8192;

  bf16x8 qh[2], ql[2];
#pragma unroll
  for (int ks = 0; ks < 2; ++ks) {
    qh[ks] = *(const bf16x8*)&qhb[(w * 16 + li) * 64 + ks * 32 + g * 8];
    ql[ks] = *(const bf16x8*)&qlb[(w * 16 + li) * 64 + ks * 32 + g * 8];
  }

#pragma unroll
  for (int j = 0; j < 2; ++j)
    gload16(kvb + (w * 2 + j) * 512 + lane * 8, &KB[0][(w * 2 + j) * 512]);
#pragma unroll
  for (int j = 0; j < 2; ++j)
    gload16(kvb + 8192 + (w * 2 + j) * 512 + lane * 8, &KB[1][(w * 2 + j) * 512]);
  VMCNTN(2);
  __syncthreads();

  float lr[4] = {0.f, 0.f, 0.f, 0.f};
  f32x4 O[4] = {};
  int cur = 0;
  const int nkb = 2 * qq + 2;

  for (int kb = 0; kb < nkb; ++kb) {
    int stb = cur + 2;
    if (stb >= 3) stb -= 3;
    if (kb + 2 < nkb) {
      const u16* src = kvb + (size_t)(kb + 2) * 8192 + (w * 2) * 512 + lane * 8;
#pragma unroll
      for (int j = 0; j < 2; ++j)
        gload16(src + j * 512, &KB[stb][(w * 2 + j) * 512]);
    }

    f32x4 s[4] = {};
#pragma unroll
    for (int ks = 0; ks < 2; ++ks)
#pragma unroll
      for (int c = 0; c < 4; ++c) {
        int jr = c * 16 + li;
        int sw = (jr >> 1) & 3;
        bf16x8 kh = *(const bf16x8*)&KB[cur][ks * 2048 + jr * 32 + ((g ^ sw) << 3)];
        s[c] = MFMA16(qh[ks], kh, s[c]);
        s[c] = MFMA16(ql[ks], kh, s[c]);
      }

    if (kb >= 2 * qq) {
#pragma unroll
      for (int c = 0; c < 4; ++c)
#pragma unroll
        for (int r = 0; r < 4; ++r) {
          int i = qq * 128 + w * 16 + g * 4 + r;
          int j = kb * 64 + c * 16 + li;
          if (!(j < i || (i == 0 && j == 0))) s[c][r] = -INFINITY;
        }
    }

#pragma unroll
    for (int c = 0; c < 4; ++c)
#pragma unroll
      for (int r = 0; r < 4; ++r) {
        float p = exp2_hw(s[c][r]);
        s[c][r] = p;
        lr[r] += p;
      }

#pragma unroll
    for (int c = 0; c < 4; ++c)
#pragma unroll
      for (int r = 0; r < 4; ++r)
        P[c >> 1][w * 16 + g * 4 + r][(c & 1) * 16 + li] = bf16_rtn(s[c][r]);

#pragma unroll
    for (int ks = 0; ks < 2; ++ks) {
      bf16x8 pa = *(const bf16x8*)&P[ks][w * 16 + li][g * 8];
#pragma unroll
      for (int c = 0; c < 4; ++c) {
        int d = c * 16 + li;
        int tc = ks * 4 + g;
        bf16x8 vb = *(const bf16x8*)&KB[cur][4096 + d * 64 + ((tc ^ (d & 7)) << 3)];
        O[c] = MFMA16(pa, vb, O[c]);
      }
    }
    if (kb + 2 < nkb) {
      VMCNTN(2);
    } else {
      VMCNT0();
    }
    __syncthreads();
    cur = (cur == 2) ? 0 : cur + 1;
  }

#pragma unroll
  for (int off = 1; off < 16; off <<= 1)
#pragma unroll
    for (int r = 0; r < 4; ++r) lr[r] += __shfl_xor(lr[r], off, 16);

#pragma unroll
  for (int c = 0; c < 4; ++c)
#pragma unroll
    for (int r = 0; r < 4; ++r) {
      float v = O[c][r] / lr[r];
      size_t row = (size_t)n * T + qq * 128 + w * 16 + g * 4 + r;
      out[row * E + h * HD + c * 16 + li] = bf16_rtn(v);
    }
}

// ---------------------------------------------------------------------------
extern "C" void kernel_launch(void* const* d_in, const int* in_sizes, int n_in,
                              void* d_out, int out_size, void* d_ws, size_t ws_size,
                              hipStream_t stream) {
  const float* kq = (const float*)d_in[0];
  const float* v = (const float*)d_in[1];
  const float* Wk = (const float*)d_in[2];
  const float* bk = (const float*)d_in[3];
  const float* Wq = (const float*)d_in[4];
  const float* bq = (const float*)d_in[5];
  const float* Wv = (const float*)d_in[6];
  const float* bv = (const float*)d_in[7];
  const float* W1 = (const float*)d_in[8];
  const float* b1 = (const float*)d_in[9];
  const float* W2 = (const float*)d_in[10];
  const float* b2 = (const float*)d_in[11];
  float* outp = (float*)d_out;

  char* ws = (char*)d_ws;
  u16* kq_hi = (u16*)(ws + 0);
  u16* v_bf = (u16*)(ws + 8388608);
  u16* hbuf = (u16*)(ws + 0);  // 32MB, aliases kq_hi/v_bf after attention
  u16* WkqT_hi = (u16*)(ws + 33554432);  // 4MB: [WkT | WqT]
  u16* WkqT_lo = (u16*)(ws + 37748736);  // 4MB
  u16* WvT = (u16*)(ws + 41943040);
  u16* W1T = (u16*)(ws + 44040192);
  u16* W2T = (u16*)(ws + 52428800);
  u16* Qh = (u16*)(ws + 60817408);
  u16* Ql = (u16*)(ws + 69206016);
  u16* KV = (u16*)(ws + 77594624);  // 16MB: 1024 slabs x 16KB (K hi + V)
  u16* attn_o = (u16*)(ws + 102760448);
  // total: 111,149,056 bytes

  // --- conversions ---
  k_cvt<<<8192, 256, 0, stream>>>(kq, v, kq_hi, v_bf);
  k_tconvW<<<dim3(32, 32, 3), 256, 0, stream>>>(Wk, Wq, Wv, WkqT_hi, WkqT_lo, WvT);
  k_tconv<<<dim3(128, 32), 256, 0, stream>>>(W1, W1T, 1024, 4096);
  k_tconv<<<dim3(32, 128), 256, 0, stream>>>(W2, W2T, 4096, 1024);

  // --- fused K|Q projection (2-pass split, 3-buf counted vmcnt, XCD swz) ---
  k_gemm_s<<<dim3(16, 32), 256, 0, stream>>>(
      kq_hi, WkqT_hi, WkqT_lo, bk, bq, KV, Qh, Ql, 4096, 2048, 1024);
  // --- V projection ---
  k_gemm<0, 5, 64><<<dim3(16, 32), 256, 0, stream>>>(
      v_bf, WvT, bv, KV, 4096, 1024, 1024);

  // --- attention ---
  k_attn<<<dim3(32, 16), 512, 0, stream>>>(Qh, Ql, KV, attn_o);

  // --- FFN ---
  // FFN1: 256x128 big-tile (A-panel reuse 2x; R10's BN=64 doubled A refetch)
  k_gemm2<1, 1><<<dim3(32, 16), 512, 0, stream>>>(
      attn_o, W1T, b1, hbuf, 4096, 4096, 1024);
  k_gemm<0, 0, 64><<<dim3(16, 32), 256, 0, stream>>>(
      hbuf, W2T, b2, outp, 4096, 1024, 4096);
}

// Round 12
// 227.996 us; speedup vs baseline: 3.2674x; 1.0190x over previous
//
#include <hip/hip_runtime.h>

typedef short bf16x8 __attribute__((ext_vector_type(8)));
typedef unsigned short u16x8 __attribute__((ext_vector_type(8)));
typedef float f32x4 __attribute__((ext_vector_type(4)));
typedef unsigned short u16;

#define MFMA16(a, b, c) __builtin_amdgcn_mfma_f32_16x16x32_bf16((a), (b), (c), 0, 0, 0)
// Full drain before barrier (R4 race lesson).
#define VMCNT0() asm volatile("s_waitcnt vmcnt(0)" ::: "memory")
// Counted wait (T4): allow n per-wave loads to remain in flight; guarantees all
// OLDER loads (the next tile to be consumed) have landed. Barrier publishes.
#define VMCNTN(n) asm volatile("s_waitcnt vmcnt(" #n ")" ::: "memory")

__device__ __forceinline__ u16 bf16_rtn(float f) {
  unsigned u = __float_as_uint(f);
  u += 0x7fffu + ((u >> 16) & 1u);
  return (u16)(u >> 16);
}
__device__ __forceinline__ float bf16_to_f(u16 h) {
  return __uint_as_float(((unsigned)h) << 16);
}
__device__ __forceinline__ void splitf(float f, u16& hi, u16& lo) {
  hi = bf16_rtn(f);
  lo = bf16_rtn(f - bf16_to_f(hi));
}
__device__ __forceinline__ void gload16(const void* g, void* l) {
  __builtin_amdgcn_global_load_lds(
      (const __attribute__((address_space(1))) unsigned int*)g,
      (__attribute__((address_space(3))) unsigned int*)l, 16, 0, 0);
}
__device__ __forceinline__ float exp2_hw(float x) {
  float r;
  asm("v_exp_f32 %0, %1" : "=v"(r) : "v"(x));
  return r;
}
// XCD-aware bijective block swizzle (T1). Requires gx*gy % 8 == 0 (all our grids).
__device__ __forceinline__ void swz_bid(int& bx, int& by) {
  int gx = gridDim.x;
  int lin = (int)blockIdx.y * gx + (int)blockIdx.x;
  int cpx = (gx * (int)gridDim.y) >> 3;
  int nl = (lin & 7) * cpx + (lin >> 3);
  bx = nl % gx;
  by = nl / gx;
}

// ---------------- elementwise convert: kq -> bf16, v -> bf16 ----------------
__global__ void k_cvt(const float* __restrict__ a, const float* __restrict__ b,
                      u16* __restrict__ ah, u16* __restrict__ vb) {
  int i = blockIdx.x * blockDim.x + threadIdx.x;
  const int N4 = 1 << 20;
  const float4 v4 = (i < N4) ? ((const float4*)a)[i] : ((const float4*)b)[i - N4];
  ushort4 h;
  h.x = bf16_rtn(v4.x);
  h.y = bf16_rtn(v4.y);
  h.z = bf16_rtn(v4.z);
  h.w = bf16_rtn(v4.w);
  if (i < N4)
    ((ushort4*)ah)[i] = h;
  else
    ((ushort4*)vb)[i - N4] = h;
}

// ------------- fused transpose of the three 1024x1024 weights -------------
__global__ void k_tconvW(const float* __restrict__ Wk, const float* __restrict__ Wq,
                         const float* __restrict__ Wv, u16* __restrict__ hi,
                         u16* __restrict__ lo, u16* __restrict__ wvt) {
  int z = blockIdx.z;
  const float* in = (z == 0) ? Wk : (z == 1) ? Wq : Wv;
  __shared__ float tile[32][33];
  int c0 = blockIdx.x * 32, r0 = blockIdx.y * 32;
  int tx = threadIdx.x & 31, ty = threadIdx.x >> 5;
#pragma unroll
  for (int i = 0; i < 4; ++i)
    tile[ty + i * 8][tx] = in[(size_t)(r0 + ty + i * 8) * 1024 + c0 + tx];
  __syncthreads();
#pragma unroll
  for (int i = 0; i < 4; ++i) {
    float v = tile[tx][ty + i * 8];
    size_t o = (size_t)(c0 + ty + i * 8) * 1024 + r0 + tx;
    if (z < 2) {
      u16 h, l;
      splitf(v, h, l);
      hi[(size_t)z * 1048576 + o] = h;
      lo[(size_t)z * 1048576 + o] = l;
    } else {
      wvt[o] = bf16_rtn(v);
    }
  }
}

// ------------- transpose fp32 [R][C] -> bf16 [C][R] (plain) -------------
__global__ void k_tconv(const float* __restrict__ in, u16* __restrict__ hi,
                        int R, int C) {
  __shared__ float tile[32][33];
  int c0 = blockIdx.x * 32, r0 = blockIdx.y * 32;
  int tx = threadIdx.x & 31, ty = threadIdx.x >> 5;
#pragma unroll
  for (int i = 0; i < 4; ++i)
    tile[ty + i * 8][tx] = in[(size_t)(r0 + ty + i * 8) * C + c0 + tx];
  __syncthreads();
#pragma unroll
  for (int i = 0; i < 4; ++i)
    hi[(size_t)(c0 + ty + i * 8) * R + r0 + tx] = bf16_rtn(tile[tx][ty + i * 8]);
}

// ------------- non-split GEMM: BM=128, BN in {64,128} -------------
// BK=64, XOR-swizzled LDS, 3-buffer depth-2, counted vmcnt (= loads/wave/tile).
// OUT: 0 = fp32 row-major, 1 = bf16 row-major, 5 = V into swizzled KV slab.
template <int GELU, int OUT, int BN>
__global__ __launch_bounds__(256) void k_gemm(
    const u16* __restrict__ A, const u16* __restrict__ B,
    const float* __restrict__ bias, void* __restrict__ C0,
    int M, int Nc, int K) {
  const int NB = BN / 32;
  const int BUFE = 8192 + BN * 64;
  __shared__ u16 sm[3 * BUFE];

  int bx, by;
  swz_bid(bx, by);
  int m0 = by * 128, n0 = bx * BN;
  int t = threadIdx.x, lane = t & 63, w = t >> 6;
  int wr = (w >> 1) * 64, wc = (w & 1) * (BN / 2);
  int li = lane & 15, g = lane >> 4;
  int lrow = lane >> 3, lcg = lane & 7;

  f32x4 acc[4][NB] = {};
  const int nk = K >> 6;

  auto stage = [&](int kb, int buf) {
    int k0 = kb * 64;
    u16* base = sm + buf * BUFE;
#pragma unroll
    for (int j = 0; j < 4; ++j) {
      int jj = w * 4 + j;
      int row = jj * 8 + lrow;
      int cg = lcg ^ (row & 7);
      gload16(A + (size_t)(m0 + row) * K + k0 + cg * 8, base + jj * 512);
    }
#pragma unroll
    for (int j = 0; j < NB; ++j) {
      int jj = w * NB + j;
      int row = jj * 8 + lrow;
      int cg = lcg ^ (row & 7);
      gload16(B + (size_t)(n0 + row) * K + k0 + cg * 8, base + 8192 + jj * 512);
    }
  };

  stage(0, 0);
  stage(1, 1);
  if (NB == 4) { VMCNTN(8); } else { VMCNTN(6); }  // = loads/wave/tile
  __syncthreads();

  int cur = 0;
  for (int kb = 0; kb < nk; ++kb) {
    int stb = cur + 2;
    if (stb >= 3) stb -= 3;
    if (kb + 2 < nk) stage(kb + 2, stb);

    const u16* bs = sm + cur * BUFE;
#pragma unroll
    for (int kk = 0; kk < 2; ++kk) {
      bf16x8 af[4], bf[NB];
#pragma unroll
      for (int i = 0; i < 4; ++i) {
        int row = wr + i * 16 + li;
        af[i] = *(const bf16x8*)&bs[row * 64 + (((kk * 4 + g) ^ (li & 7)) << 3)];
      }
#pragma unroll
      for (int b = 0; b < NB; ++b) {
        int row = wc + b * 16 + li;
        bf[b] = *(const bf16x8*)&bs[8192 + row * 64 + (((kk * 4 + g) ^ (li & 7)) << 3)];
      }
#pragma unroll
      for (int a = 0; a < 4; ++a)
#pragma unroll
        for (int b = 0; b < NB; ++b) acc[a][b] = MFMA16(af[a], bf[b], acc[a][b]);
    }
    if (kb + 2 < nk) {
      if (NB == 4) { VMCNTN(8); } else { VMCNTN(6); }
    } else {
      VMCNT0();
    }
    __syncthreads();
    cur = (cur == 2) ? 0 : cur + 1;
  }

#pragma unroll
  for (int a = 0; a < 4; ++a)
#pragma unroll
    for (int b = 0; b < NB; ++b)
#pragma unroll
      for (int r = 0; r < 4; ++r) {
        int row = m0 + wr + a * 16 + g * 4 + r;
        int col = n0 + wc + b * 16 + li;
        float v = acc[a][b][r] + bias[col];
        if (GELU) v = 0.5f * v * (1.0f + erff(v * 0.70710678118654752f));
        if (OUT == 0) {
          ((float*)C0)[(size_t)row * Nc + col] = v;
        } else if (OUT == 1) {
          ((u16*)C0)[(size_t)row * Nc + col] = bf16_rtn(v);
        } else if (OUT == 5) {
          int nn = row >> 11, tt = row & 2047, kbb = tt >> 6, tr = tt & 63;
          int hq = col >> 6, d = col & 63;
          size_t base = (((size_t)nn * 16 + hq) * 32 + kbb) * 8192 + 4096;
          size_t ov = base + d * 64 + (tr & 7) + (((tr >> 3) ^ (d & 7)) << 3);
          ((u16*)C0)[ov] = bf16_rtn(v);
        }
      }
}

// ------------- big-tile GEMM: 256x256, 8 waves, BK=64 -------------
// m201 geometry on our skeleton: per-wave output 128x64 (43.7 FLOP/LDS-byte,
// +33% vs 64x64), A/B panel refetch halved (16 readers). 2-buffer LDS (128KB);
// drain-at-barrier is free because the compute phase (~2x HBM latency) covers
// the prefetch issued at phase start. XOR-swizzled staging/reads.
template <int GELU, int OUT>
__global__ __launch_bounds__(512, 1) void k_gemm2(
    const u16* __restrict__ A, const u16* __restrict__ B,
    const float* __restrict__ bias, void* __restrict__ C0,
    int M, int Nc, int K) {
  const int BUFE = 32768;       // u16: A[256][64] | B[256][64]
  __shared__ u16 sm[2 * BUFE];  // 128 KB

  int bx, by;
  swz_bid(bx, by);
  int m0 = by * 256, n0 = bx * 256;
  int t = threadIdx.x, lane = t & 63, w = t >> 6;
  int wr = (w >> 2) * 128, wc = (w & 3) * 64;  // 2M x 4N wave grid
  int li = lane & 15, g = lane >> 4;
  int lrow = lane >> 3, lcg = lane & 7;

  f32x4 acc[8][4] = {};
  const int nk = K >> 6;

  auto stage = [&](int kb, int buf) {
    int k0 = kb * 64;
    u16* base = sm + buf * BUFE;
#pragma unroll
    for (int j = 0; j < 4; ++j) {
      int jj = w * 4 + j;       // 0..31
      int row = jj * 8 + lrow;  // 0..255
      int cg = lcg ^ (row & 7);
      gload16(A + (size_t)(m0 + row) * K + k0 + cg * 8, base + jj * 512);
      gload16(B + (size_t)(n0 + row) * K + k0 + cg * 8, base + 16384 + jj * 512);
    }
  };

  stage(0, 0);
  VMCNT0();
  __syncthreads();

  int cur = 0;
  for (int kb = 0; kb < nk; ++kb) {
    if (kb + 1 < nk) stage(kb + 1, cur ^ 1);  // issued at phase start

    const u16* bs = sm + cur * BUFE;
#pragma unroll
    for (int kk = 0; kk < 2; ++kk) {
      bf16x8 af[8], bf[4];
#pragma unroll
      for (int i = 0; i < 8; ++i) {
        int row = wr + i * 16 + li;
        af[i] = *(const bf16x8*)&bs[row * 64 + (((kk * 4 + g) ^ (li & 7)) << 3)];
      }
#pragma unroll
      for (int b = 0; b < 4; ++b) {
        int row = wc + b * 16 + li;
        bf[b] = *(const bf16x8*)&bs[16384 + row * 64 + (((kk * 4 + g) ^ (li & 7)) << 3)];
      }
#pragma unroll
      for (int a = 0; a < 8; ++a)
#pragma unroll
        for (int b = 0; b < 4; ++b) acc[a][b] = MFMA16(af[a], bf[b], acc[a][b]);
    }
    VMCNT0();         // prefetch landed long ago (compute phase >> HBM latency)
    __syncthreads();
    cur ^= 1;
  }

#pragma unroll
  for (int a = 0; a < 8; ++a)
#pragma unroll
    for (int b = 0; b < 4; ++b)
#pragma unroll
      for (int r = 0; r < 4; ++r) {
        int row = m0 + wr + a * 16 + g * 4 + r;
        int col = n0 + wc + b * 16 + li;
        float v = acc[a][b][r] + bias[col];
        if (GELU) v = 0.5f * v * (1.0f + erff(v * 0.70710678118654752f));
        if (OUT == 1)
          ((u16*)C0)[(size_t)row * Nc + col] = bf16_rtn(v);
        else
          ((float*)C0)[(size_t)row * Nc + col] = v;
      }
}

// ------------- 2-pass split GEMM (K|Q fused projection) -------------
__global__ __launch_bounds__(256) void k_gemm_s(
    const u16* __restrict__ Ahi, const u16* __restrict__ Bhi,
    const u16* __restrict__ Blo, const float* __restrict__ bias,
    const float* __restrict__ bias2, void* __restrict__ C0,
    void* __restrict__ C1, void* __restrict__ C2, int M, int Nc, int K) {
  const int BUFE = 12288;
  __shared__ u16 sm[3 * BUFE];

  int bx, by;
  swz_bid(bx, by);
  int m0 = by * 128, n0 = bx * 128;
  int t = threadIdx.x, lane = t & 63, w = t >> 6;
  int wr = (w >> 1) * 64, wc = (w & 1) * 64;
  int li = lane & 15, g = lane >> 4;
  int srow = lane >> 2;
  int sc = ((lane & 3) ^ ((srow >> 1) & 3)) * 8;

  f32x4 acc[4][4] = {};
  const int nk = K >> 5;

  auto stage = [&](int kb, int buf) {
    int k0 = kb * 32;
    u16* base = sm + buf * BUFE;
#pragma unroll
    for (int c = 0; c < 2; ++c) {
      int row = w * 32 + c * 16 + srow;
      int ldso = w * 1024 + c * 512;
      gload16(Ahi + (size_t)(m0 + row) * K + k0 + sc, base + ldso);
      gload16(Bhi + (size_t)(n0 + row) * K + k0 + sc, base + 4096 + ldso);
      gload16(Blo + (size_t)(n0 + row) * K + k0 + sc, base + 8192 + ldso);
    }
  };

  stage(0, 0);
  stage(1, 1);
  VMCNTN(6);
  __syncthreads();

  int cur = 0;
  for (int kb = 0; kb < nk; ++kb) {
    int stb = cur + 2;
    if (stb >= 3) stb -= 3;
    if (kb + 2 < nk) stage(kb + 2, stb);

    const u16* bs = sm + cur * BUFE;
    bf16x8 af[4], bfr[4], bfl[4];
#pragma unroll
    for (int i = 0; i < 4; ++i) {
      int swz = (g ^ ((li >> 1) & 3)) << 3;
      af[i] = *(const bf16x8*)&bs[(wr + i * 16 + li) * 32 + swz];
      bfr[i] = *(const bf16x8*)&bs[4096 + (wc + i * 16 + li) * 32 + swz];
      bfl[i] = *(const bf16x8*)&bs[8192 + (wc + i * 16 + li) * 32 + swz];
    }
#pragma unroll
    for (int a = 0; a < 4; ++a)
#pragma unroll
      for (int b = 0; b < 4; ++b) {
        acc[a][b] = MFMA16(af[a], bfr[b], acc[a][b]);
        acc[a][b] = MFMA16(af[a], bfl[b], acc[a][b]);
      }
    if (kb + 2 < nk) {
      VMCNTN(6);
    } else {
      VMCNT0();
    }
    __syncthreads();
    cur = (cur == 2) ? 0 : cur + 1;
  }

#pragma unroll
  for (int a = 0; a < 4; ++a)
#pragma unroll
    for (int b = 0; b < 4; ++b)
#pragma unroll
      for (int r = 0; r < 4; ++r) {
        int row = m0 + wr + a * 16 + g * 4 + r;
        int col = n0 + wc + b * 16 + li;
        float bb = col < 1024 ? bias[col] : bias2[col - 1024];
        float v = acc[a][b][r] + bb;
        if (col < 1024) {
          int nn = row >> 11, tt = row & 2047, kbb = tt >> 6, tr = tt & 63;
          int hq = col >> 6, d = col & 63, ks = d >> 5, dc = d & 31;
          size_t base = (((size_t)nn * 16 + hq) * 32 + kbb) * 8192;
          size_t oh = base + ks * 2048 + tr * 32 + (dc & 7) +
                      (((dc >> 3) ^ ((tr >> 1) & 3)) << 3);
          ((u16*)C0)[oh] = bf16_rtn(v);
        } else {
          int cq = col - 1024;
          float vq = v * 1.4426950408889634f;
          u16 hh, ll;
          splitf(vq, hh, ll);
          size_t off = (((size_t)(row >> 11) * 16 + (cq >> 6)) * 2048 + (row & 2047)) * 64 + (cq & 63);
          ((u16*)C1)[off] = hh;
          ((u16*)C2)[off] = ll;
        }
      }
}

// ------------- flash attention, strictly-causal + [0,0], no 1/sqrt(d) -------------
__global__ __launch_bounds__(512) void k_attn(
    const u16* __restrict__ Qh, const u16* __restrict__ Ql,
    const u16* __restrict__ KV, u16* __restrict__ out) {
  const int T = 2048, HD = 64, H = 16, E = 1024;
  int hc = blockIdx.x;
  int h = hc & 15, n = hc >> 4;
  int qq = 15 - (int)blockIdx.y;
  __shared__ u16 KB[3][8192];
  __shared__ u16 P[2][128][36];
  int t = threadIdx.x, lane = t & 63, w = t >> 6;
  int li = lane & 15, g = lane >> 4;

  const size_t nh = (size_t)n * H + h;
  const u16* qhb = Qh + (nh * 2048 + (size_t)qq * 128) * 64;
  const u16* qlb = Ql + (nh * 2048 + (size_t)qq * 128) * 64;
  const u16* kvb = KV + nh * 32 * 8192;

  bf16x8 qh[2], ql[2];
#pragma unroll
  for (int ks = 0; ks < 2; ++ks) {
    qh[ks] = *(const bf16x8*)&qhb[(w * 16 + li) * 64 + ks * 32 + g * 8];
    ql[ks] = *(const bf16x8*)&qlb[(w * 16 + li) * 64 + ks * 32 + g * 8];
  }

#pragma unroll
  for (int j = 0; j < 2; ++j)
    gload16(kvb + (w * 2 + j) * 512 + lane * 8, &KB[0][(w * 2 + j) * 512]);
#pragma unroll
  for (int j = 0; j < 2; ++j)
    gload16(kvb + 8192 + (w * 2 + j) * 512 + lane * 8, &KB[1][(w * 2 + j) * 512]);
  VMCNTN(2);
  __syncthreads();

  float lr[4] = {0.f, 0.f, 0.f, 0.f};
  f32x4 O[4] = {};
  int cur = 0;
  const int nkb = 2 * qq + 2;

  for (int kb = 0; kb < nkb; ++kb) {
    int stb = cur + 2;
    if (stb >= 3) stb -= 3;
    if (kb + 2 < nkb) {
      const u16* src = kvb + (size_t)(kb + 2) * 8192 + (w * 2) * 512 + lane * 8;
#pragma unroll
      for (int j = 0; j < 2; ++j)
        gload16(src + j * 512, &KB[stb][(w * 2 + j) * 512]);
    }

    f32x4 s[4] = {};
#pragma unroll
    for (int ks = 0; ks < 2; ++ks)
#pragma unroll
      for (int c = 0; c < 4; ++c) {
        int jr = c * 16 + li;
        int sw = (jr >> 1) & 3;
        bf16x8 kh = *(const bf16x8*)&KB[cur][ks * 2048 + jr * 32 + ((g ^ sw) << 3)];
        s[c] = MFMA16(qh[ks], kh, s[c]);
        s[c] = MFMA16(ql[ks], kh, s[c]);
      }

    if (kb >= 2 * qq) {
#pragma unroll
      for (int c = 0; c < 4; ++c)
#pragma unroll
        for (int r = 0; r < 4; ++r) {
          int i = qq * 128 + w * 16 + g * 4 + r;
          int j = kb * 64 + c * 16 + li;
          if (!(j < i || (i == 0 && j == 0))) s[c][r] = -INFINITY;
        }
    }

#pragma unroll
    for (int c = 0; c < 4; ++c)
#pragma unroll
      for (int r = 0; r < 4; ++r) {
        float p = exp2_hw(s[c][r]);
        s[c][r] = p;
        lr[r] += p;
      }

#pragma unroll
    for (int c = 0; c < 4; ++c)
#pragma unroll
      for (int r = 0; r < 4; ++r)
        P[c >> 1][w * 16 + g * 4 + r][(c & 1) * 16 + li] = bf16_rtn(s[c][r]);

#pragma unroll
    for (int ks = 0; ks < 2; ++ks) {
      bf16x8 pa = *(const bf16x8*)&P[ks][w * 16 + li][g * 8];
#pragma unroll
      for (int c = 0; c < 4; ++c) {
        int d = c * 16 + li;
        int tc = ks * 4 + g;
        bf16x8 vb = *(const bf16x8*)&KB[cur][4096 + d * 64 + ((tc ^ (d & 7)) << 3)];
        O[c] = MFMA16(pa, vb, O[c]);
      }
    }
    if (kb + 2 < nkb) {
      VMCNTN(2);
    } else {
      VMCNT0();
    }
    __syncthreads();
    cur = (cur == 2) ? 0 : cur + 1;
  }

#pragma unroll
  for (int off = 1; off < 16; off <<= 1)
#pragma unroll
    for (int r = 0; r < 4; ++r) lr[r] += __shfl_xor(lr[r], off, 16);

#pragma unroll
  for (int c = 0; c < 4; ++c)
#pragma unroll
    for (int r = 0; r < 4; ++r) {
      float v = O[c][r] / lr[r];
      size_t row = (size_t)n * T + qq * 128 + w * 16 + g * 4 + r;
      out[row * E + h * HD + c * 16 + li] = bf16_rtn(v);
    }
}

// ---------------------------------------------------------------------------
extern "C" void kernel_launch(void* const* d_in, const int* in_sizes, int n_in,
                              void* d_out, int out_size, void* d_ws, size_t ws_size,
                              hipStream_t stream) {
  const float* kq = (const float*)d_in[0];
  const float* v = (const float*)d_in[1];
  const float* Wk = (const float*)d_in[2];
  const float* bk = (const float*)d_in[3];
  const float* Wq = (const float*)d_in[4];
  const float* bq = (const float*)d_in[5];
  const float* Wv = (const float*)d_in[6];
  const float* bv = (const float*)d_in[7];
  const float* W1 = (const float*)d_in[8];
  const float* b1 = (const float*)d_in[9];
  const float* W2 = (const float*)d_in[10];
  const float* b2 = (const float*)d_in[11];
  float* outp = (float*)d_out;

  char* ws = (char*)d_ws;
  u16* kq_hi = (u16*)(ws + 0);
  u16* v_bf = (u16*)(ws + 8388608);
  u16* hbuf = (u16*)(ws + 0);  // 32MB, aliases kq_hi/v_bf after attention
  u16* WkqT_hi = (u16*)(ws + 33554432);  // 4MB: [WkT | WqT]
  u16* WkqT_lo = (u16*)(ws + 37748736);  // 4MB
  u16* WvT = (u16*)(ws + 41943040);
  u16* W1T = (u16*)(ws + 44040192);
  u16* W2T = (u16*)(ws + 52428800);
  u16* Qh = (u16*)(ws + 60817408);
  u16* Ql = (u16*)(ws + 69206016);
  u16* KV = (u16*)(ws + 77594624);  // 16MB: 1024 slabs x 16KB (K hi + V)
  u16* attn_o = (u16*)(ws + 102760448);
  // total: 111,149,056 bytes

  // --- conversions ---
  k_cvt<<<8192, 256, 0, stream>>>(kq, v, kq_hi, v_bf);
  k_tconvW<<<dim3(32, 32, 3), 256, 0, stream>>>(Wk, Wq, Wv, WkqT_hi, WkqT_lo, WvT);
  k_tconv<<<dim3(128, 32), 256, 0, stream>>>(W1, W1T, 1024, 4096);
  k_tconv<<<dim3(32, 128), 256, 0, stream>>>(W2, W2T, 4096, 1024);

  // --- fused K|Q projection (2-pass split, 3-buf counted vmcnt, XCD swz) ---
  k_gemm_s<<<dim3(16, 32), 256, 0, stream>>>(
      kq_hi, WkqT_hi, WkqT_lo, bk, bq, KV, Qh, Ql, 4096, 2048, 1024);
  // --- V projection ---
  k_gemm<0, 5, 64><<<dim3(16, 32), 256, 0, stream>>>(
      v_bf, WvT, bv, KV, 4096, 1024, 1024);

  // --- attention ---
  k_attn<<<dim3(32, 16), 512, 0, stream>>>(Qh, Ql, KV, attn_o);

  // --- FFN ---
  // FFN1: 256x256 big-tile (per-wave 128x64; A/B refetch halved vs 256x128)
  k_gemm2<1, 1><<<dim3(16, 16), 512, 0, stream>>>(
      attn_o, W1T, b1, hbuf, 4096, 4096, 1024);
  // FFN2: BN=128 (A=32MB logical refetch halved vs BN=64)
  k_gemm<0, 0, 128><<<dim3(8, 32), 256, 0, stream>>>(
      hbuf, W2T, b2, outp, 4096, 1024, 4096);
}